// Round 2
// baseline (1778.357 us; speedup 1.0000x reference)
//
#include <hip/hip_runtime.h>

// ---------------------------------------------------------------------------
// Problem constants (fixed by the reference)
// ---------------------------------------------------------------------------
#define TOK   4096      // B*S
#define DIM   1024
#define NQK   4096
#define NV    4096
#define NKN   8192
#define SLEN  2048
#define NH    16
#define DH    64
#define CAPA  48        // capacity for k=32 gates (slack for ties)
#define CAPK  96        // capacity for k=64 gate

typedef float  f32x4  __attribute__((ext_vector_type(4)));
typedef short  short8 __attribute__((ext_vector_type(8)));
typedef unsigned int  u32;
typedef unsigned short u16;

__device__ __forceinline__ u16 f2bf(float f) {
    u32 u = __float_as_uint(f);
    u32 r = (u + 0x7fffu + ((u >> 16) & 1u)) >> 16;
    return (u16)r;
}

__device__ __forceinline__ f32x4 mfma_bf16(short8 a, short8 b, f32x4 c) {
    asm volatile("v_mfma_f32_16x16x32_bf16 %0, %1, %2, %0"
                 : "+v"(c) : "v"(a), "v"(b));
    return c;
}

__device__ __forceinline__ float blockReduceF(float v, float* red, int wave, int lane) {
#pragma unroll
    for (int off = 32; off > 0; off >>= 1) v += __shfl_xor(v, off);
    __syncthreads();
    if (lane == 0) red[wave] = v;
    __syncthreads();
    return red[0] + red[1] + red[2] + red[3];
}

// ---------------------------------------------------------------------------
// f32 -> bf16 conversion (grid-stride, float4)
// ---------------------------------------------------------------------------
__global__ __launch_bounds__(256) void k_f32_to_bf16(const float* __restrict__ in,
                                                     u16* __restrict__ out, int n4) {
    int i = blockIdx.x * 256 + threadIdx.x;
    int stride = gridDim.x * 256;
    for (; i < n4; i += stride) {
        float4 v = reinterpret_cast<const float4*>(in)[i];
        ushort4 o = make_ushort4(f2bf(v.x), f2bf(v.y), f2bf(v.z), f2bf(v.w));
        reinterpret_cast<ushort4*>(out)[i] = o;
    }
}

// transpose 1024x1024 f32 -> bf16 (out[n][k] = in[k][n])
__global__ __launch_bounds__(256) void k_transpose_bf16(const float* __restrict__ in,
                                                        u16* __restrict__ out) {
    __shared__ float tile[32][33];
    int bx = blockIdx.x * 32;   // col of in
    int by = blockIdx.y * 32;   // row of in
    int tx = threadIdx.x & 31;
    int ty = threadIdx.x >> 5;  // 0..7
    for (int r = ty; r < 32; r += 8)
        tile[r][tx] = in[(size_t)(by + r) * DIM + bx + tx];
    __syncthreads();
    for (int r = ty; r < 32; r += 8)
        out[(size_t)(bx + r) * DIM + by + tx] = f2bf(tile[tx][r]);
}

// ---------------------------------------------------------------------------
// LayerNorm + tau projection; writes bf16 normed + f32 tau[t][ntau]
// ---------------------------------------------------------------------------
__global__ __launch_bounds__(256) void k_ln_tau(const float* __restrict__ x,
                                                const float* __restrict__ sc,
                                                const float* __restrict__ bi,
                                                const float* __restrict__ tauk,
                                                const float* __restrict__ taub,
                                                int ntau,
                                                u16* __restrict__ nrm,
                                                float* __restrict__ tau_out) {
    __shared__ float red[4];
    int t = blockIdx.x, tid = threadIdx.x, wave = tid >> 6, lane = tid & 63;
    const float4 xv = reinterpret_cast<const float4*>(x + (size_t)t * DIM)[tid];
    float s = xv.x + xv.y + xv.z + xv.w;
    s = blockReduceF(s, red, wave, lane);
    float mean = s * (1.0f / DIM);
    float d0 = xv.x - mean, d1 = xv.y - mean, d2 = xv.z - mean, d3 = xv.w - mean;
    float ss = d0 * d0 + d1 * d1 + d2 * d2 + d3 * d3;
    ss = blockReduceF(ss, red, wave, lane);
    float rstd = rsqrtf(ss * (1.0f / DIM) + 1e-6f);
    const float4 scv = reinterpret_cast<const float4*>(sc)[tid];
    const float4 biv = reinterpret_cast<const float4*>(bi)[tid];
    float n0 = d0 * rstd * scv.x + biv.x;
    float n1 = d1 * rstd * scv.y + biv.y;
    float n2 = d2 * rstd * scv.z + biv.z;
    float n3 = d3 * rstd * scv.w + biv.w;
    ushort4 o = make_ushort4(f2bf(n0), f2bf(n1), f2bf(n2), f2bf(n3));
    reinterpret_cast<ushort4*>(nrm + (size_t)t * DIM)[tid] = o;
    int d = tid * 4;
    for (int j = 0; j < ntau; j++) {
        float p = n0 * tauk[(size_t)(d + 0) * ntau + j] + n1 * tauk[(size_t)(d + 1) * ntau + j]
                + n2 * tauk[(size_t)(d + 2) * ntau + j] + n3 * tauk[(size_t)(d + 3) * ntau + j];
        p = blockReduceF(p, red, wave, lane);
        if (tid == 0) tau_out[(size_t)t * ntau + j] = p + taub[j];
    }
}

// ---------------------------------------------------------------------------
// C[M][N] = A[M][K] @ B[N][K]^T   (bf16 in, f32 out), optional residual fuse
// 128x128 tile, 4 waves, 16x16x32 MFMA, XOR-swizzled LDS (2-way, free)
// ---------------------------------------------------------------------------
__global__ __launch_bounds__(256) void k_gemm_bt(const u16* __restrict__ A,
                                                 const u16* __restrict__ B,
                                                 float* __restrict__ C,
                                                 int M, int N, int K,
                                                 const float* __restrict__ res) {
    __shared__ __align__(16) u16 As[4096];
    __shared__ __align__(16) u16 Bs[4096];
    int tid = threadIdx.x;
    int wave = tid >> 6, lane = tid & 63;
    int m0 = blockIdx.y * 128, n0 = blockIdx.x * 128;
    int srow = tid >> 2, skg = tid & 3;
    int wm = (wave >> 1) * 64, wn = (wave & 1) * 64;
    int kg = lane >> 4, l15 = lane & 15;
    f32x4 acc[4][4];
#pragma unroll
    for (int i = 0; i < 4; i++)
#pragma unroll
        for (int j = 0; j < 4; j++) { f32x4 z = {0.f, 0.f, 0.f, 0.f}; acc[i][j] = z; }

    for (int k0 = 0; k0 < K; k0 += 32) {
        __syncthreads();
#pragma unroll
        for (int i = 0; i < 2; i++) {
            int row = srow + i * 64;
            int ch = skg * 128 + (row ^ (skg * 2));
            *reinterpret_cast<uint4*>(&As[ch * 8]) =
                *reinterpret_cast<const uint4*>(A + (size_t)(m0 + row) * K + k0 + skg * 8);
            *reinterpret_cast<uint4*>(&Bs[ch * 8]) =
                *reinterpret_cast<const uint4*>(B + (size_t)(n0 + row) * K + k0 + skg * 8);
        }
        __syncthreads();
        short8 af[4], bg[4];
#pragma unroll
        for (int mi = 0; mi < 4; mi++) {
            int row = wm + mi * 16 + l15;
            af[mi] = *reinterpret_cast<const short8*>(&As[(kg * 128 + (row ^ (kg * 2))) * 8]);
        }
#pragma unroll
        for (int ni = 0; ni < 4; ni++) {
            int row = wn + ni * 16 + l15;
            bg[ni] = *reinterpret_cast<const short8*>(&Bs[(kg * 128 + (row ^ (kg * 2))) * 8]);
        }
#pragma unroll
        for (int mi = 0; mi < 4; mi++)
#pragma unroll
            for (int ni = 0; ni < 4; ni++)
                acc[mi][ni] = mfma_bf16(af[mi], bg[ni], acc[mi][ni]);
    }
    asm volatile("s_nop 7\n\ts_nop 7");
#pragma unroll
    for (int mi = 0; mi < 4; mi++) {
#pragma unroll
        for (int ni = 0; ni < 4; ni++) {
            int col = n0 + wn + ni * 16 + l15;
#pragma unroll
            for (int r = 0; r < 4; r++) {
                int rowm = m0 + wm + mi * 16 + (lane >> 4) * 4 + r;
                size_t idx = (size_t)rowm * N + col;
                float v = acc[mi][ni][r];
                if (res) v += res[idx];
                C[idx] = v;
            }
        }
    }
}

// ---------------------------------------------------------------------------
// Top-k threshold gate. One block per row. Exact kth-largest via 32-bit
// binary search on sign-flipped float keys (matches jax top_k + ">= thr").
// Emits sparse (idx, score*gate) lists (sense_emit_full = ((x@E.T)*g)@W !)
// plus bare-gate column-sum atomics for the aux loss.
// ---------------------------------------------------------------------------
__global__ __launch_bounds__(256) void k_gate(const float* __restrict__ scores, int NC, int ksel,
                                              int row_off,
                                              const float* __restrict__ tau, int tau_stride, int tcol0,
                                              int two,
                                              int* __restrict__ sel,
                                              float* __restrict__ vA, float* __restrict__ vB,
                                              int* __restrict__ cnt,
                                              float* __restrict__ csA, float* __restrict__ csB,
                                              int cap) {
    extern __shared__ u32 keys[];
    __shared__ int   redi[4];
    __shared__ int   scnt;
    __shared__ int   sidx[CAPK];
    __shared__ float sraw[CAPK];
    int r = blockIdx.x, tid = threadIdx.x, wave = tid >> 6, lane = tid & 63;
    int t = row_off + r;
    const float* srow = scores + (size_t)r * NC;
    for (int c = tid; c < NC; c += 256) {
        u32 u = __float_as_uint(srow[c]);
        keys[c] = (u & 0x80000000u) ? ~u : (u | 0x80000000u);
    }
    if (tid == 0) scnt = 0;
    __syncthreads();

    u32 thr = 0;
    for (int b = 31; b >= 0; --b) {
        u32 cand = thr | (1u << b);
        int c = 0;
        for (int i = tid; i < NC; i += 256) c += (keys[i] >= cand) ? 1 : 0;
#pragma unroll
        for (int off = 32; off > 0; off >>= 1) c += __shfl_xor(c, off);
        __syncthreads();
        if (lane == 0) redi[wave] = c;
        __syncthreads();
        c = redi[0] + redi[1] + redi[2] + redi[3];
        if (c >= ksel) thr = cand;
    }
    __syncthreads();

    for (int i = tid; i < NC; i += 256) {
        if (keys[i] >= thr) {
            int p = atomicAdd(&scnt, 1);
            if (p < cap) {
                sidx[p] = i;
                u32 ky = keys[i];
                u32 uo = (ky & 0x80000000u) ? (ky & 0x7fffffffu) : ~ky;
                sraw[p] = __uint_as_float(uo);
            }
        }
    }
    __syncthreads();
    int n = scnt < cap ? scnt : cap;
    if (tid == 0) cnt[t] = n;
    if (wave != 0) return;

    float tA = tau[(size_t)t * tau_stride + tcol0];
    float tB = two ? tau[(size_t)t * tau_stride + tcol0 + 1] : 0.f;
    float sumA = 0.f, mxA = -1e30f, sumB = 0.f, mxB = -1e30f;
    for (int i = lane; i < n; i += 64) {
        float sv = sraw[i];
        float rA = sv - tA;
        float gA = rA > 0.f ? rA : 1e-8f * expf(rA);
        float eA = expf(gA) - 1.0f;            // match reference quantization
        sumA += eA; mxA = fmaxf(mxA, eA);
        if (two) {
            float rB = sv - tB;
            float gB = rB > 0.f ? rB : 1e-8f * expf(rB);
            float eB = expf(gB) - 1.0f;
            sumB += eB; mxB = fmaxf(mxB, eB);
        }
    }
#pragma unroll
    for (int off = 32; off > 0; off >>= 1) {
        sumA += __shfl_xor(sumA, off); mxA = fmaxf(mxA, __shfl_xor(mxA, off));
        sumB += __shfl_xor(sumB, off); mxB = fmaxf(mxB, __shfl_xor(mxB, off));
    }
    float fA = tanhf(mxA) / (sumA + 1e-8f);
    float fB = tanhf(mxB) / (sumB + 1e-8f);
    for (int i = lane; i < n; i += 64) {
        float sv = sraw[i]; int ci = sidx[i];
        float rA = sv - tA;
        float gA = rA > 0.f ? rA : 1e-8f * expf(rA);
        float ga = (expf(gA) - 1.0f) * fA;     // bare gate (aux loss)
        sel[(size_t)t * cap + i] = ci;
        vA[(size_t)t * cap + i] = ga * sv;     // emit weight = score * gate
        atomicAdd(&csA[ci], ga);
        if (two) {
            float rB = sv - tB;
            float gB = rB > 0.f ? rB : 1e-8f * expf(rB);
            float gb = (expf(gB) - 1.0f) * fB;
            vB[(size_t)t * cap + i] = gb * sv;
            atomicAdd(&csB[ci], gb);
        }
    }
}

// ---------------------------------------------------------------------------
// Sparse emits:  O[t] = sum_s val[s] * w[idx[s]]
// ---------------------------------------------------------------------------
__global__ __launch_bounds__(256) void k_gather2(const float* __restrict__ w,
                                                 const int* __restrict__ sel,
                                                 const float* __restrict__ vA,
                                                 const float* __restrict__ vB,
                                                 const int* __restrict__ cnt, int cap,
                                                 float* __restrict__ OA, float* __restrict__ OB) {
    __shared__ int   sI[CAPK];
    __shared__ float sA[CAPK];
    __shared__ float sB[CAPK];
    int t = blockIdx.x, tid = threadIdx.x;
    int n = cnt[t];
    if (tid < n) { sI[tid] = sel[(size_t)t * cap + tid]; sA[tid] = vA[(size_t)t * cap + tid]; sB[tid] = vB[(size_t)t * cap + tid]; }
    __syncthreads();
    float a0 = 0, a1 = 0, a2 = 0, a3 = 0, b0 = 0, b1 = 0, b2 = 0, b3 = 0;
    for (int s = 0; s < n; s++) {
        const float4 wv = reinterpret_cast<const float4*>(w + (size_t)sI[s] * DIM)[tid];
        float va = sA[s], vb = sB[s];
        a0 += va * wv.x; a1 += va * wv.y; a2 += va * wv.z; a3 += va * wv.w;
        b0 += vb * wv.x; b1 += vb * wv.y; b2 += vb * wv.z; b3 += vb * wv.w;
    }
    reinterpret_cast<float4*>(OA + (size_t)t * DIM)[tid] = make_float4(a0, a1, a2, a3);
    reinterpret_cast<float4*>(OB + (size_t)t * DIM)[tid] = make_float4(b0, b1, b2, b3);
}

__global__ __launch_bounds__(256) void k_gather1(const float* __restrict__ w,
                                                 const int* __restrict__ sel,
                                                 const float* __restrict__ vv,
                                                 const int* __restrict__ cnt, int cap,
                                                 float* __restrict__ O) {
    __shared__ int   sI[CAPK];
    __shared__ float sV[CAPK];
    int t = blockIdx.x, tid = threadIdx.x;
    int n = cnt[t];
    if (tid < n) { sI[tid] = sel[(size_t)t * cap + tid]; sV[tid] = vv[(size_t)t * cap + tid]; }
    __syncthreads();
    float a0 = 0, a1 = 0, a2 = 0, a3 = 0;
    for (int s = 0; s < n; s++) {
        const float4 wv = reinterpret_cast<const float4*>(w + (size_t)sI[s] * DIM)[tid];
        float va = sV[s];
        a0 += va * wv.x; a1 += va * wv.y; a2 += va * wv.z; a3 += va * wv.w;
    }
    reinterpret_cast<float4*>(O + (size_t)t * DIM)[tid] = make_float4(a0, a1, a2, a3);
}

// know emit fused with final residual: io[t] += sum val*w
__global__ __launch_bounds__(256) void k_gather_final(const float* __restrict__ w,
                                                      const int* __restrict__ sel,
                                                      const float* __restrict__ vv,
                                                      const int* __restrict__ cnt, int cap,
                                                      float* __restrict__ io) {
    __shared__ int   sI[CAPK];
    __shared__ float sV[CAPK];
    int t = blockIdx.x, tid = threadIdx.x;
    int n = cnt[t];
    if (tid < n) { sI[tid] = sel[(size_t)t * cap + tid]; sV[tid] = vv[(size_t)t * cap + tid]; }
    __syncthreads();
    float4 base = reinterpret_cast<const float4*>(io + (size_t)t * DIM)[tid];
    float a0 = base.x, a1 = base.y, a2 = base.z, a3 = base.w;
    for (int s = 0; s < n; s++) {
        const float4 wv = reinterpret_cast<const float4*>(w + (size_t)sI[s] * DIM)[tid];
        float va = sV[s];
        a0 += va * wv.x; a1 += va * wv.y; a2 += va * wv.z; a3 += va * wv.w;
    }
    reinterpret_cast<float4*>(io + (size_t)t * DIM)[tid] = make_float4(a0, a1, a2, a3);
}

// ---------------------------------------------------------------------------
// Causal flash attention (f32). Block = (b,h,16 q rows), 4 waves x 4 rows.
// QK^T: lane = key; PV: lane = dim. 65-float LDS stride => conflict-free.
// Output written directly as bf16 for the expand_O MFMA GEMM.
// ---------------------------------------------------------------------------
__global__ __launch_bounds__(256) void k_attn(const float* __restrict__ Q,
                                              const float* __restrict__ K,
                                              const float* __restrict__ V,
                                              u16* __restrict__ O) {
    __shared__ float Kt[64][65];
    __shared__ float Vt[64][65];
    __shared__ float qs[16][65];
    __shared__ float pbuf[4][4][64];
    int tid = threadIdx.x, wave = tid >> 6, lane = tid & 63;
    int q0 = blockIdx.x * 16, h = blockIdx.y, bb = blockIdx.z;
    size_t base = ((size_t)bb * SLEN) * DIM + (size_t)h * DH;
    {
        int r = tid >> 4, c = (tid & 15) * 4;
        const float4 qv = *reinterpret_cast<const float4*>(Q + base + (size_t)(q0 + r) * DIM + c);
        qs[r][c] = qv.x; qs[r][c + 1] = qv.y; qs[r][c + 2] = qv.z; qs[r][c + 3] = qv.w;
    }
    float m[4], l[4], acc[4];
#pragma unroll
    for (int i = 0; i < 4; i++) { m[i] = -1e30f; l[i] = 0.f; acc[i] = 0.f; }
    int nchunk = (q0 + 16 + 63) >> 6;
    const float* q0p = qs[wave * 4 + 0];
    const float* q1p = qs[wave * 4 + 1];
    const float* q2p = qs[wave * 4 + 2];
    const float* q3p = qs[wave * 4 + 3];
    for (int kc = 0; kc < nchunk; kc++) {
        __syncthreads();
        {
            int r = tid >> 2, c0 = (tid & 3) * 16;
            const float* kp = K + base + (size_t)(kc * 64 + r) * DIM + c0;
            const float* vp = V + base + (size_t)(kc * 64 + r) * DIM + c0;
#pragma unroll
            for (int j = 0; j < 4; j++) {
                const float4 kv = *reinterpret_cast<const float4*>(kp + j * 4);
                Kt[r][c0 + j * 4 + 0] = kv.x; Kt[r][c0 + j * 4 + 1] = kv.y;
                Kt[r][c0 + j * 4 + 2] = kv.z; Kt[r][c0 + j * 4 + 3] = kv.w;
                const float4 vv = *reinterpret_cast<const float4*>(vp + j * 4);
                Vt[r][c0 + j * 4 + 0] = vv.x; Vt[r][c0 + j * 4 + 1] = vv.y;
                Vt[r][c0 + j * 4 + 2] = vv.z; Vt[r][c0 + j * 4 + 3] = vv.w;
            }
        }
        __syncthreads();
        float s0 = 0, s1 = 0, s2 = 0, s3 = 0;
#pragma unroll 8
        for (int d = 0; d < 64; d++) {
            float kd = Kt[lane][d];
            s0 += q0p[d] * kd; s1 += q1p[d] * kd; s2 += q2p[d] * kd; s3 += q3p[d] * kd;
        }
        int kj = kc * 64 + lane;
        float sv[4] = {s0, s1, s2, s3};
#pragma unroll
        for (int i = 0; i < 4; i++) {
            int rq = q0 + wave * 4 + i;
            float s = sv[i] * 0.125f;
            if (kj > rq) s = -1e30f;
            float mx = s;
#pragma unroll
            for (int off = 32; off > 0; off >>= 1) mx = fmaxf(mx, __shfl_xor(mx, off));
            float mnew = fmaxf(m[i], mx);
            float al = __expf(m[i] - mnew);
            float p  = __expf(s - mnew);
            float ps = p;
#pragma unroll
            for (int off = 32; off > 0; off >>= 1) ps += __shfl_xor(ps, off);
            m[i] = mnew;
            l[i] = l[i] * al + ps;
            acc[i] *= al;
            pbuf[wave][i][lane] = p;
        }
#pragma unroll 4
        for (int j = 0; j < 64; j++) {
            float vj = Vt[j][lane];
            acc[0] += pbuf[wave][0][j] * vj;
            acc[1] += pbuf[wave][1][j] * vj;
            acc[2] += pbuf[wave][2][j] * vj;
            acc[3] += pbuf[wave][3][j] * vj;
        }
    }
#pragma unroll
    for (int i = 0; i < 4; i++) {
        float o = acc[i] / l[i];
        O[base + (size_t)(q0 + wave * 4 + i) * DIM + lane] = f2bf(o);
    }
}

// ---------------------------------------------------------------------------
// aux = sum over gate columns of (colsum/T - 1/N)^2 * N
// ---------------------------------------------------------------------------
__global__ __launch_bounds__(256) void k_aux(const float* __restrict__ cs,
                                             float* __restrict__ out_aux) {
    __shared__ float red[4];
    int gtid = blockIdx.x * 256 + threadIdx.x;
    float acc = 0.f;
    for (int i = gtid; i < 3 * 4096 + 8192; i += gridDim.x * 256) {
        float mean = cs[i] * (1.0f / 4096.0f);
        float tN, Nf;
        if (i < 12288) { tN = 1.0f / 4096.0f; Nf = 4096.0f; }
        else           { tN = 1.0f / 8192.0f; Nf = 8192.0f; }
        float d = mean - tN;
        acc += d * d * Nf;
    }
    acc = blockReduceF(acc, red, threadIdx.x >> 6, threadIdx.x & 63);
    if (threadIdx.x == 0) atomicAdd(out_aux, acc);
}

// ---------------------------------------------------------------------------
extern "C" void kernel_launch(void* const* d_in, const int* in_sizes, int n_in,
                              void* d_out, int out_size, void* d_ws, size_t ws_size,
                              hipStream_t stream) {
    const float* x         = (const float*)d_in[0];
    const float* qk_emb    = (const float*)d_in[1];
    const float* qk_w      = (const float*)d_in[2];
    const float* v_emb     = (const float*)d_in[3];
    const float* v_w       = (const float*)d_in[4];
    const float* know_emb  = (const float*)d_in[5];
    const float* know_w    = (const float*)d_in[6];
    const float* tau_attn_k = (const float*)d_in[7];
    const float* tau_attn_b = (const float*)d_in[8];
    const float* tau_know_k = (const float*)d_in[9];
    const float* tau_know_b = (const float*)d_in[10];
    const float* expand_O  = (const float*)d_in[11];
    const float* ln1_s     = (const float*)d_in[12];
    const float* ln1_b     = (const float*)d_in[13];
    const float* ln2_s     = (const float*)d_in[14];
    const float* ln2_b     = (const float*)d_in[15];
    float* out = (float*)d_out;
    char*  ws  = (char*)d_ws;

    // workspace layout (bytes)
    u16*   nrm_bf   = (u16*)(ws + 0);                 //  8 MB
    u16*   qkemb_bf = (u16*)(ws + 8388608);           //  8 MB
    u16*   vemb_bf  = (u16*)(ws + 16777216);          //  8 MB
    u16*   knemb_bf = (u16*)(ws + 25165824);          // 16 MB
    u16*   expT_bf  = (u16*)(ws + 41943040);          //  2 MB
    u16*   attn_bf  = (u16*)(ws + 44040192);          //  8 MB
    float* scores   = (float*)(ws + 52428800);        // 64 MB
    float* Qb       = (float*)(ws + 119537664);       // 16 MB
    float* Kb       = (float*)(ws + 136314880);       // 16 MB
    float* Vb       = (float*)(ws + 153092096);       // 16 MB
    int*   selQK    = (int*)(ws + 169869312);
    float* valQ     = (float*)(ws + 170655744);
    float* valK     = (float*)(ws + 171442176);
    int*   selV     = (int*)(ws + 172228608);
    float* valV     = (float*)(ws + 173015040);
    int*   selKn    = (int*)(ws + 173801472);
    float* valKn    = (float*)(ws + 175374336);
    int*   cntQK    = (int*)(ws + 176947200);
    int*   cntV     = (int*)(ws + 176963584);
    int*   cntKn    = (int*)(ws + 176979968);
    float* tauA     = (float*)(ws + 176996352);       // [T][3]
    float* tauKn    = (float*)(ws + 177045504);       // [T]
    float* colsum   = (float*)(ws + 177061888);       // 20480 floats: Q,K,V,Kn
    const size_t WS_NEEDED = 177143808;
    if (ws_size < WS_NEEDED) return;   // workspace too small — bail cleanly

    float* colQ = colsum, *colK = colsum + 4096, *colV = colsum + 8192, *colKn = colsum + 12288;

    hipMemsetAsync(colsum, 0, 20480 * sizeof(float), stream);
    hipMemsetAsync(out + (size_t)TOK * DIM, 0, sizeof(float), stream);

    // bf16 conversions
    k_f32_to_bf16<<<1024, 256, 0, stream>>>(qk_emb,  qkemb_bf, NQK * DIM / 4);
    k_f32_to_bf16<<<1024, 256, 0, stream>>>(v_emb,   vemb_bf,  NV * DIM / 4);
    k_f32_to_bf16<<<2048, 256, 0, stream>>>(know_emb, knemb_bf, NKN * DIM / 4);
    k_transpose_bf16<<<dim3(32, 32), 256, 0, stream>>>(expand_O, expT_bf);

    // LN1 + tau(3)
    k_ln_tau<<<TOK, 256, 0, stream>>>(x, ln1_s, ln1_b, tau_attn_k, tau_attn_b, 3, nrm_bf, tauA);

    // scores_qk + gate (g_Q, g_K share selection)
    k_gemm_bt<<<dim3(NQK / 128, TOK / 128), 256, 0, stream>>>(nrm_bf, qkemb_bf, scores, TOK, NQK, DIM, nullptr);
    k_gate<<<TOK, 256, NQK * sizeof(u32), stream>>>(scores, NQK, 32, 0, tauA, 3, 0, 1,
                                                    selQK, valQ, valK, cntQK, colQ, colK, CAPA);
    // scores_v + gate (g_V)
    k_gemm_bt<<<dim3(NV / 128, TOK / 128), 256, 0, stream>>>(nrm_bf, vemb_bf, scores, TOK, NV, DIM, nullptr);
    k_gate<<<TOK, 256, NV * sizeof(u32), stream>>>(scores, NV, 32, 0, tauA, 3, 2, 0,
                                                   selV, valV, nullptr, cntV, colV, nullptr, CAPA);

    // sparse emits Q, K, V
    k_gather2<<<TOK, 256, 0, stream>>>(qk_w, selQK, valQ, valK, cntQK, CAPA, Qb, Kb);
    k_gather1<<<TOK, 256, 0, stream>>>(v_w, selV, valV, cntV, CAPA, Vb);

    // causal MHA -> bf16
    k_attn<<<dim3(SLEN / 16, NH, 2), 256, 0, stream>>>(Qb, Kb, Vb, attn_bf);

    // out @ expand_O + residual x  -> x1 (stored in d_out)
    k_gemm_bt<<<dim3(DIM / 128, TOK / 128), 256, 0, stream>>>(attn_bf, expT_bf, out, TOK, DIM, DIM, x);

    // LN2 + tau_know
    k_ln_tau<<<TOK, 256, 0, stream>>>(out, ln2_s, ln2_b, tau_know_k, tau_know_b, 1, nrm_bf, tauKn);

    // know scores + gate, in 2 token chunks (scores buffer = 64 MB)
    for (int c = 0; c < 2; c++) {
        k_gemm_bt<<<dim3(NKN / 128, 2048 / 128), 256, 0, stream>>>(
            nrm_bf + (size_t)c * 2048 * DIM, knemb_bf, scores, 2048, NKN, DIM, nullptr);
        k_gate<<<2048, 256, NKN * sizeof(u32), stream>>>(scores, NKN, 64, c * 2048, tauKn, 1, 0, 0,
                                                         selKn, valKn, nullptr, cntKn, colKn, nullptr, CAPK);
    }

    // know emit + final residual (in place on d_out)
    k_gather_final<<<TOK, 256, 0, stream>>>(know_w, selKn, valKn, cntKn, CAPK, out);

    // aux scalar
    k_aux<<<20, 256, 0, stream>>>(colsum, out + (size_t)TOK * DIM);
}

// Round 3
// 958.131 us; speedup vs baseline: 1.8561x; 1.8561x over previous
//
#include <hip/hip_runtime.h>

// ---------------------------------------------------------------------------
// Problem constants (fixed by the reference)
// ---------------------------------------------------------------------------
#define TOK   4096      // B*S
#define DIM   1024
#define NQK   4096
#define NV    4096
#define NKN   8192
#define SLEN  2048
#define NH    16
#define DH    64
#define CAPA  48        // capacity for k=32 gates (slack for ties)
#define CAPK  96        // capacity for k=64 gate
#define APAD  72        // attn LDS row pad (bf16 elems): 144B keeps b128 align

typedef float  f32x4  __attribute__((ext_vector_type(4)));
typedef short  short8 __attribute__((ext_vector_type(8)));
typedef unsigned int  u32;
typedef unsigned short u16;

__device__ __forceinline__ u16 f2bf(float f) {
    u32 u = __float_as_uint(f);
    u32 r = (u + 0x7fffu + ((u >> 16) & 1u)) >> 16;
    return (u16)r;
}

__device__ __forceinline__ f32x4 mfma_bf16(short8 a, short8 b, f32x4 c) {
    asm volatile("v_mfma_f32_16x16x32_bf16 %0, %1, %2, %0"
                 : "+v"(c) : "v"(a), "v"(b));
    return c;
}

__device__ __forceinline__ float blockReduceF(float v, float* red, int wave, int lane) {
#pragma unroll
    for (int off = 32; off > 0; off >>= 1) v += __shfl_xor(v, off);
    __syncthreads();
    if (lane == 0) red[wave] = v;
    __syncthreads();
    return red[0] + red[1] + red[2] + red[3];
}

// ---------------------------------------------------------------------------
// f32 -> bf16 conversion (grid-stride, float4)
// ---------------------------------------------------------------------------
__global__ __launch_bounds__(256) void k_f32_to_bf16(const float* __restrict__ in,
                                                     u16* __restrict__ out, int n4) {
    int i = blockIdx.x * 256 + threadIdx.x;
    int stride = gridDim.x * 256;
    for (; i < n4; i += stride) {
        float4 v = reinterpret_cast<const float4*>(in)[i];
        ushort4 o = make_ushort4(f2bf(v.x), f2bf(v.y), f2bf(v.z), f2bf(v.w));
        reinterpret_cast<ushort4*>(out)[i] = o;
    }
}

// transpose 1024x1024 f32 -> bf16 (out[n][k] = in[k][n])
__global__ __launch_bounds__(256) void k_transpose_bf16(const float* __restrict__ in,
                                                        u16* __restrict__ out) {
    __shared__ float tile[32][33];
    int bx = blockIdx.x * 32;   // col of in
    int by = blockIdx.y * 32;   // row of in
    int tx = threadIdx.x & 31;
    int ty = threadIdx.x >> 5;  // 0..7
    for (int r = ty; r < 32; r += 8)
        tile[r][tx] = in[(size_t)(by + r) * DIM + bx + tx];
    __syncthreads();
    for (int r = ty; r < 32; r += 8)
        out[(size_t)(bx + r) * DIM + by + tx] = f2bf(tile[tx][r]);
}

// ---------------------------------------------------------------------------
// LayerNorm + tau projection; writes bf16 normed + f32 tau[t][ntau]
// ---------------------------------------------------------------------------
__global__ __launch_bounds__(256) void k_ln_tau(const float* __restrict__ x,
                                                const float* __restrict__ sc,
                                                const float* __restrict__ bi,
                                                const float* __restrict__ tauk,
                                                const float* __restrict__ taub,
                                                int ntau,
                                                u16* __restrict__ nrm,
                                                float* __restrict__ tau_out) {
    __shared__ float red[4];
    int t = blockIdx.x, tid = threadIdx.x, wave = tid >> 6, lane = tid & 63;
    const float4 xv = reinterpret_cast<const float4*>(x + (size_t)t * DIM)[tid];
    float s = xv.x + xv.y + xv.z + xv.w;
    s = blockReduceF(s, red, wave, lane);
    float mean = s * (1.0f / DIM);
    float d0 = xv.x - mean, d1 = xv.y - mean, d2 = xv.z - mean, d3 = xv.w - mean;
    float ss = d0 * d0 + d1 * d1 + d2 * d2 + d3 * d3;
    ss = blockReduceF(ss, red, wave, lane);
    float rstd = rsqrtf(ss * (1.0f / DIM) + 1e-6f);
    const float4 scv = reinterpret_cast<const float4*>(sc)[tid];
    const float4 biv = reinterpret_cast<const float4*>(bi)[tid];
    float n0 = d0 * rstd * scv.x + biv.x;
    float n1 = d1 * rstd * scv.y + biv.y;
    float n2 = d2 * rstd * scv.z + biv.z;
    float n3 = d3 * rstd * scv.w + biv.w;
    ushort4 o = make_ushort4(f2bf(n0), f2bf(n1), f2bf(n2), f2bf(n3));
    reinterpret_cast<ushort4*>(nrm + (size_t)t * DIM)[tid] = o;
    int d = tid * 4;
    for (int j = 0; j < ntau; j++) {
        float p = n0 * tauk[(size_t)(d + 0) * ntau + j] + n1 * tauk[(size_t)(d + 1) * ntau + j]
                + n2 * tauk[(size_t)(d + 2) * ntau + j] + n3 * tauk[(size_t)(d + 3) * ntau + j];
        p = blockReduceF(p, red, wave, lane);
        if (tid == 0) tau_out[(size_t)t * ntau + j] = p + taub[j];
    }
}

// ---------------------------------------------------------------------------
// C[M][N] = A[M][K] @ B[N][K]^T   (bf16 in, f32 out), optional residual fuse
// 128x128 tile, 4 waves, 16x16x32 MFMA, XOR-swizzled LDS (2-way, free)
// ---------------------------------------------------------------------------
__global__ __launch_bounds__(256) void k_gemm_bt(const u16* __restrict__ A,
                                                 const u16* __restrict__ B,
                                                 float* __restrict__ C,
                                                 int M, int N, int K,
                                                 const float* __restrict__ res) {
    __shared__ __align__(16) u16 As[4096];
    __shared__ __align__(16) u16 Bs[4096];
    int tid = threadIdx.x;
    int wave = tid >> 6, lane = tid & 63;
    int m0 = blockIdx.y * 128, n0 = blockIdx.x * 128;
    int srow = tid >> 2, skg = tid & 3;
    int wm = (wave >> 1) * 64, wn = (wave & 1) * 64;
    int kg = lane >> 4, l15 = lane & 15;
    f32x4 acc[4][4];
#pragma unroll
    for (int i = 0; i < 4; i++)
#pragma unroll
        for (int j = 0; j < 4; j++) { f32x4 z = {0.f, 0.f, 0.f, 0.f}; acc[i][j] = z; }

    for (int k0 = 0; k0 < K; k0 += 32) {
        __syncthreads();
#pragma unroll
        for (int i = 0; i < 2; i++) {
            int row = srow + i * 64;
            int ch = skg * 128 + (row ^ (skg * 2));
            *reinterpret_cast<uint4*>(&As[ch * 8]) =
                *reinterpret_cast<const uint4*>(A + (size_t)(m0 + row) * K + k0 + skg * 8);
            *reinterpret_cast<uint4*>(&Bs[ch * 8]) =
                *reinterpret_cast<const uint4*>(B + (size_t)(n0 + row) * K + k0 + skg * 8);
        }
        __syncthreads();
        short8 af[4], bg[4];
#pragma unroll
        for (int mi = 0; mi < 4; mi++) {
            int row = wm + mi * 16 + l15;
            af[mi] = *reinterpret_cast<const short8*>(&As[(kg * 128 + (row ^ (kg * 2))) * 8]);
        }
#pragma unroll
        for (int ni = 0; ni < 4; ni++) {
            int row = wn + ni * 16 + l15;
            bg[ni] = *reinterpret_cast<const short8*>(&Bs[(kg * 128 + (row ^ (kg * 2))) * 8]);
        }
#pragma unroll
        for (int mi = 0; mi < 4; mi++)
#pragma unroll
            for (int ni = 0; ni < 4; ni++)
                acc[mi][ni] = mfma_bf16(af[mi], bg[ni], acc[mi][ni]);
    }
    asm volatile("s_nop 7\n\ts_nop 7");
#pragma unroll
    for (int mi = 0; mi < 4; mi++) {
#pragma unroll
        for (int ni = 0; ni < 4; ni++) {
            int col = n0 + wn + ni * 16 + l15;
#pragma unroll
            for (int r = 0; r < 4; r++) {
                int rowm = m0 + wm + mi * 16 + (lane >> 4) * 4 + r;
                size_t idx = (size_t)rowm * N + col;
                float v = acc[mi][ni][r];
                if (res) v += res[idx];
                C[idx] = v;
            }
        }
    }
}

// ---------------------------------------------------------------------------
// Top-k threshold gate. One block per row. Exact kth-largest via 32-bit
// binary search on sign-flipped float keys (matches jax top_k + ">= thr").
// Emits sparse (idx, score*gate) lists (sense_emit_full = ((x@E.T)*g)@W !)
// plus bare-gate column-sum atomics for the aux loss.
// ---------------------------------------------------------------------------
__global__ __launch_bounds__(256) void k_gate(const float* __restrict__ scores, int NC, int ksel,
                                              int row_off,
                                              const float* __restrict__ tau, int tau_stride, int tcol0,
                                              int two,
                                              int* __restrict__ sel,
                                              float* __restrict__ vA, float* __restrict__ vB,
                                              int* __restrict__ cnt,
                                              float* __restrict__ csA, float* __restrict__ csB,
                                              int cap) {
    extern __shared__ u32 keys[];
    __shared__ int   redi[4];
    __shared__ int   scnt;
    __shared__ int   sidx[CAPK];
    __shared__ float sraw[CAPK];
    int r = blockIdx.x, tid = threadIdx.x, wave = tid >> 6, lane = tid & 63;
    int t = row_off + r;
    const float* srow = scores + (size_t)r * NC;
    for (int c = tid; c < NC; c += 256) {
        u32 u = __float_as_uint(srow[c]);
        keys[c] = (u & 0x80000000u) ? ~u : (u | 0x80000000u);
    }
    if (tid == 0) scnt = 0;
    __syncthreads();

    u32 thr = 0;
    for (int b = 31; b >= 0; --b) {
        u32 cand = thr | (1u << b);
        int c = 0;
        for (int i = tid; i < NC; i += 256) c += (keys[i] >= cand) ? 1 : 0;
#pragma unroll
        for (int off = 32; off > 0; off >>= 1) c += __shfl_xor(c, off);
        __syncthreads();
        if (lane == 0) redi[wave] = c;
        __syncthreads();
        c = redi[0] + redi[1] + redi[2] + redi[3];
        if (c >= ksel) thr = cand;
    }
    __syncthreads();

    for (int i = tid; i < NC; i += 256) {
        if (keys[i] >= thr) {
            int p = atomicAdd(&scnt, 1);
            if (p < cap) {
                sidx[p] = i;
                u32 ky = keys[i];
                u32 uo = (ky & 0x80000000u) ? (ky & 0x7fffffffu) : ~ky;
                sraw[p] = __uint_as_float(uo);
            }
        }
    }
    __syncthreads();
    int n = scnt < cap ? scnt : cap;
    if (tid == 0) cnt[t] = n;
    if (wave != 0) return;

    float tA = tau[(size_t)t * tau_stride + tcol0];
    float tB = two ? tau[(size_t)t * tau_stride + tcol0 + 1] : 0.f;
    float sumA = 0.f, mxA = -1e30f, sumB = 0.f, mxB = -1e30f;
    for (int i = lane; i < n; i += 64) {
        float sv = sraw[i];
        float rA = sv - tA;
        float gA = rA > 0.f ? rA : 1e-8f * expf(rA);
        float eA = expf(gA) - 1.0f;            // match reference quantization
        sumA += eA; mxA = fmaxf(mxA, eA);
        if (two) {
            float rB = sv - tB;
            float gB = rB > 0.f ? rB : 1e-8f * expf(rB);
            float eB = expf(gB) - 1.0f;
            sumB += eB; mxB = fmaxf(mxB, eB);
        }
    }
#pragma unroll
    for (int off = 32; off > 0; off >>= 1) {
        sumA += __shfl_xor(sumA, off); mxA = fmaxf(mxA, __shfl_xor(mxA, off));
        sumB += __shfl_xor(sumB, off); mxB = fmaxf(mxB, __shfl_xor(mxB, off));
    }
    float fA = tanhf(mxA) / (sumA + 1e-8f);
    float fB = tanhf(mxB) / (sumB + 1e-8f);
    for (int i = lane; i < n; i += 64) {
        float sv = sraw[i]; int ci = sidx[i];
        float rA = sv - tA;
        float gA = rA > 0.f ? rA : 1e-8f * expf(rA);
        float ga = (expf(gA) - 1.0f) * fA;     // bare gate (aux loss)
        sel[(size_t)t * cap + i] = ci;
        vA[(size_t)t * cap + i] = ga * sv;     // emit weight = score * gate
        atomicAdd(&csA[ci], ga);
        if (two) {
            float rB = sv - tB;
            float gB = rB > 0.f ? rB : 1e-8f * expf(rB);
            float gb = (expf(gB) - 1.0f) * fB;
            vB[(size_t)t * cap + i] = gb * sv;
            atomicAdd(&csB[ci], gb);
        }
    }
}

// ---------------------------------------------------------------------------
// Sparse emits (bf16 out for attention):  O[t] = sum_s val[s] * w[idx[s]]
// ---------------------------------------------------------------------------
__global__ __launch_bounds__(256) void k_gather2(const float* __restrict__ w,
                                                 const int* __restrict__ sel,
                                                 const float* __restrict__ vA,
                                                 const float* __restrict__ vB,
                                                 const int* __restrict__ cnt, int cap,
                                                 u16* __restrict__ OA, u16* __restrict__ OB) {
    __shared__ int   sI[CAPK];
    __shared__ float sA[CAPK];
    __shared__ float sB[CAPK];
    int t = blockIdx.x, tid = threadIdx.x;
    int n = cnt[t];
    if (tid < n) { sI[tid] = sel[(size_t)t * cap + tid]; sA[tid] = vA[(size_t)t * cap + tid]; sB[tid] = vB[(size_t)t * cap + tid]; }
    __syncthreads();
    float a0 = 0, a1 = 0, a2 = 0, a3 = 0, b0 = 0, b1 = 0, b2 = 0, b3 = 0;
    for (int s = 0; s < n; s++) {
        const float4 wv = reinterpret_cast<const float4*>(w + (size_t)sI[s] * DIM)[tid];
        float va = sA[s], vb = sB[s];
        a0 += va * wv.x; a1 += va * wv.y; a2 += va * wv.z; a3 += va * wv.w;
        b0 += vb * wv.x; b1 += vb * wv.y; b2 += vb * wv.z; b3 += vb * wv.w;
    }
    reinterpret_cast<ushort4*>(OA + (size_t)t * DIM)[tid] = make_ushort4(f2bf(a0), f2bf(a1), f2bf(a2), f2bf(a3));
    reinterpret_cast<ushort4*>(OB + (size_t)t * DIM)[tid] = make_ushort4(f2bf(b0), f2bf(b1), f2bf(b2), f2bf(b3));
}

__global__ __launch_bounds__(256) void k_gather1(const float* __restrict__ w,
                                                 const int* __restrict__ sel,
                                                 const float* __restrict__ vv,
                                                 const int* __restrict__ cnt, int cap,
                                                 u16* __restrict__ O) {
    __shared__ int   sI[CAPK];
    __shared__ float sV[CAPK];
    int t = blockIdx.x, tid = threadIdx.x;
    int n = cnt[t];
    if (tid < n) { sI[tid] = sel[(size_t)t * cap + tid]; sV[tid] = vv[(size_t)t * cap + tid]; }
    __syncthreads();
    float a0 = 0, a1 = 0, a2 = 0, a3 = 0;
    for (int s = 0; s < n; s++) {
        const float4 wv = reinterpret_cast<const float4*>(w + (size_t)sI[s] * DIM)[tid];
        float va = sV[s];
        a0 += va * wv.x; a1 += va * wv.y; a2 += va * wv.z; a3 += va * wv.w;
    }
    reinterpret_cast<ushort4*>(O + (size_t)t * DIM)[tid] = make_ushort4(f2bf(a0), f2bf(a1), f2bf(a2), f2bf(a3));
}

// know emit fused with final residual: io[t] += sum val*w
__global__ __launch_bounds__(256) void k_gather_final(const float* __restrict__ w,
                                                      const int* __restrict__ sel,
                                                      const float* __restrict__ vv,
                                                      const int* __restrict__ cnt, int cap,
                                                      float* __restrict__ io) {
    __shared__ int   sI[CAPK];
    __shared__ float sV[CAPK];
    int t = blockIdx.x, tid = threadIdx.x;
    int n = cnt[t];
    if (tid < n) { sI[tid] = sel[(size_t)t * cap + tid]; sV[tid] = vv[(size_t)t * cap + tid]; }
    __syncthreads();
    float4 base = reinterpret_cast<const float4*>(io + (size_t)t * DIM)[tid];
    float a0 = base.x, a1 = base.y, a2 = base.z, a3 = base.w;
    for (int s = 0; s < n; s++) {
        const float4 wv = reinterpret_cast<const float4*>(w + (size_t)sI[s] * DIM)[tid];
        float va = sV[s];
        a0 += va * wv.x; a1 += va * wv.y; a2 += va * wv.z; a3 += va * wv.w;
    }
    reinterpret_cast<float4*>(io + (size_t)t * DIM)[tid] = make_float4(a0, a1, a2, a3);
}

// ---------------------------------------------------------------------------
// Causal flash attention, bf16 MFMA (16x16x32).
// Block = 256 thr / 4 waves, one (b,h), 64 q rows (16 per wave).
// K staged [key][dim] pad-72; V staged transposed [dim][key] with 8-block
// rotation swizzle; P routed per-wave through LDS (C-layout -> A-fragment).
// Grid (h, b, qtile) so causal load imbalance spreads across CUs.
// ---------------------------------------------------------------------------
__global__ __launch_bounds__(256) void k_attn(const u16* __restrict__ Q,
                                              const u16* __restrict__ K,
                                              const u16* __restrict__ V,
                                              u16* __restrict__ O) {
    __shared__ __align__(16) u16 Qs[64 * APAD];
    __shared__ __align__(16) u16 Ks[64 * APAD];
    __shared__ __align__(16) u16 Vt[64 * APAD];
    __shared__ __align__(16) u16 Ps[4][16 * APAD];
    int tid = threadIdx.x, wave = tid >> 6, lane = tid & 63;
    int h = blockIdx.x, bb = blockIdx.y, qt = blockIdx.z;
    int q0 = qt * 64;
    size_t base = ((size_t)bb * SLEN) * DIM + (size_t)h * DH;
    int sr = tid >> 2, sc = (tid & 3) * 16;     // staging row (0..63), col (0/16/32/48)
    int g = lane >> 4, l15 = lane & 15;

    // stage Q tile once
    {
        const u16* qp = Q + base + (size_t)(q0 + sr) * DIM + sc;
        *reinterpret_cast<short8*>(&Qs[sr * APAD + sc])     = *reinterpret_cast<const short8*>(qp);
        *reinterpret_cast<short8*>(&Qs[sr * APAD + sc + 8]) = *reinterpret_cast<const short8*>(qp + 8);
    }
    __syncthreads();
    short8 qa0 = *reinterpret_cast<const short8*>(&Qs[(wave * 16 + l15) * APAD + g * 8]);
    short8 qa1 = *reinterpret_cast<const short8*>(&Qs[(wave * 16 + l15) * APAD + 32 + g * 8]);

    float m[4], l[4];
    f32x4 oacc[4];
#pragma unroll
    for (int i = 0; i < 4; i++) {
        m[i] = -1e30f; l[i] = 0.f;
        f32x4 z = {0.f, 0.f, 0.f, 0.f}; oacc[i] = z;
    }
    u16* pw = &Ps[wave][0];

    for (int kc = 0; kc <= qt; kc++) {
        __syncthreads();
        // ---- stage K [key][dim] and V transposed [dim][key] ----
        {
            const u16* kp = K + base + (size_t)(kc * 64 + sr) * DIM + sc;
            *reinterpret_cast<short8*>(&Ks[sr * APAD + sc])     = *reinterpret_cast<const short8*>(kp);
            *reinterpret_cast<short8*>(&Ks[sr * APAD + sc + 8]) = *reinterpret_cast<const short8*>(kp + 8);
            const u16* vp = V + base + (size_t)(kc * 64 + sr) * DIM + sc;
            short8 w0 = *reinterpret_cast<const short8*>(vp);
            short8 w1 = *reinterpret_cast<const short8*>(vp + 8);
            const u16* w0p = reinterpret_cast<const u16*>(&w0);
            const u16* w1p = reinterpret_cast<const u16*>(&w1);
#pragma unroll
            for (int j = 0; j < 16; j++) {
                int d = sc + j;
                int phys = (((sr >> 3) + d + (d >> 4)) & 7);   // rotate key-blocks per dim
                Vt[d * APAD + phys * 8 + (sr & 7)] = (j < 8) ? w0p[j] : w1p[j - 8];
            }
        }
        __syncthreads();

        // ---- QK^T: 8 MFMAs -> s4[ks] (q_local = wave*16 + g*4 + r, key = ks*16 + l15)
        f32x4 s4[4];
#pragma unroll
        for (int ks = 0; ks < 4; ks++) {
            f32x4 z = {0.f, 0.f, 0.f, 0.f}; s4[ks] = z;
            short8 kb0 = *reinterpret_cast<const short8*>(&Ks[(ks * 16 + l15) * APAD + g * 8]);
            short8 kb1 = *reinterpret_cast<const short8*>(&Ks[(ks * 16 + l15) * APAD + 32 + g * 8]);
            s4[ks] = mfma_bf16(qa0, kb0, s4[ks]);
            s4[ks] = mfma_bf16(qa1, kb1, s4[ks]);
        }
        asm volatile("s_nop 7\n\ts_nop 7");   // MFMA -> VALU read hazard

        // ---- scale + causal mask ----
        int key_base = kc * 64 + l15;
#pragma unroll
        for (int ks = 0; ks < 4; ks++) {
            int key = key_base + ks * 16;
#pragma unroll
            for (int r = 0; r < 4; r++) {
                int q_abs = q0 + wave * 16 + g * 4 + r;
                float sv = s4[ks][r] * 0.125f;
                s4[ks][r] = (key > q_abs) ? -1e30f : sv;
            }
        }

        // ---- online softmax per q-row; write P (bf16) to per-wave LDS ----
#pragma unroll
        for (int r = 0; r < 4; r++) {
            float mx = fmaxf(fmaxf(s4[0][r], s4[1][r]), fmaxf(s4[2][r], s4[3][r]));
            mx = fmaxf(mx, __shfl_xor(mx, 1));
            mx = fmaxf(mx, __shfl_xor(mx, 2));
            mx = fmaxf(mx, __shfl_xor(mx, 4));
            mx = fmaxf(mx, __shfl_xor(mx, 8));
            float mnew = fmaxf(m[r], mx);
            float al = __expf(m[r] - mnew);
            m[r] = mnew;
            float p0 = __expf(s4[0][r] - mnew);
            float p1 = __expf(s4[1][r] - mnew);
            float p2 = __expf(s4[2][r] - mnew);
            float p3 = __expf(s4[3][r] - mnew);
            float ps = p0 + p1 + p2 + p3;
            ps += __shfl_xor(ps, 1);
            ps += __shfl_xor(ps, 2);
            ps += __shfl_xor(ps, 4);
            ps += __shfl_xor(ps, 8);
            l[r] = l[r] * al + ps;
#pragma unroll
            for (int ds_ = 0; ds_ < 4; ds_++) oacc[ds_][r] *= al;
            int row = g * 4 + r;
            pw[row * APAD +  0 + l15] = f2bf(p0);
            pw[row * APAD + 16 + l15] = f2bf(p1);
            pw[row * APAD + 32 + l15] = f2bf(p2);
            pw[row * APAD + 48 + l15] = f2bf(p3);
        }

        // ---- PV: read P as A-fragments, V^T as B-fragments; 8 MFMAs ----
        short8 pa0 = *reinterpret_cast<const short8*>(&pw[l15 * APAD + g * 8]);
        short8 pa1 = *reinterpret_cast<const short8*>(&pw[l15 * APAD + 32 + g * 8]);
#pragma unroll
        for (int dsub = 0; dsub < 4; dsub++) {
            int d = dsub * 16 + l15;
            int rot = d + (d >> 4);
            short8 vb0 = *reinterpret_cast<const short8*>(&Vt[d * APAD + (((0 + g) + rot) & 7) * 8]);
            short8 vb1 = *reinterpret_cast<const short8*>(&Vt[d * APAD + (((4 + g) + rot) & 7) * 8]);
            oacc[dsub] = mfma_bf16(pa0, vb0, oacc[dsub]);
            oacc[dsub] = mfma_bf16(pa1, vb1, oacc[dsub]);
        }
    }
    asm volatile("s_nop 7\n\ts_nop 7");       // MFMA -> VALU read hazard

    // ---- epilogue: O = oacc / l, bf16 ----
#pragma unroll
    for (int r = 0; r < 4; r++) {
        float inv = 1.0f / l[r];
        int row = q0 + wave * 16 + g * 4 + r;
#pragma unroll
        for (int dsub = 0; dsub < 4; dsub++) {
            O[base + (size_t)row * DIM + dsub * 16 + l15] = f2bf(oacc[dsub][r] * inv);
        }
    }
}

// ---------------------------------------------------------------------------
// aux = sum over gate columns of (colsum/T - 1/N)^2 * N
// ---------------------------------------------------------------------------
__global__ __launch_bounds__(256) void k_aux(const float* __restrict__ cs,
                                             float* __restrict__ out_aux) {
    __shared__ float red[4];
    int gtid = blockIdx.x * 256 + threadIdx.x;
    float acc = 0.f;
    for (int i = gtid; i < 3 * 4096 + 8192; i += gridDim.x * 256) {
        float mean = cs[i] * (1.0f / 4096.0f);
        float tN, Nf;
        if (i < 12288) { tN = 1.0f / 4096.0f; Nf = 4096.0f; }
        else           { tN = 1.0f / 8192.0f; Nf = 8192.0f; }
        float d = mean - tN;
        acc += d * d * Nf;
    }
    acc = blockReduceF(acc, red, threadIdx.x >> 6, threadIdx.x & 63);
    if (threadIdx.x == 0) atomicAdd(out_aux, acc);
}

// ---------------------------------------------------------------------------
extern "C" void kernel_launch(void* const* d_in, const int* in_sizes, int n_in,
                              void* d_out, int out_size, void* d_ws, size_t ws_size,
                              hipStream_t stream) {
    const float* x         = (const float*)d_in[0];
    const float* qk_emb    = (const float*)d_in[1];
    const float* qk_w      = (const float*)d_in[2];
    const float* v_emb     = (const float*)d_in[3];
    const float* v_w       = (const float*)d_in[4];
    const float* know_emb  = (const float*)d_in[5];
    const float* know_w    = (const float*)d_in[6];
    const float* tau_attn_k = (const float*)d_in[7];
    const float* tau_attn_b = (const float*)d_in[8];
    const float* tau_know_k = (const float*)d_in[9];
    const float* tau_know_b = (const float*)d_in[10];
    const float* expand_O  = (const float*)d_in[11];
    const float* ln1_s     = (const float*)d_in[12];
    const float* ln1_b     = (const float*)d_in[13];
    const float* ln2_s     = (const float*)d_in[14];
    const float* ln2_b     = (const float*)d_in[15];
    float* out = (float*)d_out;
    char*  ws  = (char*)d_ws;

    // workspace layout (bytes)
    u16*   nrm_bf   = (u16*)(ws + 0);                 //  8 MB
    u16*   qkemb_bf = (u16*)(ws + 8388608);           //  8 MB
    u16*   vemb_bf  = (u16*)(ws + 16777216);          //  8 MB
    u16*   knemb_bf = (u16*)(ws + 25165824);          // 16 MB
    u16*   expT_bf  = (u16*)(ws + 41943040);          //  2 MB
    u16*   attn_bf  = (u16*)(ws + 44040192);          //  8 MB
    float* scores   = (float*)(ws + 52428800);        // 64 MB
    u16*   Qb       = (u16*)(ws + 119537664);         //  8 MB (bf16)
    u16*   Kb       = (u16*)(ws + 136314880);         //  8 MB (bf16)
    u16*   Vb       = (u16*)(ws + 153092096);         //  8 MB (bf16)
    int*   selQK    = (int*)(ws + 169869312);
    float* valQ     = (float*)(ws + 170655744);
    float* valK     = (float*)(ws + 171442176);
    int*   selV     = (int*)(ws + 172228608);
    float* valV     = (float*)(ws + 173015040);
    int*   selKn    = (int*)(ws + 173801472);
    float* valKn    = (float*)(ws + 175374336);
    int*   cntQK    = (int*)(ws + 176947200);
    int*   cntV     = (int*)(ws + 176963584);
    int*   cntKn    = (int*)(ws + 176979968);
    float* tauA     = (float*)(ws + 176996352);       // [T][3]
    float* tauKn    = (float*)(ws + 177045504);       // [T]
    float* colsum   = (float*)(ws + 177061888);       // 20480 floats: Q,K,V,Kn
    const size_t WS_NEEDED = 177143808;
    if (ws_size < WS_NEEDED) return;   // workspace too small — bail cleanly

    float* colQ = colsum, *colK = colsum + 4096, *colV = colsum + 8192, *colKn = colsum + 12288;

    hipMemsetAsync(colsum, 0, 20480 * sizeof(float), stream);
    hipMemsetAsync(out + (size_t)TOK * DIM, 0, sizeof(float), stream);

    // bf16 conversions
    k_f32_to_bf16<<<1024, 256, 0, stream>>>(qk_emb,  qkemb_bf, NQK * DIM / 4);
    k_f32_to_bf16<<<1024, 256, 0, stream>>>(v_emb,   vemb_bf,  NV * DIM / 4);
    k_f32_to_bf16<<<2048, 256, 0, stream>>>(know_emb, knemb_bf, NKN * DIM / 4);
    k_transpose_bf16<<<dim3(32, 32), 256, 0, stream>>>(expand_O, expT_bf);

    // LN1 + tau(3)
    k_ln_tau<<<TOK, 256, 0, stream>>>(x, ln1_s, ln1_b, tau_attn_k, tau_attn_b, 3, nrm_bf, tauA);

    // scores_qk + gate (g_Q, g_K share selection)
    k_gemm_bt<<<dim3(NQK / 128, TOK / 128), 256, 0, stream>>>(nrm_bf, qkemb_bf, scores, TOK, NQK, DIM, nullptr);
    k_gate<<<TOK, 256, NQK * sizeof(u32), stream>>>(scores, NQK, 32, 0, tauA, 3, 0, 1,
                                                    selQK, valQ, valK, cntQK, colQ, colK, CAPA);
    // scores_v + gate (g_V)
    k_gemm_bt<<<dim3(NV / 128, TOK / 128), 256, 0, stream>>>(nrm_bf, vemb_bf, scores, TOK, NV, DIM, nullptr);
    k_gate<<<TOK, 256, NV * sizeof(u32), stream>>>(scores, NV, 32, 0, tauA, 3, 2, 0,
                                                   selV, valV, nullptr, cntV, colV, nullptr, CAPA);

    // sparse emits Q, K, V (bf16)
    k_gather2<<<TOK, 256, 0, stream>>>(qk_w, selQK, valQ, valK, cntQK, CAPA, Qb, Kb);
    k_gather1<<<TOK, 256, 0, stream>>>(v_w, selV, valV, cntV, CAPA, Vb);

    // causal MHA (bf16 MFMA) -> bf16
    k_attn<<<dim3(NH, 2, SLEN / 64), 256, 0, stream>>>(Qb, Kb, Vb, attn_bf);

    // out @ expand_O + residual x  -> x1 (stored in d_out)
    k_gemm_bt<<<dim3(DIM / 128, TOK / 128), 256, 0, stream>>>(attn_bf, expT_bf, out, TOK, DIM, DIM, x);

    // LN2 + tau_know
    k_ln_tau<<<TOK, 256, 0, stream>>>(out, ln2_s, ln2_b, tau_know_k, tau_know_b, 1, nrm_bf, tauKn);

    // know scores + gate, in 2 token chunks (scores buffer = 64 MB)
    for (int c = 0; c < 2; c++) {
        k_gemm_bt<<<dim3(NKN / 128, 2048 / 128), 256, 0, stream>>>(
            nrm_bf + (size_t)c * 2048 * DIM, knemb_bf, scores, 2048, NKN, DIM, nullptr);
        k_gate<<<2048, 256, NKN * sizeof(u32), stream>>>(scores, NKN, 64, c * 2048, tauKn, 1, 0, 0,
                                                         selKn, valKn, nullptr, cntKn, colKn, nullptr, CAPK);
    }

    // know emit + final residual (in place on d_out)
    k_gather_final<<<TOK, 256, 0, stream>>>(know_w, selKn, valKn, cntKn, CAPK, out);

    // aux scalar
    k_aux<<<20, 256, 0, stream>>>(colsum, out + (size_t)TOK * DIM);
}

// Round 4
// 958.112 us; speedup vs baseline: 1.8561x; 1.0000x over previous
//
#include <hip/hip_runtime.h>

// ---------------------------------------------------------------------------
// Problem constants (fixed by the reference)
// ---------------------------------------------------------------------------
#define TOK   4096      // B*S
#define DIM   1024
#define NQK   4096
#define NV    4096
#define NKN   8192
#define SLEN  2048
#define NH    16
#define DH    64
#define CAPA  48        // capacity for k=32 gates (slack for ties)
#define CAPK  96        // capacity for k=64 gate
#define APAD  72        // attn LDS row pad (bf16 elems): 144B keeps b128 align

typedef float  f32x4  __attribute__((ext_vector_type(4)));
typedef short  short8 __attribute__((ext_vector_type(8)));
typedef unsigned int  u32;
typedef unsigned short u16;

__device__ __forceinline__ u16 f2bf(float f) {
    u32 u = __float_as_uint(f);
    u32 r = (u + 0x7fffu + ((u >> 16) & 1u)) >> 16;
    return (u16)r;
}
__device__ __forceinline__ float bf2f(u16 v) { return __uint_as_float(((u32)v) << 16); }

__device__ __forceinline__ f32x4 mfma_bf16(short8 a, short8 b, f32x4 c) {
    asm volatile("v_mfma_f32_16x16x32_bf16 %0, %1, %2, %0"
                 : "+v"(c) : "v"(a), "v"(b));
    return c;
}

// async global->LDS, 16B per lane; LDS dest = wave-uniform base + lane*16
__device__ __forceinline__ void gload16(const u16* g, u16* s) {
    __builtin_amdgcn_global_load_lds((const __attribute__((address_space(1))) void*)g,
                                     (__attribute__((address_space(3))) void*)s, 16, 0, 0);
}

__device__ __forceinline__ float blockReduceF(float v, float* red, int wave, int lane) {
#pragma unroll
    for (int off = 32; off > 0; off >>= 1) v += __shfl_xor(v, off);
    __syncthreads();
    if (lane == 0) red[wave] = v;
    __syncthreads();
    return red[0] + red[1] + red[2] + red[3];
}

// ---------------------------------------------------------------------------
// f32 -> bf16 conversion (grid-stride, float4)
// ---------------------------------------------------------------------------
__global__ __launch_bounds__(256) void k_f32_to_bf16(const float* __restrict__ in,
                                                     u16* __restrict__ out, int n4) {
    int i = blockIdx.x * 256 + threadIdx.x;
    int stride = gridDim.x * 256;
    for (; i < n4; i += stride) {
        float4 v = reinterpret_cast<const float4*>(in)[i];
        ushort4 o = make_ushort4(f2bf(v.x), f2bf(v.y), f2bf(v.z), f2bf(v.w));
        reinterpret_cast<ushort4*>(out)[i] = o;
    }
}

// transpose 1024x1024 f32 -> bf16 (out[n][k] = in[k][n])
__global__ __launch_bounds__(256) void k_transpose_bf16(const float* __restrict__ in,
                                                        u16* __restrict__ out) {
    __shared__ float tile[32][33];
    int bx = blockIdx.x * 32;   // col of in
    int by = blockIdx.y * 32;   // row of in
    int tx = threadIdx.x & 31;
    int ty = threadIdx.x >> 5;  // 0..7
    for (int r = ty; r < 32; r += 8)
        tile[r][tx] = in[(size_t)(by + r) * DIM + bx + tx];
    __syncthreads();
    for (int r = ty; r < 32; r += 8)
        out[(size_t)(bx + r) * DIM + by + tx] = f2bf(tile[tx][r]);
}

// ---------------------------------------------------------------------------
// LayerNorm + tau projection; writes bf16 normed + f32 tau[t][ntau]
// ---------------------------------------------------------------------------
__global__ __launch_bounds__(256) void k_ln_tau(const float* __restrict__ x,
                                                const float* __restrict__ sc,
                                                const float* __restrict__ bi,
                                                const float* __restrict__ tauk,
                                                const float* __restrict__ taub,
                                                int ntau,
                                                u16* __restrict__ nrm,
                                                float* __restrict__ tau_out) {
    __shared__ float red[4];
    int t = blockIdx.x, tid = threadIdx.x, wave = tid >> 6, lane = tid & 63;
    const float4 xv = reinterpret_cast<const float4*>(x + (size_t)t * DIM)[tid];
    float s = xv.x + xv.y + xv.z + xv.w;
    s = blockReduceF(s, red, wave, lane);
    float mean = s * (1.0f / DIM);
    float d0 = xv.x - mean, d1 = xv.y - mean, d2 = xv.z - mean, d3 = xv.w - mean;
    float ss = d0 * d0 + d1 * d1 + d2 * d2 + d3 * d3;
    ss = blockReduceF(ss, red, wave, lane);
    float rstd = rsqrtf(ss * (1.0f / DIM) + 1e-6f);
    const float4 scv = reinterpret_cast<const float4*>(sc)[tid];
    const float4 biv = reinterpret_cast<const float4*>(bi)[tid];
    float n0 = d0 * rstd * scv.x + biv.x;
    float n1 = d1 * rstd * scv.y + biv.y;
    float n2 = d2 * rstd * scv.z + biv.z;
    float n3 = d3 * rstd * scv.w + biv.w;
    ushort4 o = make_ushort4(f2bf(n0), f2bf(n1), f2bf(n2), f2bf(n3));
    reinterpret_cast<ushort4*>(nrm + (size_t)t * DIM)[tid] = o;
    int d = tid * 4;
    for (int j = 0; j < ntau; j++) {
        float p = n0 * tauk[(size_t)(d + 0) * ntau + j] + n1 * tauk[(size_t)(d + 1) * ntau + j]
                + n2 * tauk[(size_t)(d + 2) * ntau + j] + n3 * tauk[(size_t)(d + 3) * ntau + j];
        p = blockReduceF(p, red, wave, lane);
        if (tid == 0) tau_out[(size_t)t * ntau + j] = p + taub[j];
    }
}

// ---------------------------------------------------------------------------
// C[M][N] = A[M][K] @ B[N][K]^T   (bf16 in, f32 out), optional residual fuse
// m97 structure: 128x128 tile, 4 waves, 16x16x32 MFMA, BK=32,
// global_load_lds width-16 staging into linear LDS [kg(4)][row(128)][8].
// Wave w stages kg=w: issue0 rows 0..63 (=lane), issue1 rows 64..127.
// ---------------------------------------------------------------------------
__global__ __launch_bounds__(256) void k_gemm_bt(const u16* __restrict__ A,
                                                 const u16* __restrict__ B,
                                                 float* __restrict__ C,
                                                 int M, int N, int K,
                                                 const float* __restrict__ res) {
    __shared__ __align__(16) u16 As[4096];
    __shared__ __align__(16) u16 Bs[4096];
    int tid = threadIdx.x;
    int wave = tid >> 6, lane = tid & 63;
    int m0 = blockIdx.y * 128, n0 = blockIdx.x * 128;
    int wm = (wave >> 1) * 64, wn = (wave & 1) * 64;
    int kg = lane >> 4, l15 = lane & 15;

    // staging pointers (per-lane global, wave-uniform LDS)
    const u16* gA0 = A + (size_t)(m0 + lane) * K + wave * 8;
    const u16* gA1 = A + (size_t)(m0 + 64 + lane) * K + wave * 8;
    const u16* gB0 = B + (size_t)(n0 + lane) * K + wave * 8;
    const u16* gB1 = B + (size_t)(n0 + 64 + lane) * K + wave * 8;
    u16* sA0 = As + wave * 1024;
    u16* sA1 = As + wave * 1024 + 512;
    u16* sB0 = Bs + wave * 1024;
    u16* sB1 = Bs + wave * 1024 + 512;

    f32x4 acc[4][4];
#pragma unroll
    for (int i = 0; i < 4; i++)
#pragma unroll
        for (int j = 0; j < 4; j++) { f32x4 z = {0.f, 0.f, 0.f, 0.f}; acc[i][j] = z; }

    for (int k0 = 0; k0 < K; k0 += 32) {
        __syncthreads();          // previous iter's LDS reads done
        gload16(gA0 + k0, sA0);
        gload16(gA1 + k0, sA1);
        gload16(gB0 + k0, sB0);
        gload16(gB1 + k0, sB1);
        __syncthreads();          // drains vmcnt+lgkm, staging visible
        short8 af[4], bg[4];
#pragma unroll
        for (int mi = 0; mi < 4; mi++) {
            int row = wm + mi * 16 + l15;
            af[mi] = *reinterpret_cast<const short8*>(&As[(kg * 128 + row) * 8]);
        }
#pragma unroll
        for (int ni = 0; ni < 4; ni++) {
            int row = wn + ni * 16 + l15;
            bg[ni] = *reinterpret_cast<const short8*>(&Bs[(kg * 128 + row) * 8]);
        }
#pragma unroll
        for (int mi = 0; mi < 4; mi++)
#pragma unroll
            for (int ni = 0; ni < 4; ni++)
                acc[mi][ni] = mfma_bf16(af[mi], bg[ni], acc[mi][ni]);
    }
    asm volatile("s_nop 7\n\ts_nop 7");
#pragma unroll
    for (int mi = 0; mi < 4; mi++) {
#pragma unroll
        for (int ni = 0; ni < 4; ni++) {
            int col = n0 + wn + ni * 16 + l15;
#pragma unroll
            for (int r = 0; r < 4; r++) {
                int rowm = m0 + wm + mi * 16 + (lane >> 4) * 4 + r;
                size_t idx = (size_t)rowm * N + col;
                float v = acc[mi][ni][r];
                if (res) v += res[idx];
                C[idx] = v;
            }
        }
    }
}

// ---------------------------------------------------------------------------
// Top-k threshold gate. One block per row. Exact kth-largest via 32-bit
// binary search on sign-flipped float keys (matches jax top_k + ">= thr").
// Emits sparse (idx, score*gate) lists (sense_emit_full = ((x@E.T)*g)@W !)
// plus bare-gate column-sum atomics for the aux loss.
// ---------------------------------------------------------------------------
__global__ __launch_bounds__(256) void k_gate(const float* __restrict__ scores, int NC, int ksel,
                                              int row_off,
                                              const float* __restrict__ tau, int tau_stride, int tcol0,
                                              int two,
                                              int* __restrict__ sel,
                                              float* __restrict__ vA, float* __restrict__ vB,
                                              int* __restrict__ cnt,
                                              float* __restrict__ csA, float* __restrict__ csB,
                                              int cap) {
    extern __shared__ u32 keys[];
    __shared__ int   redi[4];
    __shared__ int   scnt;
    __shared__ int   sidx[CAPK];
    __shared__ float sraw[CAPK];
    int r = blockIdx.x, tid = threadIdx.x, wave = tid >> 6, lane = tid & 63;
    int t = row_off + r;
    const float* srow = scores + (size_t)r * NC;
    for (int c = tid; c < NC; c += 256) {
        u32 u = __float_as_uint(srow[c]);
        keys[c] = (u & 0x80000000u) ? ~u : (u | 0x80000000u);
    }
    if (tid == 0) scnt = 0;
    __syncthreads();

    u32 thr = 0;
    for (int b = 31; b >= 0; --b) {
        u32 cand = thr | (1u << b);
        int c = 0;
        for (int i = tid; i < NC; i += 256) c += (keys[i] >= cand) ? 1 : 0;
#pragma unroll
        for (int off = 32; off > 0; off >>= 1) c += __shfl_xor(c, off);
        __syncthreads();
        if (lane == 0) redi[wave] = c;
        __syncthreads();
        c = redi[0] + redi[1] + redi[2] + redi[3];
        if (c >= ksel) thr = cand;
    }
    __syncthreads();

    for (int i = tid; i < NC; i += 256) {
        if (keys[i] >= thr) {
            int p = atomicAdd(&scnt, 1);
            if (p < cap) {
                sidx[p] = i;
                u32 ky = keys[i];
                u32 uo = (ky & 0x80000000u) ? (ky & 0x7fffffffu) : ~ky;
                sraw[p] = __uint_as_float(uo);
            }
        }
    }
    __syncthreads();
    int n = scnt < cap ? scnt : cap;
    if (tid == 0) cnt[t] = n;
    if (wave != 0) return;

    float tA = tau[(size_t)t * tau_stride + tcol0];
    float tB = two ? tau[(size_t)t * tau_stride + tcol0 + 1] : 0.f;
    float sumA = 0.f, mxA = -1e30f, sumB = 0.f, mxB = -1e30f;
    for (int i = lane; i < n; i += 64) {
        float sv = sraw[i];
        float rA = sv - tA;
        float gA = rA > 0.f ? rA : 1e-8f * expf(rA);
        float eA = expf(gA) - 1.0f;            // match reference quantization
        sumA += eA; mxA = fmaxf(mxA, eA);
        if (two) {
            float rB = sv - tB;
            float gB = rB > 0.f ? rB : 1e-8f * expf(rB);
            float eB = expf(gB) - 1.0f;
            sumB += eB; mxB = fmaxf(mxB, eB);
        }
    }
#pragma unroll
    for (int off = 32; off > 0; off >>= 1) {
        sumA += __shfl_xor(sumA, off); mxA = fmaxf(mxA, __shfl_xor(mxA, off));
        sumB += __shfl_xor(sumB, off); mxB = fmaxf(mxB, __shfl_xor(mxB, off));
    }
    float fA = tanhf(mxA) / (sumA + 1e-8f);
    float fB = tanhf(mxB) / (sumB + 1e-8f);
    for (int i = lane; i < n; i += 64) {
        float sv = sraw[i]; int ci = sidx[i];
        float rA = sv - tA;
        float gA = rA > 0.f ? rA : 1e-8f * expf(rA);
        float ga = (expf(gA) - 1.0f) * fA;     // bare gate (aux loss)
        sel[(size_t)t * cap + i] = ci;
        vA[(size_t)t * cap + i] = ga * sv;     // emit weight = score * gate
        atomicAdd(&csA[ci], ga);
        if (two) {
            float rB = sv - tB;
            float gB = rB > 0.f ? rB : 1e-8f * expf(rB);
            float gb = (expf(gB) - 1.0f) * fB;
            vB[(size_t)t * cap + i] = gb * sv;
            atomicAdd(&csB[ci], gb);
        }
    }
}

// ---------------------------------------------------------------------------
// Sparse emits (bf16 weights, bf16 out):  O[t] = sum_s val[s] * w[idx[s]]
// ---------------------------------------------------------------------------
__global__ __launch_bounds__(256) void k_gather2(const u16* __restrict__ w,
                                                 const int* __restrict__ sel,
                                                 const float* __restrict__ vA,
                                                 const float* __restrict__ vB,
                                                 const int* __restrict__ cnt, int cap,
                                                 u16* __restrict__ OA, u16* __restrict__ OB) {
    __shared__ int   sI[CAPK];
    __shared__ float sA[CAPK];
    __shared__ float sB[CAPK];
    int t = blockIdx.x, tid = threadIdx.x;
    int n = cnt[t];
    if (tid < n) { sI[tid] = sel[(size_t)t * cap + tid]; sA[tid] = vA[(size_t)t * cap + tid]; sB[tid] = vB[(size_t)t * cap + tid]; }
    __syncthreads();
    float a0 = 0, a1 = 0, a2 = 0, a3 = 0, b0 = 0, b1 = 0, b2 = 0, b3 = 0;
    for (int s = 0; s < n; s++) {
        const ushort4 wv = reinterpret_cast<const ushort4*>(w + (size_t)sI[s] * DIM)[tid];
        float w0 = bf2f(wv.x), w1 = bf2f(wv.y), w2 = bf2f(wv.z), w3 = bf2f(wv.w);
        float va = sA[s], vb = sB[s];
        a0 += va * w0; a1 += va * w1; a2 += va * w2; a3 += va * w3;
        b0 += vb * w0; b1 += vb * w1; b2 += vb * w2; b3 += vb * w3;
    }
    reinterpret_cast<ushort4*>(OA + (size_t)t * DIM)[tid] = make_ushort4(f2bf(a0), f2bf(a1), f2bf(a2), f2bf(a3));
    reinterpret_cast<ushort4*>(OB + (size_t)t * DIM)[tid] = make_ushort4(f2bf(b0), f2bf(b1), f2bf(b2), f2bf(b3));
}

__global__ __launch_bounds__(256) void k_gather1(const u16* __restrict__ w,
                                                 const int* __restrict__ sel,
                                                 const float* __restrict__ vv,
                                                 const int* __restrict__ cnt, int cap,
                                                 u16* __restrict__ O) {
    __shared__ int   sI[CAPK];
    __shared__ float sV[CAPK];
    int t = blockIdx.x, tid = threadIdx.x;
    int n = cnt[t];
    if (tid < n) { sI[tid] = sel[(size_t)t * cap + tid]; sV[tid] = vv[(size_t)t * cap + tid]; }
    __syncthreads();
    float a0 = 0, a1 = 0, a2 = 0, a3 = 0;
    for (int s = 0; s < n; s++) {
        const ushort4 wv = reinterpret_cast<const ushort4*>(w + (size_t)sI[s] * DIM)[tid];
        float va = sV[s];
        a0 += va * bf2f(wv.x); a1 += va * bf2f(wv.y); a2 += va * bf2f(wv.z); a3 += va * bf2f(wv.w);
    }
    reinterpret_cast<ushort4*>(O + (size_t)t * DIM)[tid] = make_ushort4(f2bf(a0), f2bf(a1), f2bf(a2), f2bf(a3));
}

// know emit fused with final residual: io[t] += sum val*w (bf16 weights)
__global__ __launch_bounds__(256) void k_gather_final(const u16* __restrict__ w,
                                                      const int* __restrict__ sel,
                                                      const float* __restrict__ vv,
                                                      const int* __restrict__ cnt, int cap,
                                                      float* __restrict__ io) {
    __shared__ int   sI[CAPK];
    __shared__ float sV[CAPK];
    int t = blockIdx.x, tid = threadIdx.x;
    int n = cnt[t];
    if (tid < n) { sI[tid] = sel[(size_t)t * cap + tid]; sV[tid] = vv[(size_t)t * cap + tid]; }
    __syncthreads();
    float4 base = reinterpret_cast<const float4*>(io + (size_t)t * DIM)[tid];
    float a0 = base.x, a1 = base.y, a2 = base.z, a3 = base.w;
    for (int s = 0; s < n; s++) {
        const ushort4 wv = reinterpret_cast<const ushort4*>(w + (size_t)sI[s] * DIM)[tid];
        float va = sV[s];
        a0 += va * bf2f(wv.x); a1 += va * bf2f(wv.y); a2 += va * bf2f(wv.z); a3 += va * bf2f(wv.w);
    }
    reinterpret_cast<float4*>(io + (size_t)t * DIM)[tid] = make_float4(a0, a1, a2, a3);
}

// ---------------------------------------------------------------------------
// Causal flash attention, bf16 MFMA (16x16x32).
// Block = 256 thr / 4 waves, one (b,h), 64 q rows (16 per wave).
// ---------------------------------------------------------------------------
__global__ __launch_bounds__(256) void k_attn(const u16* __restrict__ Q,
                                              const u16* __restrict__ K,
                                              const u16* __restrict__ V,
                                              u16* __restrict__ O) {
    __shared__ __align__(16) u16 Qs[64 * APAD];
    __shared__ __align__(16) u16 Ks[64 * APAD];
    __shared__ __align__(16) u16 Vt[64 * APAD];
    __shared__ __align__(16) u16 Ps[4][16 * APAD];
    int tid = threadIdx.x, wave = tid >> 6, lane = tid & 63;
    int h = blockIdx.x, bb = blockIdx.y, qt = blockIdx.z;
    int q0 = qt * 64;
    size_t base = ((size_t)bb * SLEN) * DIM + (size_t)h * DH;
    int sr = tid >> 2, sc = (tid & 3) * 16;     // staging row (0..63), col (0/16/32/48)
    int g = lane >> 4, l15 = lane & 15;

    // stage Q tile once
    {
        const u16* qp = Q + base + (size_t)(q0 + sr) * DIM + sc;
        *reinterpret_cast<short8*>(&Qs[sr * APAD + sc])     = *reinterpret_cast<const short8*>(qp);
        *reinterpret_cast<short8*>(&Qs[sr * APAD + sc + 8]) = *reinterpret_cast<const short8*>(qp + 8);
    }
    __syncthreads();
    short8 qa0 = *reinterpret_cast<const short8*>(&Qs[(wave * 16 + l15) * APAD + g * 8]);
    short8 qa1 = *reinterpret_cast<const short8*>(&Qs[(wave * 16 + l15) * APAD + 32 + g * 8]);

    float m[4], l[4];
    f32x4 oacc[4];
#pragma unroll
    for (int i = 0; i < 4; i++) {
        m[i] = -1e30f; l[i] = 0.f;
        f32x4 z = {0.f, 0.f, 0.f, 0.f}; oacc[i] = z;
    }
    u16* pw = &Ps[wave][0];

    for (int kc = 0; kc <= qt; kc++) {
        __syncthreads();
        // ---- stage K [key][dim] and V transposed [dim][key] ----
        {
            const u16* kp = K + base + (size_t)(kc * 64 + sr) * DIM + sc;
            *reinterpret_cast<short8*>(&Ks[sr * APAD + sc])     = *reinterpret_cast<const short8*>(kp);
            *reinterpret_cast<short8*>(&Ks[sr * APAD + sc + 8]) = *reinterpret_cast<const short8*>(kp + 8);
            const u16* vp = V + base + (size_t)(kc * 64 + sr) * DIM + sc;
            short8 w0 = *reinterpret_cast<const short8*>(vp);
            short8 w1 = *reinterpret_cast<const short8*>(vp + 8);
            const u16* w0p = reinterpret_cast<const u16*>(&w0);
            const u16* w1p = reinterpret_cast<const u16*>(&w1);
#pragma unroll
            for (int j = 0; j < 16; j++) {
                int d = sc + j;
                int phys = (((sr >> 3) + d + (d >> 4)) & 7);   // rotate key-blocks per dim
                Vt[d * APAD + phys * 8 + (sr & 7)] = (j < 8) ? w0p[j] : w1p[j - 8];
            }
        }
        __syncthreads();

        // ---- QK^T: 8 MFMAs -> s4[ks] (q_local = wave*16 + g*4 + r, key = ks*16 + l15)
        f32x4 s4[4];
#pragma unroll
        for (int ks = 0; ks < 4; ks++) {
            f32x4 z = {0.f, 0.f, 0.f, 0.f}; s4[ks] = z;
            short8 kb0 = *reinterpret_cast<const short8*>(&Ks[(ks * 16 + l15) * APAD + g * 8]);
            short8 kb1 = *reinterpret_cast<const short8*>(&Ks[(ks * 16 + l15) * APAD + 32 + g * 8]);
            s4[ks] = mfma_bf16(qa0, kb0, s4[ks]);
            s4[ks] = mfma_bf16(qa1, kb1, s4[ks]);
        }
        asm volatile("s_nop 7\n\ts_nop 7");   // MFMA -> VALU read hazard

        // ---- scale + causal mask ----
        int key_base = kc * 64 + l15;
#pragma unroll
        for (int ks = 0; ks < 4; ks++) {
            int key = key_base + ks * 16;
#pragma unroll
            for (int r = 0; r < 4; r++) {
                int q_abs = q0 + wave * 16 + g * 4 + r;
                float sv = s4[ks][r] * 0.125f;
                s4[ks][r] = (key > q_abs) ? -1e30f : sv;
            }
        }

        // ---- online softmax per q-row; write P (bf16) to per-wave LDS ----
#pragma unroll
        for (int r = 0; r < 4; r++) {
            float mx = fmaxf(fmaxf(s4[0][r], s4[1][r]), fmaxf(s4[2][r], s4[3][r]));
            mx = fmaxf(mx, __shfl_xor(mx, 1));
            mx = fmaxf(mx, __shfl_xor(mx, 2));
            mx = fmaxf(mx, __shfl_xor(mx, 4));
            mx = fmaxf(mx, __shfl_xor(mx, 8));
            float mnew = fmaxf(m[r], mx);
            float al = __expf(m[r] - mnew);
            m[r] = mnew;
            float p0 = __expf(s4[0][r] - mnew);
            float p1 = __expf(s4[1][r] - mnew);
            float p2 = __expf(s4[2][r] - mnew);
            float p3 = __expf(s4[3][r] - mnew);
            float ps = p0 + p1 + p2 + p3;
            ps += __shfl_xor(ps, 1);
            ps += __shfl_xor(ps, 2);
            ps += __shfl_xor(ps, 4);
            ps += __shfl_xor(ps, 8);
            l[r] = l[r] * al + ps;
#pragma unroll
            for (int ds_ = 0; ds_ < 4; ds_++) oacc[ds_][r] *= al;
            int row = g * 4 + r;
            pw[row * APAD +  0 + l15] = f2bf(p0);
            pw[row * APAD + 16 + l15] = f2bf(p1);
            pw[row * APAD + 32 + l15] = f2bf(p2);
            pw[row * APAD + 48 + l15] = f2bf(p3);
        }

        // ---- PV: read P as A-fragments, V^T as B-fragments; 8 MFMAs ----
        short8 pa0 = *reinterpret_cast<const short8*>(&pw[l15 * APAD + g * 8]);
        short8 pa1 = *reinterpret_cast<const short8*>(&pw[l15 * APAD + 32 + g * 8]);
#pragma unroll
        for (int dsub = 0; dsub < 4; dsub++) {
            int d = dsub * 16 + l15;
            int rot = d + (d >> 4);
            short8 vb0 = *reinterpret_cast<const short8*>(&Vt[d * APAD + (((0 + g) + rot) & 7) * 8]);
            short8 vb1 = *reinterpret_cast<const short8*>(&Vt[d * APAD + (((4 + g) + rot) & 7) * 8]);
            oacc[dsub] = mfma_bf16(pa0, vb0, oacc[dsub]);
            oacc[dsub] = mfma_bf16(pa1, vb1, oacc[dsub]);
        }
    }
    asm volatile("s_nop 7\n\ts_nop 7");       // MFMA -> VALU read hazard

    // ---- epilogue: O = oacc / l, bf16 ----
#pragma unroll
    for (int r = 0; r < 4; r++) {
        float inv = 1.0f / l[r];
        int row = q0 + wave * 16 + g * 4 + r;
#pragma unroll
        for (int dsub = 0; dsub < 4; dsub++) {
            O[base + (size_t)row * DIM + dsub * 16 + l15] = f2bf(oacc[dsub][r] * inv);
        }
    }
}

// ---------------------------------------------------------------------------
// aux = sum over gate columns of (colsum/T - 1/N)^2 * N
// ---------------------------------------------------------------------------
__global__ __launch_bounds__(256) void k_aux(const float* __restrict__ cs,
                                             float* __restrict__ out_aux) {
    __shared__ float red[4];
    int gtid = blockIdx.x * 256 + threadIdx.x;
    float acc = 0.f;
    for (int i = gtid; i < 3 * 4096 + 8192; i += gridDim.x * 256) {
        float mean = cs[i] * (1.0f / 4096.0f);
        float tN, Nf;
        if (i < 12288) { tN = 1.0f / 4096.0f; Nf = 4096.0f; }
        else           { tN = 1.0f / 8192.0f; Nf = 8192.0f; }
        float d = mean - tN;
        acc += d * d * Nf;
    }
    acc = blockReduceF(acc, red, threadIdx.x >> 6, threadIdx.x & 63);
    if (threadIdx.x == 0) atomicAdd(out_aux, acc);
}

// ---------------------------------------------------------------------------
extern "C" void kernel_launch(void* const* d_in, const int* in_sizes, int n_in,
                              void* d_out, int out_size, void* d_ws, size_t ws_size,
                              hipStream_t stream) {
    const float* x         = (const float*)d_in[0];
    const float* qk_emb    = (const float*)d_in[1];
    const float* qk_w      = (const float*)d_in[2];
    const float* v_emb     = (const float*)d_in[3];
    const float* v_w       = (const float*)d_in[4];
    const float* know_emb  = (const float*)d_in[5];
    const float* know_w    = (const float*)d_in[6];
    const float* tau_attn_k = (const float*)d_in[7];
    const float* tau_attn_b = (const float*)d_in[8];
    const float* tau_know_k = (const float*)d_in[9];
    const float* tau_know_b = (const float*)d_in[10];
    const float* expand_O  = (const float*)d_in[11];
    const float* ln1_s     = (const float*)d_in[12];
    const float* ln1_b     = (const float*)d_in[13];
    const float* ln2_s     = (const float*)d_in[14];
    const float* ln2_b     = (const float*)d_in[15];
    float* out = (float*)d_out;
    char*  ws  = (char*)d_ws;

    // workspace layout (bytes)
    u16*   nrm_bf   = (u16*)(ws + 0);                 //  8 MB
    u16*   qkemb_bf = (u16*)(ws + 8388608);           //  8 MB
    u16*   vemb_bf  = (u16*)(ws + 16777216);          //  8 MB
    u16*   knemb_bf = (u16*)(ws + 25165824);          // 16 MB
    u16*   expT_bf  = (u16*)(ws + 41943040);          //  2 MB
    u16*   attn_bf  = (u16*)(ws + 44040192);          //  8 MB
    u16*   qkw_bf   = (u16*)(ws + 52428800);          //  8 MB
    u16*   vw_bf    = (u16*)(ws + 60817408);          //  8 MB
    u16*   knw_bf   = (u16*)(ws + 69206016);          // 16 MB
    u16*   Qb       = (u16*)(ws + 85983232);          //  8 MB (bf16)
    u16*   Kb       = (u16*)(ws + 94371840);          //  8 MB (bf16)
    u16*   Vb       = (u16*)(ws + 102760448);         //  8 MB (bf16)
    float* scores   = (float*)(ws + 111149056);       // 64 MB
    int*   selQK    = (int*)(ws + 178257920);
    float* valQ     = (float*)(ws + 179044352);
    float* valK     = (float*)(ws + 179830784);
    int*   selV     = (int*)(ws + 180617216);
    float* valV     = (float*)(ws + 181403648);
    int*   selKn    = (int*)(ws + 182190080);
    float* valKn    = (float*)(ws + 183762944);
    int*   cntQK    = (int*)(ws + 185335808);
    int*   cntV     = (int*)(ws + 185352192);
    int*   cntKn    = (int*)(ws + 185368576);
    float* tauA     = (float*)(ws + 185384960);       // [T][3]
    float* tauKn    = (float*)(ws + 185434112);       // [T]
    float* colsum   = (float*)(ws + 185450496);       // 20480 floats: Q,K,V,Kn
    const size_t WS_NEEDED = 185532416;
    if (ws_size < WS_NEEDED) return;   // workspace too small — bail cleanly

    float* colQ = colsum, *colK = colsum + 4096, *colV = colsum + 8192, *colKn = colsum + 12288;

    hipMemsetAsync(colsum, 0, 20480 * sizeof(float), stream);
    hipMemsetAsync(out + (size_t)TOK * DIM, 0, sizeof(float), stream);

    // bf16 conversions (embeddings + weights)
    k_f32_to_bf16<<<1024, 256, 0, stream>>>(qk_emb,  qkemb_bf, NQK * DIM / 4);
    k_f32_to_bf16<<<1024, 256, 0, stream>>>(v_emb,   vemb_bf,  NV * DIM / 4);
    k_f32_to_bf16<<<2048, 256, 0, stream>>>(know_emb, knemb_bf, NKN * DIM / 4);
    k_f32_to_bf16<<<1024, 256, 0, stream>>>(qk_w,   qkw_bf, NQK * DIM / 4);
    k_f32_to_bf16<<<1024, 256, 0, stream>>>(v_w,    vw_bf,  NV * DIM / 4);
    k_f32_to_bf16<<<2048, 256, 0, stream>>>(know_w, knw_bf, NKN * DIM / 4);
    k_transpose_bf16<<<dim3(32, 32), 256, 0, stream>>>(expand_O, expT_bf);

    // LN1 + tau(3)
    k_ln_tau<<<TOK, 256, 0, stream>>>(x, ln1_s, ln1_b, tau_attn_k, tau_attn_b, 3, nrm_bf, tauA);

    // scores_qk + gate (g_Q, g_K share selection)
    k_gemm_bt<<<dim3(NQK / 128, TOK / 128), 256, 0, stream>>>(nrm_bf, qkemb_bf, scores, TOK, NQK, DIM, nullptr);
    k_gate<<<TOK, 256, NQK * sizeof(u32), stream>>>(scores, NQK, 32, 0, tauA, 3, 0, 1,
                                                    selQK, valQ, valK, cntQK, colQ, colK, CAPA);
    // scores_v + gate (g_V)
    k_gemm_bt<<<dim3(NV / 128, TOK / 128), 256, 0, stream>>>(nrm_bf, vemb_bf, scores, TOK, NV, DIM, nullptr);
    k_gate<<<TOK, 256, NV * sizeof(u32), stream>>>(scores, NV, 32, 0, tauA, 3, 2, 0,
                                                   selV, valV, nullptr, cntV, colV, nullptr, CAPA);

    // sparse emits Q, K, V (bf16 weights -> bf16 out)
    k_gather2<<<TOK, 256, 0, stream>>>(qkw_bf, selQK, valQ, valK, cntQK, CAPA, Qb, Kb);
    k_gather1<<<TOK, 256, 0, stream>>>(vw_bf, selV, valV, cntV, CAPA, Vb);

    // causal MHA (bf16 MFMA) -> bf16
    k_attn<<<dim3(NH, 2, SLEN / 64), 256, 0, stream>>>(Qb, Kb, Vb, attn_bf);

    // out @ expand_O + residual x  -> x1 (stored in d_out)
    k_gemm_bt<<<dim3(DIM / 128, TOK / 128), 256, 0, stream>>>(attn_bf, expT_bf, out, TOK, DIM, DIM, x);

    // LN2 + tau_know
    k_ln_tau<<<TOK, 256, 0, stream>>>(out, ln2_s, ln2_b, tau_know_k, tau_know_b, 1, nrm_bf, tauKn);

    // know scores + gate, in 2 token chunks (scores buffer = 64 MB)
    for (int c = 0; c < 2; c++) {
        k_gemm_bt<<<dim3(NKN / 128, 2048 / 128), 256, 0, stream>>>(
            nrm_bf + (size_t)c * 2048 * DIM, knemb_bf, scores, 2048, NKN, DIM, nullptr);
        k_gate<<<2048, 256, NKN * sizeof(u32), stream>>>(scores, NKN, 64, c * 2048, tauKn, 1, 0, 0,
                                                         selKn, valKn, nullptr, cntKn, colKn, nullptr, CAPK);
    }

    // know emit + final residual (in place on d_out)
    k_gather_final<<<TOK, 256, 0, stream>>>(knw_bf, selKn, valKn, cntKn, CAPK, out);

    // aux scalar
    k_aux<<<20, 256, 0, stream>>>(colsum, out + (size_t)TOK * DIM);
}

// Round 5
// 842.829 us; speedup vs baseline: 2.1100x; 1.1368x over previous
//
#include <hip/hip_runtime.h>

// ---------------------------------------------------------------------------
// Problem constants (fixed by the reference)
// ---------------------------------------------------------------------------
#define TOK   4096      // B*S
#define DIM   1024
#define NQK   4096
#define NV    4096
#define NKN   8192
#define SLEN  2048
#define NH    16
#define DH    64
#define CAPA  48        // capacity for k=32 gates (slack for ties)
#define CAPK  96        // capacity for k=64 gate
#define APAD  72        // attn LDS row pad (bf16 elems): 144B keeps b128 align

typedef float  f32x4  __attribute__((ext_vector_type(4)));
typedef short  short8 __attribute__((ext_vector_type(8)));
typedef unsigned int  u32;
typedef unsigned short u16;

__device__ __forceinline__ u16 f2bf(float f) {
    u32 u = __float_as_uint(f);
    u32 r = (u + 0x7fffu + ((u >> 16) & 1u)) >> 16;
    return (u16)r;
}
__device__ __forceinline__ float bf2f(u16 v) { return __uint_as_float(((u32)v) << 16); }

__device__ __forceinline__ f32x4 mfma_bf16(short8 a, short8 b, f32x4 c) {
    asm volatile("v_mfma_f32_16x16x32_bf16 %0, %1, %2, %0"
                 : "+v"(c) : "v"(a), "v"(b));
    return c;
}

// async global->LDS, 16B per lane; LDS dest = wave-uniform base + lane*16
__device__ __forceinline__ void gload16(const u16* g, u16* s) {
    __builtin_amdgcn_global_load_lds((const __attribute__((address_space(1))) void*)g,
                                     (__attribute__((address_space(3))) void*)s, 16, 0, 0);
}

__device__ __forceinline__ float blockReduceF(float v, float* red, int wave, int lane) {
#pragma unroll
    for (int off = 32; off > 0; off >>= 1) v += __shfl_xor(v, off);
    __syncthreads();
    if (lane == 0) red[wave] = v;
    __syncthreads();
    return red[0] + red[1] + red[2] + red[3];
}

// ---------------------------------------------------------------------------
// f32 -> bf16 conversion (grid-stride, float4)
// ---------------------------------------------------------------------------
__global__ __launch_bounds__(256) void k_f32_to_bf16(const float* __restrict__ in,
                                                     u16* __restrict__ out, int n4) {
    int i = blockIdx.x * 256 + threadIdx.x;
    int stride = gridDim.x * 256;
    for (; i < n4; i += stride) {
        float4 v = reinterpret_cast<const float4*>(in)[i];
        ushort4 o = make_ushort4(f2bf(v.x), f2bf(v.y), f2bf(v.z), f2bf(v.w));
        reinterpret_cast<ushort4*>(out)[i] = o;
    }
}

// transpose 1024x1024 f32 -> bf16 (out[n][k] = in[k][n])
__global__ __launch_bounds__(256) void k_transpose_bf16(const float* __restrict__ in,
                                                        u16* __restrict__ out) {
    __shared__ float tile[32][33];
    int bx = blockIdx.x * 32;   // col of in
    int by = blockIdx.y * 32;   // row of in
    int tx = threadIdx.x & 31;
    int ty = threadIdx.x >> 5;  // 0..7
    for (int r = ty; r < 32; r += 8)
        tile[r][tx] = in[(size_t)(by + r) * DIM + bx + tx];
    __syncthreads();
    for (int r = ty; r < 32; r += 8)
        out[(size_t)(bx + r) * DIM + by + tx] = f2bf(tile[tx][r]);
}

// ---------------------------------------------------------------------------
// LayerNorm + tau projection; writes bf16 normed + f32 tau[t][ntau]
// ---------------------------------------------------------------------------
__global__ __launch_bounds__(256) void k_ln_tau(const float* __restrict__ x,
                                                const float* __restrict__ sc,
                                                const float* __restrict__ bi,
                                                const float* __restrict__ tauk,
                                                const float* __restrict__ taub,
                                                int ntau,
                                                u16* __restrict__ nrm,
                                                float* __restrict__ tau_out) {
    __shared__ float red[4];
    int t = blockIdx.x, tid = threadIdx.x, wave = tid >> 6, lane = tid & 63;
    const float4 xv = reinterpret_cast<const float4*>(x + (size_t)t * DIM)[tid];
    float s = xv.x + xv.y + xv.z + xv.w;
    s = blockReduceF(s, red, wave, lane);
    float mean = s * (1.0f / DIM);
    float d0 = xv.x - mean, d1 = xv.y - mean, d2 = xv.z - mean, d3 = xv.w - mean;
    float ss = d0 * d0 + d1 * d1 + d2 * d2 + d3 * d3;
    ss = blockReduceF(ss, red, wave, lane);
    float rstd = rsqrtf(ss * (1.0f / DIM) + 1e-6f);
    const float4 scv = reinterpret_cast<const float4*>(sc)[tid];
    const float4 biv = reinterpret_cast<const float4*>(bi)[tid];
    float n0 = d0 * rstd * scv.x + biv.x;
    float n1 = d1 * rstd * scv.y + biv.y;
    float n2 = d2 * rstd * scv.z + biv.z;
    float n3 = d3 * rstd * scv.w + biv.w;
    ushort4 o = make_ushort4(f2bf(n0), f2bf(n1), f2bf(n2), f2bf(n3));
    reinterpret_cast<ushort4*>(nrm + (size_t)t * DIM)[tid] = o;
    int d = tid * 4;
    for (int j = 0; j < ntau; j++) {
        float p = n0 * tauk[(size_t)(d + 0) * ntau + j] + n1 * tauk[(size_t)(d + 1) * ntau + j]
                + n2 * tauk[(size_t)(d + 2) * ntau + j] + n3 * tauk[(size_t)(d + 3) * ntau + j];
        p = blockReduceF(p, red, wave, lane);
        if (tid == 0) tau_out[(size_t)t * ntau + j] = p + taub[j];
    }
}

// ---------------------------------------------------------------------------
// C[M][N] = A[M][K] @ B[N][K]^T   (bf16 in, f32 out), optional residual fuse
// m97 structure: 128x128 tile, 4 waves, 16x16x32 MFMA, BK=32,
// global_load_lds width-16 staging into linear LDS [kg(4)][row(128)][8].
// TAG only distinguishes call sites in rocprof.
// ---------------------------------------------------------------------------
template<int TAG>
__global__ __launch_bounds__(256) void k_gemm_bt(const u16* __restrict__ A,
                                                 const u16* __restrict__ B,
                                                 float* __restrict__ C,
                                                 int M, int N, int K,
                                                 const float* __restrict__ res) {
    __shared__ __align__(16) u16 As[4096];
    __shared__ __align__(16) u16 Bs[4096];
    int tid = threadIdx.x;
    int wave = tid >> 6, lane = tid & 63;
    int m0 = blockIdx.y * 128, n0 = blockIdx.x * 128;
    int wm = (wave >> 1) * 64, wn = (wave & 1) * 64;
    int kg = lane >> 4, l15 = lane & 15;

    // staging pointers (per-lane global, wave-uniform LDS)
    const u16* gA0 = A + (size_t)(m0 + lane) * K + wave * 8;
    const u16* gA1 = A + (size_t)(m0 + 64 + lane) * K + wave * 8;
    const u16* gB0 = B + (size_t)(n0 + lane) * K + wave * 8;
    const u16* gB1 = B + (size_t)(n0 + 64 + lane) * K + wave * 8;
    u16* sA0 = As + wave * 1024;
    u16* sA1 = As + wave * 1024 + 512;
    u16* sB0 = Bs + wave * 1024;
    u16* sB1 = Bs + wave * 1024 + 512;

    f32x4 acc[4][4];
#pragma unroll
    for (int i = 0; i < 4; i++)
#pragma unroll
        for (int j = 0; j < 4; j++) { f32x4 z = {0.f, 0.f, 0.f, 0.f}; acc[i][j] = z; }

    for (int k0 = 0; k0 < K; k0 += 32) {
        __syncthreads();          // previous iter's LDS reads done
        gload16(gA0 + k0, sA0);
        gload16(gA1 + k0, sA1);
        gload16(gB0 + k0, sB0);
        gload16(gB1 + k0, sB1);
        __syncthreads();          // drains vmcnt+lgkm, staging visible
        short8 af[4], bg[4];
#pragma unroll
        for (int mi = 0; mi < 4; mi++) {
            int row = wm + mi * 16 + l15;
            af[mi] = *reinterpret_cast<const short8*>(&As[(kg * 128 + row) * 8]);
        }
#pragma unroll
        for (int ni = 0; ni < 4; ni++) {
            int row = wn + ni * 16 + l15;
            bg[ni] = *reinterpret_cast<const short8*>(&Bs[(kg * 128 + row) * 8]);
        }
#pragma unroll
        for (int mi = 0; mi < 4; mi++)
#pragma unroll
            for (int ni = 0; ni < 4; ni++)
                acc[mi][ni] = mfma_bf16(af[mi], bg[ni], acc[mi][ni]);
    }
    asm volatile("s_nop 7\n\ts_nop 7");
#pragma unroll
    for (int mi = 0; mi < 4; mi++) {
#pragma unroll
        for (int ni = 0; ni < 4; ni++) {
            int col = n0 + wn + ni * 16 + l15;
#pragma unroll
            for (int r = 0; r < 4; r++) {
                int rowm = m0 + wm + mi * 16 + (lane >> 4) * 4 + r;
                size_t idx = (size_t)rowm * N + col;
                float v = acc[mi][ni][r];
                if (res) v += res[idx];
                C[idx] = v;
            }
        }
    }
}

// ---------------------------------------------------------------------------
// Top-k threshold gate, radix-select version.
// Keys = sign-flipped float bits (monotone). 4 passes of 8-bit digits:
// predicated LDS histogram + block suffix-scan -> exact kth-largest key.
// Then select keys >= thr (ties included, capacity-capped) — identical
// semantics to jax top_k + ">= thr".
// Emits sparse (idx, score*gate) lists plus bare-gate colsum atomics.
// ---------------------------------------------------------------------------
__global__ __launch_bounds__(256) void k_gate(const float* __restrict__ scores, int NC, int ksel,
                                              int row_off,
                                              const float* __restrict__ tau, int tau_stride, int tcol0,
                                              int two,
                                              int* __restrict__ sel,
                                              float* __restrict__ vA, float* __restrict__ vB,
                                              int* __restrict__ cnt,
                                              float* __restrict__ csA, float* __restrict__ csB,
                                              int cap) {
    extern __shared__ u32 keys[];
    __shared__ int   hist[256];
    __shared__ int   scnt;
    __shared__ int   dsel;
    __shared__ int   knext;
    __shared__ int   sidx[CAPK];
    __shared__ float sraw[CAPK];
    int r = blockIdx.x, tid = threadIdx.x, wave = tid >> 6, lane = tid & 63;
    int t = row_off + r;

    // stage + transform keys (vectorized)
    const float4* srow4 = reinterpret_cast<const float4*>(scores + (size_t)r * NC);
    for (int c = tid; c < NC / 4; c += 256) {
        float4 v = srow4[c];
        u32 u0 = __float_as_uint(v.x), u1 = __float_as_uint(v.y);
        u32 u2 = __float_as_uint(v.z), u3 = __float_as_uint(v.w);
        u0 = (u0 & 0x80000000u) ? ~u0 : (u0 | 0x80000000u);
        u1 = (u1 & 0x80000000u) ? ~u1 : (u1 | 0x80000000u);
        u2 = (u2 & 0x80000000u) ? ~u2 : (u2 | 0x80000000u);
        u3 = (u3 & 0x80000000u) ? ~u3 : (u3 | 0x80000000u);
        reinterpret_cast<uint4*>(keys)[c] = make_uint4(u0, u1, u2, u3);
    }
    if (tid == 0) scnt = 0;

    // ---- radix select: 4 passes of 8 bits, MSB first ----
    u32 prefix = 0;
    int krem = ksel;
#pragma unroll
    for (int pass = 0; pass < 4; pass++) {
        int shift = 24 - pass * 8;
        hist[tid] = 0;
        __syncthreads();
        u32 pmask = (pass == 0) ? 0u : (0xFFFFFFFFu << (shift + 8));
        for (int i = tid; i < NC; i += 256) {
            u32 ky = keys[i];
            if ((ky & pmask) == prefix)
                atomicAdd(&hist[(ky >> shift) & 255], 1);
        }
        __syncthreads();
        // suffix-sum: hist[d] := sum_{e>=d} hist[e]  (Hillis-Steele, 8 steps)
        int v = hist[tid];
#pragma unroll
        for (int off = 1; off < 256; off <<= 1) {
            int other = (tid + off < 256) ? hist[tid + off] : 0;
            __syncthreads();
            v += other;
            hist[tid] = v;
            __syncthreads();
        }
        int sfx = v;
        int sfx_next = (tid < 255) ? hist[tid + 1] : 0;
        if (sfx >= krem && (tid == 255 || sfx_next < krem)) {
            dsel = tid;
            knext = krem - sfx_next;
        }
        __syncthreads();
        prefix |= ((u32)dsel) << shift;
        krem = knext;
        __syncthreads();
    }
    u32 thr = prefix;   // exact kth-largest key

    // ---- select keys >= thr ----
    for (int i = tid; i < NC; i += 256) {
        u32 ky = keys[i];
        if (ky >= thr) {
            int p = atomicAdd(&scnt, 1);
            if (p < cap) {
                sidx[p] = i;
                u32 uo = (ky & 0x80000000u) ? (ky & 0x7fffffffu) : ~ky;
                sraw[p] = __uint_as_float(uo);
            }
        }
    }
    __syncthreads();
    int n = scnt < cap ? scnt : cap;
    if (tid == 0) cnt[t] = n;
    if (wave != 0) return;

    float tA = tau[(size_t)t * tau_stride + tcol0];
    float tB = two ? tau[(size_t)t * tau_stride + tcol0 + 1] : 0.f;
    float sumA = 0.f, mxA = -1e30f, sumB = 0.f, mxB = -1e30f;
    for (int i = lane; i < n; i += 64) {
        float sv = sraw[i];
        float rA = sv - tA;
        float gA = rA > 0.f ? rA : 1e-8f * expf(rA);
        float eA = expf(gA) - 1.0f;            // match reference quantization
        sumA += eA; mxA = fmaxf(mxA, eA);
        if (two) {
            float rB = sv - tB;
            float gB = rB > 0.f ? rB : 1e-8f * expf(rB);
            float eB = expf(gB) - 1.0f;
            sumB += eB; mxB = fmaxf(mxB, eB);
        }
    }
#pragma unroll
    for (int off = 32; off > 0; off >>= 1) {
        sumA += __shfl_xor(sumA, off); mxA = fmaxf(mxA, __shfl_xor(mxA, off));
        sumB += __shfl_xor(sumB, off); mxB = fmaxf(mxB, __shfl_xor(mxB, off));
    }
    float fA = tanhf(mxA) / (sumA + 1e-8f);
    float fB = tanhf(mxB) / (sumB + 1e-8f);
    for (int i = lane; i < n; i += 64) {
        float sv = sraw[i]; int ci = sidx[i];
        float rA = sv - tA;
        float gA = rA > 0.f ? rA : 1e-8f * expf(rA);
        float ga = (expf(gA) - 1.0f) * fA;     // bare gate (aux loss)
        sel[(size_t)t * cap + i] = ci;
        vA[(size_t)t * cap + i] = ga * sv;     // emit weight = score * gate
        atomicAdd(&csA[ci], ga);
        if (two) {
            float rB = sv - tB;
            float gB = rB > 0.f ? rB : 1e-8f * expf(rB);
            float gb = (expf(gB) - 1.0f) * fB;
            vB[(size_t)t * cap + i] = gb * sv;
            atomicAdd(&csB[ci], gb);
        }
    }
}

// ---------------------------------------------------------------------------
// Sparse emits (bf16 weights, bf16 out):  O[t] = sum_s val[s] * w[idx[s]]
// ---------------------------------------------------------------------------
__global__ __launch_bounds__(256) void k_gather2(const u16* __restrict__ w,
                                                 const int* __restrict__ sel,
                                                 const float* __restrict__ vA,
                                                 const float* __restrict__ vB,
                                                 const int* __restrict__ cnt, int cap,
                                                 u16* __restrict__ OA, u16* __restrict__ OB) {
    __shared__ int   sI[CAPK];
    __shared__ float sA[CAPK];
    __shared__ float sB[CAPK];
    int t = blockIdx.x, tid = threadIdx.x;
    int n = cnt[t];
    if (tid < n) { sI[tid] = sel[(size_t)t * cap + tid]; sA[tid] = vA[(size_t)t * cap + tid]; sB[tid] = vB[(size_t)t * cap + tid]; }
    __syncthreads();
    float a0 = 0, a1 = 0, a2 = 0, a3 = 0, b0 = 0, b1 = 0, b2 = 0, b3 = 0;
    for (int s = 0; s < n; s++) {
        const ushort4 wv = reinterpret_cast<const ushort4*>(w + (size_t)sI[s] * DIM)[tid];
        float w0 = bf2f(wv.x), w1 = bf2f(wv.y), w2 = bf2f(wv.z), w3 = bf2f(wv.w);
        float va = sA[s], vb = sB[s];
        a0 += va * w0; a1 += va * w1; a2 += va * w2; a3 += va * w3;
        b0 += vb * w0; b1 += vb * w1; b2 += vb * w2; b3 += vb * w3;
    }
    reinterpret_cast<ushort4*>(OA + (size_t)t * DIM)[tid] = make_ushort4(f2bf(a0), f2bf(a1), f2bf(a2), f2bf(a3));
    reinterpret_cast<ushort4*>(OB + (size_t)t * DIM)[tid] = make_ushort4(f2bf(b0), f2bf(b1), f2bf(b2), f2bf(b3));
}

__global__ __launch_bounds__(256) void k_gather1(const u16* __restrict__ w,
                                                 const int* __restrict__ sel,
                                                 const float* __restrict__ vv,
                                                 const int* __restrict__ cnt, int cap,
                                                 u16* __restrict__ O) {
    __shared__ int   sI[CAPK];
    __shared__ float sV[CAPK];
    int t = blockIdx.x, tid = threadIdx.x;
    int n = cnt[t];
    if (tid < n) { sI[tid] = sel[(size_t)t * cap + tid]; sV[tid] = vv[(size_t)t * cap + tid]; }
    __syncthreads();
    float a0 = 0, a1 = 0, a2 = 0, a3 = 0;
    for (int s = 0; s < n; s++) {
        const ushort4 wv = reinterpret_cast<const ushort4*>(w + (size_t)sI[s] * DIM)[tid];
        float va = sV[s];
        a0 += va * bf2f(wv.x); a1 += va * bf2f(wv.y); a2 += va * bf2f(wv.z); a3 += va * bf2f(wv.w);
    }
    reinterpret_cast<ushort4*>(O + (size_t)t * DIM)[tid] = make_ushort4(f2bf(a0), f2bf(a1), f2bf(a2), f2bf(a3));
}

// know emit fused with final residual: io[t] += sum val*w (bf16 weights)
__global__ __launch_bounds__(256) void k_gather_final(const u16* __restrict__ w,
                                                      const int* __restrict__ sel,
                                                      const float* __restrict__ vv,
                                                      const int* __restrict__ cnt, int cap,
                                                      float* __restrict__ io) {
    __shared__ int   sI[CAPK];
    __shared__ float sV[CAPK];
    int t = blockIdx.x, tid = threadIdx.x;
    int n = cnt[t];
    if (tid < n) { sI[tid] = sel[(size_t)t * cap + tid]; sV[tid] = vv[(size_t)t * cap + tid]; }
    __syncthreads();
    float4 base = reinterpret_cast<const float4*>(io + (size_t)t * DIM)[tid];
    float a0 = base.x, a1 = base.y, a2 = base.z, a3 = base.w;
    for (int s = 0; s < n; s++) {
        const ushort4 wv = reinterpret_cast<const ushort4*>(w + (size_t)sI[s] * DIM)[tid];
        float va = sV[s];
        a0 += va * bf2f(wv.x); a1 += va * bf2f(wv.y); a2 += va * bf2f(wv.z); a3 += va * bf2f(wv.w);
    }
    reinterpret_cast<float4*>(io + (size_t)t * DIM)[tid] = make_float4(a0, a1, a2, a3);
}

// ---------------------------------------------------------------------------
// Causal flash attention, bf16 MFMA (16x16x32).
// Block = 256 thr / 4 waves, one (b,h), 64 q rows (16 per wave).
// ---------------------------------------------------------------------------
__global__ __launch_bounds__(256) void k_attn(const u16* __restrict__ Q,
                                              const u16* __restrict__ K,
                                              const u16* __restrict__ V,
                                              u16* __restrict__ O) {
    __shared__ __align__(16) u16 Qs[64 * APAD];
    __shared__ __align__(16) u16 Ks[64 * APAD];
    __shared__ __align__(16) u16 Vt[64 * APAD];
    __shared__ __align__(16) u16 Ps[4][16 * APAD];
    int tid = threadIdx.x, wave = tid >> 6, lane = tid & 63;
    int h = blockIdx.x, bb = blockIdx.y, qt = blockIdx.z;
    int q0 = qt * 64;
    size_t base = ((size_t)bb * SLEN) * DIM + (size_t)h * DH;
    int sr = tid >> 2, sc = (tid & 3) * 16;     // staging row (0..63), col (0/16/32/48)
    int g = lane >> 4, l15 = lane & 15;

    // stage Q tile once
    {
        const u16* qp = Q + base + (size_t)(q0 + sr) * DIM + sc;
        *reinterpret_cast<short8*>(&Qs[sr * APAD + sc])     = *reinterpret_cast<const short8*>(qp);
        *reinterpret_cast<short8*>(&Qs[sr * APAD + sc + 8]) = *reinterpret_cast<const short8*>(qp + 8);
    }
    __syncthreads();
    short8 qa0 = *reinterpret_cast<const short8*>(&Qs[(wave * 16 + l15) * APAD + g * 8]);
    short8 qa1 = *reinterpret_cast<const short8*>(&Qs[(wave * 16 + l15) * APAD + 32 + g * 8]);

    float m[4], l[4];
    f32x4 oacc[4];
#pragma unroll
    for (int i = 0; i < 4; i++) {
        m[i] = -1e30f; l[i] = 0.f;
        f32x4 z = {0.f, 0.f, 0.f, 0.f}; oacc[i] = z;
    }
    u16* pw = &Ps[wave][0];

    for (int kc = 0; kc <= qt; kc++) {
        __syncthreads();
        // ---- stage K [key][dim] and V transposed [dim][key] ----
        {
            const u16* kp = K + base + (size_t)(kc * 64 + sr) * DIM + sc;
            *reinterpret_cast<short8*>(&Ks[sr * APAD + sc])     = *reinterpret_cast<const short8*>(kp);
            *reinterpret_cast<short8*>(&Ks[sr * APAD + sc + 8]) = *reinterpret_cast<const short8*>(kp + 8);
            const u16* vp = V + base + (size_t)(kc * 64 + sr) * DIM + sc;
            short8 w0 = *reinterpret_cast<const short8*>(vp);
            short8 w1 = *reinterpret_cast<const short8*>(vp + 8);
            const u16* w0p = reinterpret_cast<const u16*>(&w0);
            const u16* w1p = reinterpret_cast<const u16*>(&w1);
#pragma unroll
            for (int j = 0; j < 16; j++) {
                int d = sc + j;
                int phys = (((sr >> 3) + d + (d >> 4)) & 7);   // rotate key-blocks per dim
                Vt[d * APAD + phys * 8 + (sr & 7)] = (j < 8) ? w0p[j] : w1p[j - 8];
            }
        }
        __syncthreads();

        // ---- QK^T: 8 MFMAs -> s4[ks] (q_local = wave*16 + g*4 + r, key = ks*16 + l15)
        f32x4 s4[4];
#pragma unroll
        for (int ks = 0; ks < 4; ks++) {
            f32x4 z = {0.f, 0.f, 0.f, 0.f}; s4[ks] = z;
            short8 kb0 = *reinterpret_cast<const short8*>(&Ks[(ks * 16 + l15) * APAD + g * 8]);
            short8 kb1 = *reinterpret_cast<const short8*>(&Ks[(ks * 16 + l15) * APAD + 32 + g * 8]);
            s4[ks] = mfma_bf16(qa0, kb0, s4[ks]);
            s4[ks] = mfma_bf16(qa1, kb1, s4[ks]);
        }
        asm volatile("s_nop 7\n\ts_nop 7");   // MFMA -> VALU read hazard

        // ---- scale + causal mask ----
        int key_base = kc * 64 + l15;
#pragma unroll
        for (int ks = 0; ks < 4; ks++) {
            int key = key_base + ks * 16;
#pragma unroll
            for (int r = 0; r < 4; r++) {
                int q_abs = q0 + wave * 16 + g * 4 + r;
                float sv = s4[ks][r] * 0.125f;
                s4[ks][r] = (key > q_abs) ? -1e30f : sv;
            }
        }

        // ---- online softmax per q-row; write P (bf16) to per-wave LDS ----
#pragma unroll
        for (int r = 0; r < 4; r++) {
            float mx = fmaxf(fmaxf(s4[0][r], s4[1][r]), fmaxf(s4[2][r], s4[3][r]));
            mx = fmaxf(mx, __shfl_xor(mx, 1));
            mx = fmaxf(mx, __shfl_xor(mx, 2));
            mx = fmaxf(mx, __shfl_xor(mx, 4));
            mx = fmaxf(mx, __shfl_xor(mx, 8));
            float mnew = fmaxf(m[r], mx);
            float al = __expf(m[r] - mnew);
            m[r] = mnew;
            float p0 = __expf(s4[0][r] - mnew);
            float p1 = __expf(s4[1][r] - mnew);
            float p2 = __expf(s4[2][r] - mnew);
            float p3 = __expf(s4[3][r] - mnew);
            float ps = p0 + p1 + p2 + p3;
            ps += __shfl_xor(ps, 1);
            ps += __shfl_xor(ps, 2);
            ps += __shfl_xor(ps, 4);
            ps += __shfl_xor(ps, 8);
            l[r] = l[r] * al + ps;
#pragma unroll
            for (int ds_ = 0; ds_ < 4; ds_++) oacc[ds_][r] *= al;
            int row = g * 4 + r;
            pw[row * APAD +  0 + l15] = f2bf(p0);
            pw[row * APAD + 16 + l15] = f2bf(p1);
            pw[row * APAD + 32 + l15] = f2bf(p2);
            pw[row * APAD + 48 + l15] = f2bf(p3);
        }

        // ---- PV: read P as A-fragments, V^T as B-fragments; 8 MFMAs ----
        short8 pa0 = *reinterpret_cast<const short8*>(&pw[l15 * APAD + g * 8]);
        short8 pa1 = *reinterpret_cast<const short8*>(&pw[l15 * APAD + 32 + g * 8]);
#pragma unroll
        for (int dsub = 0; dsub < 4; dsub++) {
            int d = dsub * 16 + l15;
            int rot = d + (d >> 4);
            short8 vb0 = *reinterpret_cast<const short8*>(&Vt[d * APAD + (((0 + g) + rot) & 7) * 8]);
            short8 vb1 = *reinterpret_cast<const short8*>(&Vt[d * APAD + (((4 + g) + rot) & 7) * 8]);
            oacc[dsub] = mfma_bf16(pa0, vb0, oacc[dsub]);
            oacc[dsub] = mfma_bf16(pa1, vb1, oacc[dsub]);
        }
    }
    asm volatile("s_nop 7\n\ts_nop 7");       // MFMA -> VALU read hazard

    // ---- epilogue: O = oacc / l, bf16 ----
#pragma unroll
    for (int r = 0; r < 4; r++) {
        float inv = 1.0f / l[r];
        int row = q0 + wave * 16 + g * 4 + r;
#pragma unroll
        for (int dsub = 0; dsub < 4; dsub++) {
            O[base + (size_t)row * DIM + dsub * 16 + l15] = f2bf(oacc[dsub][r] * inv);
        }
    }
}

// ---------------------------------------------------------------------------
// aux = sum over gate columns of (colsum/T - 1/N)^2 * N
// ---------------------------------------------------------------------------
__global__ __launch_bounds__(256) void k_aux(const float* __restrict__ cs,
                                             float* __restrict__ out_aux) {
    __shared__ float red[4];
    int gtid = blockIdx.x * 256 + threadIdx.x;
    float acc = 0.f;
    for (int i = gtid; i < 3 * 4096 + 8192; i += gridDim.x * 256) {
        float mean = cs[i] * (1.0f / 4096.0f);
        float tN, Nf;
        if (i < 12288) { tN = 1.0f / 4096.0f; Nf = 4096.0f; }
        else           { tN = 1.0f / 8192.0f; Nf = 8192.0f; }
        float d = mean - tN;
        acc += d * d * Nf;
    }
    acc = blockReduceF(acc, red, threadIdx.x >> 6, threadIdx.x & 63);
    if (threadIdx.x == 0) atomicAdd(out_aux, acc);
}

// ---------------------------------------------------------------------------
extern "C" void kernel_launch(void* const* d_in, const int* in_sizes, int n_in,
                              void* d_out, int out_size, void* d_ws, size_t ws_size,
                              hipStream_t stream) {
    const float* x         = (const float*)d_in[0];
    const float* qk_emb    = (const float*)d_in[1];
    const float* qk_w      = (const float*)d_in[2];
    const float* v_emb     = (const float*)d_in[3];
    const float* v_w       = (const float*)d_in[4];
    const float* know_emb  = (const float*)d_in[5];
    const float* know_w    = (const float*)d_in[6];
    const float* tau_attn_k = (const float*)d_in[7];
    const float* tau_attn_b = (const float*)d_in[8];
    const float* tau_know_k = (const float*)d_in[9];
    const float* tau_know_b = (const float*)d_in[10];
    const float* expand_O  = (const float*)d_in[11];
    const float* ln1_s     = (const float*)d_in[12];
    const float* ln1_b     = (const float*)d_in[13];
    const float* ln2_s     = (const float*)d_in[14];
    const float* ln2_b     = (const float*)d_in[15];
    float* out = (float*)d_out;
    char*  ws  = (char*)d_ws;

    // workspace layout (bytes)
    u16*   nrm_bf   = (u16*)(ws + 0);                 //  8 MB
    u16*   qkemb_bf = (u16*)(ws + 8388608);           //  8 MB
    u16*   vemb_bf  = (u16*)(ws + 16777216);          //  8 MB
    u16*   knemb_bf = (u16*)(ws + 25165824);          // 16 MB
    u16*   expT_bf  = (u16*)(ws + 41943040);          //  2 MB
    u16*   attn_bf  = (u16*)(ws + 44040192);          //  8 MB
    u16*   qkw_bf   = (u16*)(ws + 52428800);          //  8 MB
    u16*   vw_bf    = (u16*)(ws + 60817408);          //  8 MB
    u16*   knw_bf   = (u16*)(ws + 69206016);          // 16 MB
    u16*   Qb       = (u16*)(ws + 85983232);          //  8 MB (bf16)
    u16*   Kb       = (u16*)(ws + 94371840);          //  8 MB (bf16)
    u16*   Vb       = (u16*)(ws + 102760448);         //  8 MB (bf16)
    float* scores   = (float*)(ws + 111149056);       // 64 MB
    int*   selQK    = (int*)(ws + 178257920);
    float* valQ     = (float*)(ws + 179044352);
    float* valK     = (float*)(ws + 179830784);
    int*   selV     = (int*)(ws + 180617216);
    float* valV     = (float*)(ws + 181403648);
    int*   selKn    = (int*)(ws + 182190080);
    float* valKn    = (float*)(ws + 183762944);
    int*   cntQK    = (int*)(ws + 185335808);
    int*   cntV     = (int*)(ws + 185352192);
    int*   cntKn    = (int*)(ws + 185368576);
    float* tauA     = (float*)(ws + 185384960);       // [T][3]
    float* tauKn    = (float*)(ws + 185434112);       // [T]
    float* colsum   = (float*)(ws + 185450496);       // 20480 floats: Q,K,V,Kn
    const size_t WS_NEEDED = 185532416;
    if (ws_size < WS_NEEDED) return;   // workspace too small — bail cleanly

    float* colQ = colsum, *colK = colsum + 4096, *colV = colsum + 8192, *colKn = colsum + 12288;

    hipMemsetAsync(colsum, 0, 20480 * sizeof(float), stream);
    hipMemsetAsync(out + (size_t)TOK * DIM, 0, sizeof(float), stream);

    // bf16 conversions (embeddings + weights)
    k_f32_to_bf16<<<1024, 256, 0, stream>>>(qk_emb,  qkemb_bf, NQK * DIM / 4);
    k_f32_to_bf16<<<1024, 256, 0, stream>>>(v_emb,   vemb_bf,  NV * DIM / 4);
    k_f32_to_bf16<<<2048, 256, 0, stream>>>(know_emb, knemb_bf, NKN * DIM / 4);
    k_f32_to_bf16<<<1024, 256, 0, stream>>>(qk_w,   qkw_bf, NQK * DIM / 4);
    k_f32_to_bf16<<<1024, 256, 0, stream>>>(v_w,    vw_bf,  NV * DIM / 4);
    k_f32_to_bf16<<<2048, 256, 0, stream>>>(know_w, knw_bf, NKN * DIM / 4);
    k_transpose_bf16<<<dim3(32, 32), 256, 0, stream>>>(expand_O, expT_bf);

    // LN1 + tau(3)
    k_ln_tau<<<TOK, 256, 0, stream>>>(x, ln1_s, ln1_b, tau_attn_k, tau_attn_b, 3, nrm_bf, tauA);

    // scores_qk + gate (g_Q, g_K share selection)
    k_gemm_bt<0><<<dim3(NQK / 128, TOK / 128), 256, 0, stream>>>(nrm_bf, qkemb_bf, scores, TOK, NQK, DIM, nullptr);
    k_gate<<<TOK, 256, NQK * sizeof(u32), stream>>>(scores, NQK, 32, 0, tauA, 3, 0, 1,
                                                    selQK, valQ, valK, cntQK, colQ, colK, CAPA);
    // scores_v + gate (g_V)
    k_gemm_bt<1><<<dim3(NV / 128, TOK / 128), 256, 0, stream>>>(nrm_bf, vemb_bf, scores, TOK, NV, DIM, nullptr);
    k_gate<<<TOK, 256, NV * sizeof(u32), stream>>>(scores, NV, 32, 0, tauA, 3, 2, 0,
                                                   selV, valV, nullptr, cntV, colV, nullptr, CAPA);

    // sparse emits Q, K, V (bf16 weights -> bf16 out)
    k_gather2<<<TOK, 256, 0, stream>>>(qkw_bf, selQK, valQ, valK, cntQK, CAPA, Qb, Kb);
    k_gather1<<<TOK, 256, 0, stream>>>(vw_bf, selV, valV, cntV, CAPA, Vb);

    // causal MHA (bf16 MFMA) -> bf16
    k_attn<<<dim3(NH, 2, SLEN / 64), 256, 0, stream>>>(Qb, Kb, Vb, attn_bf);

    // out @ expand_O + residual x  -> x1 (stored in d_out)
    k_gemm_bt<2><<<dim3(DIM / 128, TOK / 128), 256, 0, stream>>>(attn_bf, expT_bf, out, TOK, DIM, DIM, x);

    // LN2 + tau_know
    k_ln_tau<<<TOK, 256, 0, stream>>>(out, ln2_s, ln2_b, tau_know_k, tau_know_b, 1, nrm_bf, tauKn);

    // know scores + gate, in 2 token chunks (scores buffer = 64 MB)
    for (int c = 0; c < 2; c++) {
        k_gemm_bt<3><<<dim3(NKN / 128, 2048 / 128), 256, 0, stream>>>(
            nrm_bf + (size_t)c * 2048 * DIM, knemb_bf, scores, 2048, NKN, DIM, nullptr);
        k_gate<<<2048, 256, NKN * sizeof(u32), stream>>>(scores, NKN, 64, c * 2048, tauKn, 1, 0, 0,
                                                         selKn, valKn, nullptr, cntKn, colKn, nullptr, CAPK);
    }

    // know emit + final residual (in place on d_out)
    k_gather_final<<<TOK, 256, 0, stream>>>(knw_bf, selKn, valKn, cntKn, CAPK, out);

    // aux scalar
    k_aux<<<20, 256, 0, stream>>>(colsum, out + (size_t)TOK * DIM);
}

// Round 6
// 818.637 us; speedup vs baseline: 2.1723x; 1.0296x over previous
//
#include <hip/hip_runtime.h>

// ---------------------------------------------------------------------------
// Problem constants (fixed by the reference)
// ---------------------------------------------------------------------------
#define TOK   4096      // B*S
#define DIM   1024
#define NQK   4096
#define NV    4096
#define NKN   8192
#define SLEN  2048
#define NH    16
#define DH    64
#define CAPA  48        // capacity for k=32 gates (slack for ties)
#define CAPK  96        // capacity for k=64 gate
#define APAD  72        // attn LDS row pad (bf16 elems): 144B keeps b128 align

typedef float  f32x4  __attribute__((ext_vector_type(4)));
typedef short  short8 __attribute__((ext_vector_type(8)));
typedef unsigned int  u32;
typedef unsigned short u16;

__device__ __forceinline__ u16 f2bf(float f) {
    u32 u = __float_as_uint(f);
    u32 r = (u + 0x7fffu + ((u >> 16) & 1u)) >> 16;
    return (u16)r;
}
__device__ __forceinline__ float bf2f(u16 v) { return __uint_as_float(((u32)v) << 16); }

// monotone bf16 -> u16 key (order-preserving over floats)
__device__ __forceinline__ u16 bfkey(u16 b) {
    return (b & 0x8000u) ? (u16)(~b) : (u16)(b | 0x8000u);
}
// inverse: key -> bf16 bits
__device__ __forceinline__ u16 keybf(u16 k) {
    return (k & 0x8000u) ? (u16)(k & 0x7fffu) : (u16)(~k);
}

__device__ __forceinline__ f32x4 mfma_bf16(short8 a, short8 b, f32x4 c) {
    asm volatile("v_mfma_f32_16x16x32_bf16 %0, %1, %2, %0"
                 : "+v"(c) : "v"(a), "v"(b));
    return c;
}

// async global->LDS, 16B per lane; LDS dest = wave-uniform base + lane*16
__device__ __forceinline__ void gload16(const u16* g, u16* s) {
    __builtin_amdgcn_global_load_lds((const __attribute__((address_space(1))) void*)g,
                                     (__attribute__((address_space(3))) void*)s, 16, 0, 0);
}

__device__ __forceinline__ float blockReduceF(float v, float* red, int wave, int lane) {
#pragma unroll
    for (int off = 32; off > 0; off >>= 1) v += __shfl_xor(v, off);
    __syncthreads();
    if (lane == 0) red[wave] = v;
    __syncthreads();
    return red[0] + red[1] + red[2] + red[3];
}

// ---------------------------------------------------------------------------
// fused f32 -> bf16 conversion of all six tables (one launch)
// sizes in float4 units: qk_emb 1M, v_emb 1M, know_emb 2M, qk_w 1M, v_w 1M,
// know_w 2M  (total 8M float4s)
// ---------------------------------------------------------------------------
__global__ __launch_bounds__(256) void k_convert_all(const float* __restrict__ p0,
                                                     const float* __restrict__ p1,
                                                     const float* __restrict__ p2,
                                                     const float* __restrict__ p3,
                                                     const float* __restrict__ p4,
                                                     const float* __restrict__ p5,
                                                     u16* __restrict__ o0, u16* __restrict__ o1,
                                                     u16* __restrict__ o2, u16* __restrict__ o3,
                                                     u16* __restrict__ o4, u16* __restrict__ o5) {
    const int S0 = 1048576, S1 = 2097152, S2 = 4194304, S3 = 5242880, S4 = 6291456, S5 = 8388608;
    for (int i = blockIdx.x * 256 + threadIdx.x; i < S5; i += gridDim.x * 256) {
        const float* in; u16* out; int off;
        if (i < S0)      { in = p0; out = o0; off = i; }
        else if (i < S1) { in = p1; out = o1; off = i - S0; }
        else if (i < S2) { in = p2; out = o2; off = i - S1; }
        else if (i < S3) { in = p3; out = o3; off = i - S2; }
        else if (i < S4) { in = p4; out = o4; off = i - S3; }
        else             { in = p5; out = o5; off = i - S4; }
        float4 v = reinterpret_cast<const float4*>(in)[off];
        reinterpret_cast<ushort4*>(out)[off] = make_ushort4(f2bf(v.x), f2bf(v.y), f2bf(v.z), f2bf(v.w));
    }
}

// transpose 1024x1024 f32 -> bf16 (out[n][k] = in[k][n])
__global__ __launch_bounds__(256) void k_transpose_bf16(const float* __restrict__ in,
                                                        u16* __restrict__ out) {
    __shared__ float tile[32][33];
    int bx = blockIdx.x * 32;   // col of in
    int by = blockIdx.y * 32;   // row of in
    int tx = threadIdx.x & 31;
    int ty = threadIdx.x >> 5;  // 0..7
    for (int r = ty; r < 32; r += 8)
        tile[r][tx] = in[(size_t)(by + r) * DIM + bx + tx];
    __syncthreads();
    for (int r = ty; r < 32; r += 8)
        out[(size_t)(bx + r) * DIM + by + tx] = f2bf(tile[tx][r]);
}

// ---------------------------------------------------------------------------
// LayerNorm + tau projection; writes bf16 normed + f32 tau[t][ntau]
// ---------------------------------------------------------------------------
__global__ __launch_bounds__(256) void k_ln_tau(const float* __restrict__ x,
                                                const float* __restrict__ sc,
                                                const float* __restrict__ bi,
                                                const float* __restrict__ tauk,
                                                const float* __restrict__ taub,
                                                int ntau,
                                                u16* __restrict__ nrm,
                                                float* __restrict__ tau_out) {
    __shared__ float red[4];
    int t = blockIdx.x, tid = threadIdx.x, wave = tid >> 6, lane = tid & 63;
    const float4 xv = reinterpret_cast<const float4*>(x + (size_t)t * DIM)[tid];
    float s = xv.x + xv.y + xv.z + xv.w;
    s = blockReduceF(s, red, wave, lane);
    float mean = s * (1.0f / DIM);
    float d0 = xv.x - mean, d1 = xv.y - mean, d2 = xv.z - mean, d3 = xv.w - mean;
    float ss = d0 * d0 + d1 * d1 + d2 * d2 + d3 * d3;
    ss = blockReduceF(ss, red, wave, lane);
    float rstd = rsqrtf(ss * (1.0f / DIM) + 1e-6f);
    const float4 scv = reinterpret_cast<const float4*>(sc)[tid];
    const float4 biv = reinterpret_cast<const float4*>(bi)[tid];
    float n0 = d0 * rstd * scv.x + biv.x;
    float n1 = d1 * rstd * scv.y + biv.y;
    float n2 = d2 * rstd * scv.z + biv.z;
    float n3 = d3 * rstd * scv.w + biv.w;
    ushort4 o = make_ushort4(f2bf(n0), f2bf(n1), f2bf(n2), f2bf(n3));
    reinterpret_cast<ushort4*>(nrm + (size_t)t * DIM)[tid] = o;
    int d = tid * 4;
    for (int j = 0; j < ntau; j++) {
        float p = n0 * tauk[(size_t)(d + 0) * ntau + j] + n1 * tauk[(size_t)(d + 1) * ntau + j]
                + n2 * tauk[(size_t)(d + 2) * ntau + j] + n3 * tauk[(size_t)(d + 3) * ntau + j];
        p = blockReduceF(p, red, wave, lane);
        if (tid == 0) tau_out[(size_t)t * ntau + j] = p + taub[j];
    }
}

// ---------------------------------------------------------------------------
// C = A[M][K] @ B[N][K]^T  (bf16 in).  KEYOUT=0: f32 out (+res fuse).
// KEYOUT=1: write u16 monotone keys of bf16(score) for radix-select gates.
// m97 structure: 128x128 tile, 4 waves, 16x16x32 MFMA, BK=32,
// global_load_lds width-16 staging into linear LDS [kg(4)][row(128)][8].
// ---------------------------------------------------------------------------
template<int TAG, int KEYOUT>
__global__ __launch_bounds__(256) void k_gemm_bt(const u16* __restrict__ A,
                                                 const u16* __restrict__ B,
                                                 void* __restrict__ Cv,
                                                 int M, int N, int K,
                                                 const float* __restrict__ res) {
    __shared__ __align__(16) u16 As[4096];
    __shared__ __align__(16) u16 Bs[4096];
    int tid = threadIdx.x;
    int wave = tid >> 6, lane = tid & 63;
    int m0 = blockIdx.y * 128, n0 = blockIdx.x * 128;
    int wm = (wave >> 1) * 64, wn = (wave & 1) * 64;
    int kg = lane >> 4, l15 = lane & 15;

    const u16* gA0 = A + (size_t)(m0 + lane) * K + wave * 8;
    const u16* gA1 = A + (size_t)(m0 + 64 + lane) * K + wave * 8;
    const u16* gB0 = B + (size_t)(n0 + lane) * K + wave * 8;
    const u16* gB1 = B + (size_t)(n0 + 64 + lane) * K + wave * 8;
    u16* sA0 = As + wave * 1024;
    u16* sA1 = As + wave * 1024 + 512;
    u16* sB0 = Bs + wave * 1024;
    u16* sB1 = Bs + wave * 1024 + 512;

    f32x4 acc[4][4];
#pragma unroll
    for (int i = 0; i < 4; i++)
#pragma unroll
        for (int j = 0; j < 4; j++) { f32x4 z = {0.f, 0.f, 0.f, 0.f}; acc[i][j] = z; }

    for (int k0 = 0; k0 < K; k0 += 32) {
        __syncthreads();
        gload16(gA0 + k0, sA0);
        gload16(gA1 + k0, sA1);
        gload16(gB0 + k0, sB0);
        gload16(gB1 + k0, sB1);
        __syncthreads();
        short8 af[4], bg[4];
#pragma unroll
        for (int mi = 0; mi < 4; mi++) {
            int row = wm + mi * 16 + l15;
            af[mi] = *reinterpret_cast<const short8*>(&As[(kg * 128 + row) * 8]);
        }
#pragma unroll
        for (int ni = 0; ni < 4; ni++) {
            int row = wn + ni * 16 + l15;
            bg[ni] = *reinterpret_cast<const short8*>(&Bs[(kg * 128 + row) * 8]);
        }
#pragma unroll
        for (int mi = 0; mi < 4; mi++)
#pragma unroll
            for (int ni = 0; ni < 4; ni++)
                acc[mi][ni] = mfma_bf16(af[mi], bg[ni], acc[mi][ni]);
    }
    asm volatile("s_nop 7\n\ts_nop 7");
#pragma unroll
    for (int mi = 0; mi < 4; mi++) {
#pragma unroll
        for (int ni = 0; ni < 4; ni++) {
            int col = n0 + wn + ni * 16 + l15;
#pragma unroll
            for (int r = 0; r < 4; r++) {
                int rowm = m0 + wm + mi * 16 + (lane >> 4) * 4 + r;
                size_t idx = (size_t)rowm * N + col;
                float v = acc[mi][ni][r];
                if (KEYOUT) {
                    ((u16*)Cv)[idx] = bfkey(f2bf(v));
                } else {
                    if (res) v += res[idx];
                    ((float*)Cv)[idx] = v;
                }
            }
        }
    }
}

// ---------------------------------------------------------------------------
// Top-k threshold gate over u16 keys (monotone bf16). 2-pass radix select
// (8-bit digits) via predicated LDS histogram + suffix-scan -> exact
// kth-largest key; select keys >= thr (ties included, capacity-capped).
// Emits sparse (idx, score*gate) lists plus bare-gate colsum atomics.
// ---------------------------------------------------------------------------
__global__ __launch_bounds__(256) void k_gate(const u16* __restrict__ keys_g, int NC, int ksel,
                                              int row_off,
                                              const float* __restrict__ tau, int tau_stride, int tcol0,
                                              int two,
                                              int* __restrict__ sel,
                                              float* __restrict__ vA, float* __restrict__ vB,
                                              int* __restrict__ cnt,
                                              float* __restrict__ csA, float* __restrict__ csB,
                                              int cap) {
    extern __shared__ u16 keys[];
    __shared__ int   hist[256];
    __shared__ int   scnt;
    __shared__ int   dsel;
    __shared__ int   knext;
    __shared__ int   sidx[CAPK];
    __shared__ float sraw[CAPK];
    int r = blockIdx.x, tid = threadIdx.x, wave = tid >> 6, lane = tid & 63;
    int t = row_off + r;

    // stage keys (uint4 = 8 keys)
    const uint4* srow8 = reinterpret_cast<const uint4*>(keys_g + (size_t)r * NC);
    for (int c = tid; c < NC / 8; c += 256)
        reinterpret_cast<uint4*>(keys)[c] = srow8[c];
    if (tid == 0) scnt = 0;

    // ---- radix select: 2 passes of 8 bits, MSB first ----
    u32 prefix = 0;
    int krem = ksel;
#pragma unroll
    for (int pass = 0; pass < 2; pass++) {
        int shift = 8 - pass * 8;
        hist[tid] = 0;
        __syncthreads();
        u32 pmask = (pass == 0) ? 0u : 0xFF00u;
        for (int i = tid; i < NC; i += 256) {
            u32 ky = keys[i];
            if ((ky & pmask) == prefix)
                atomicAdd(&hist[(ky >> shift) & 255], 1);
        }
        __syncthreads();
        // suffix-sum: hist[d] := sum_{e>=d} hist[e]
        int v = hist[tid];
#pragma unroll
        for (int off = 1; off < 256; off <<= 1) {
            int other = (tid + off < 256) ? hist[tid + off] : 0;
            __syncthreads();
            v += other;
            hist[tid] = v;
            __syncthreads();
        }
        int sfx = v;
        int sfx_next = (tid < 255) ? hist[tid + 1] : 0;
        if (sfx >= krem && (tid == 255 || sfx_next < krem)) {
            dsel = tid;
            knext = krem - sfx_next;
        }
        __syncthreads();
        prefix |= ((u32)dsel) << shift;
        krem = knext;
        __syncthreads();
    }
    u32 thr = prefix;   // exact kth-largest u16 key

    // ---- select keys >= thr ----
    for (int i = tid; i < NC; i += 256) {
        u32 ky = keys[i];
        if (ky >= thr) {
            int p = atomicAdd(&scnt, 1);
            if (p < cap) {
                sidx[p] = i;
                sraw[p] = bf2f(keybf((u16)ky));
            }
        }
    }
    __syncthreads();
    int n = scnt < cap ? scnt : cap;
    if (tid == 0) cnt[t] = n;
    if (wave != 0) return;

    float tA = tau[(size_t)t * tau_stride + tcol0];
    float tB = two ? tau[(size_t)t * tau_stride + tcol0 + 1] : 0.f;
    float sumA = 0.f, mxA = -1e30f, sumB = 0.f, mxB = -1e30f;
    for (int i = lane; i < n; i += 64) {
        float sv = sraw[i];
        float rA = sv - tA;
        float gA = rA > 0.f ? rA : 1e-8f * expf(rA);
        float eA = expf(gA) - 1.0f;            // match reference quantization
        sumA += eA; mxA = fmaxf(mxA, eA);
        if (two) {
            float rB = sv - tB;
            float gB = rB > 0.f ? rB : 1e-8f * expf(rB);
            float eB = expf(gB) - 1.0f;
            sumB += eB; mxB = fmaxf(mxB, eB);
        }
    }
#pragma unroll
    for (int off = 32; off > 0; off >>= 1) {
        sumA += __shfl_xor(sumA, off); mxA = fmaxf(mxA, __shfl_xor(mxA, off));
        sumB += __shfl_xor(sumB, off); mxB = fmaxf(mxB, __shfl_xor(mxB, off));
    }
    float fA = tanhf(mxA) / (sumA + 1e-8f);
    float fB = tanhf(mxB) / (sumB + 1e-8f);
    for (int i = lane; i < n; i += 64) {
        float sv = sraw[i]; int ci = sidx[i];
        float rA = sv - tA;
        float gA = rA > 0.f ? rA : 1e-8f * expf(rA);
        float ga = (expf(gA) - 1.0f) * fA;     // bare gate (aux loss)
        sel[(size_t)t * cap + i] = ci;
        vA[(size_t)t * cap + i] = ga * sv;     // emit weight = score * gate
        atomicAdd(&csA[ci], ga);
        if (two) {
            float rB = sv - tB;
            float gB = rB > 0.f ? rB : 1e-8f * expf(rB);
            float gb = (expf(gB) - 1.0f) * fB;
            vB[(size_t)t * cap + i] = gb * sv;
            atomicAdd(&csB[ci], gb);
        }
    }
}

// ---------------------------------------------------------------------------
// Sparse emits (bf16 weights, bf16 out):  O[t] = sum_s val[s] * w[idx[s]]
// ---------------------------------------------------------------------------
__global__ __launch_bounds__(256) void k_gather2(const u16* __restrict__ w,
                                                 const int* __restrict__ sel,
                                                 const float* __restrict__ vA,
                                                 const float* __restrict__ vB,
                                                 const int* __restrict__ cnt, int cap,
                                                 u16* __restrict__ OA, u16* __restrict__ OB) {
    __shared__ int   sI[CAPK];
    __shared__ float sA[CAPK];
    __shared__ float sB[CAPK];
    int t = blockIdx.x, tid = threadIdx.x;
    int n = cnt[t];
    if (tid < n) { sI[tid] = sel[(size_t)t * cap + tid]; sA[tid] = vA[(size_t)t * cap + tid]; sB[tid] = vB[(size_t)t * cap + tid]; }
    __syncthreads();
    float a0 = 0, a1 = 0, a2 = 0, a3 = 0, b0 = 0, b1 = 0, b2 = 0, b3 = 0;
    for (int s = 0; s < n; s++) {
        const ushort4 wv = reinterpret_cast<const ushort4*>(w + (size_t)sI[s] * DIM)[tid];
        float w0 = bf2f(wv.x), w1 = bf2f(wv.y), w2 = bf2f(wv.z), w3 = bf2f(wv.w);
        float va = sA[s], vb = sB[s];
        a0 += va * w0; a1 += va * w1; a2 += va * w2; a3 += va * w3;
        b0 += vb * w0; b1 += vb * w1; b2 += vb * w2; b3 += vb * w3;
    }
    reinterpret_cast<ushort4*>(OA + (size_t)t * DIM)[tid] = make_ushort4(f2bf(a0), f2bf(a1), f2bf(a2), f2bf(a3));
    reinterpret_cast<ushort4*>(OB + (size_t)t * DIM)[tid] = make_ushort4(f2bf(b0), f2bf(b1), f2bf(b2), f2bf(b3));
}

__global__ __launch_bounds__(256) void k_gather1(const u16* __restrict__ w,
                                                 const int* __restrict__ sel,
                                                 const float* __restrict__ vv,
                                                 const int* __restrict__ cnt, int cap,
                                                 u16* __restrict__ O) {
    __shared__ int   sI[CAPK];
    __shared__ float sV[CAPK];
    int t = blockIdx.x, tid = threadIdx.x;
    int n = cnt[t];
    if (tid < n) { sI[tid] = sel[(size_t)t * cap + tid]; sV[tid] = vv[(size_t)t * cap + tid]; }
    __syncthreads();
    float a0 = 0, a1 = 0, a2 = 0, a3 = 0;
    for (int s = 0; s < n; s++) {
        const ushort4 wv = reinterpret_cast<const ushort4*>(w + (size_t)sI[s] * DIM)[tid];
        float va = sV[s];
        a0 += va * bf2f(wv.x); a1 += va * bf2f(wv.y); a2 += va * bf2f(wv.z); a3 += va * bf2f(wv.w);
    }
    reinterpret_cast<ushort4*>(O + (size_t)t * DIM)[tid] = make_ushort4(f2bf(a0), f2bf(a1), f2bf(a2), f2bf(a3));
}

// know emit fused with final residual: io[t] += sum val*w (bf16 weights)
__global__ __launch_bounds__(256) void k_gather_final(const u16* __restrict__ w,
                                                      const int* __restrict__ sel,
                                                      const float* __restrict__ vv,
                                                      const int* __restrict__ cnt, int cap,
                                                      float* __restrict__ io) {
    __shared__ int   sI[CAPK];
    __shared__ float sV[CAPK];
    int t = blockIdx.x, tid = threadIdx.x;
    int n = cnt[t];
    if (tid < n) { sI[tid] = sel[(size_t)t * cap + tid]; sV[tid] = vv[(size_t)t * cap + tid]; }
    __syncthreads();
    float4 base = reinterpret_cast<const float4*>(io + (size_t)t * DIM)[tid];
    float a0 = base.x, a1 = base.y, a2 = base.z, a3 = base.w;
    for (int s = 0; s < n; s++) {
        const ushort4 wv = reinterpret_cast<const ushort4*>(w + (size_t)sI[s] * DIM)[tid];
        float va = sV[s];
        a0 += va * bf2f(wv.x); a1 += va * bf2f(wv.y); a2 += va * bf2f(wv.z); a3 += va * bf2f(wv.w);
    }
    reinterpret_cast<float4*>(io + (size_t)t * DIM)[tid] = make_float4(a0, a1, a2, a3);
}

// ---------------------------------------------------------------------------
// Causal flash attention, bf16 MFMA (16x16x32).
// Block = 256 thr / 4 waves, one (b,h), 64 q rows (16 per wave).
// qt in blockIdx.x REVERSED so heavy (high-qt) blocks dispatch first.
// ---------------------------------------------------------------------------
__global__ __launch_bounds__(256) void k_attn(const u16* __restrict__ Q,
                                              const u16* __restrict__ K,
                                              const u16* __restrict__ V,
                                              u16* __restrict__ O) {
    __shared__ __align__(16) u16 Qs[64 * APAD];
    __shared__ __align__(16) u16 Ks[64 * APAD];
    __shared__ __align__(16) u16 Vt[64 * APAD];
    __shared__ __align__(16) u16 Ps[4][16 * APAD];
    int tid = threadIdx.x, wave = tid >> 6, lane = tid & 63;
    int qt = gridDim.x - 1 - blockIdx.x;   // heavy first
    int h = blockIdx.y, bb = blockIdx.z;
    int q0 = qt * 64;
    size_t base = ((size_t)bb * SLEN) * DIM + (size_t)h * DH;
    int sr = tid >> 2, sc = (tid & 3) * 16;     // staging row (0..63), col (0/16/32/48)
    int g = lane >> 4, l15 = lane & 15;

    // stage Q tile once
    {
        const u16* qp = Q + base + (size_t)(q0 + sr) * DIM + sc;
        *reinterpret_cast<short8*>(&Qs[sr * APAD + sc])     = *reinterpret_cast<const short8*>(qp);
        *reinterpret_cast<short8*>(&Qs[sr * APAD + sc + 8]) = *reinterpret_cast<const short8*>(qp + 8);
    }
    __syncthreads();
    short8 qa0 = *reinterpret_cast<const short8*>(&Qs[(wave * 16 + l15) * APAD + g * 8]);
    short8 qa1 = *reinterpret_cast<const short8*>(&Qs[(wave * 16 + l15) * APAD + 32 + g * 8]);

    float m[4], l[4];
    f32x4 oacc[4];
#pragma unroll
    for (int i = 0; i < 4; i++) {
        m[i] = -1e30f; l[i] = 0.f;
        f32x4 z = {0.f, 0.f, 0.f, 0.f}; oacc[i] = z;
    }
    u16* pw = &Ps[wave][0];

    for (int kc = 0; kc <= qt; kc++) {
        __syncthreads();
        // ---- stage K [key][dim] and V transposed [dim][key] ----
        {
            const u16* kp = K + base + (size_t)(kc * 64 + sr) * DIM + sc;
            *reinterpret_cast<short8*>(&Ks[sr * APAD + sc])     = *reinterpret_cast<const short8*>(kp);
            *reinterpret_cast<short8*>(&Ks[sr * APAD + sc + 8]) = *reinterpret_cast<const short8*>(kp + 8);
            const u16* vp = V + base + (size_t)(kc * 64 + sr) * DIM + sc;
            short8 w0 = *reinterpret_cast<const short8*>(vp);
            short8 w1 = *reinterpret_cast<const short8*>(vp + 8);
            const u16* w0p = reinterpret_cast<const u16*>(&w0);
            const u16* w1p = reinterpret_cast<const u16*>(&w1);
#pragma unroll
            for (int j = 0; j < 16; j++) {
                int d = sc + j;
                int phys = (((sr >> 3) + d + (d >> 4)) & 7);   // rotate key-blocks per dim
                Vt[d * APAD + phys * 8 + (sr & 7)] = (j < 8) ? w0p[j] : w1p[j - 8];
            }
        }
        __syncthreads();

        // ---- QK^T: 8 MFMAs -> s4[ks] (q_local = wave*16 + g*4 + r, key = ks*16 + l15)
        f32x4 s4[4];
#pragma unroll
        for (int ks = 0; ks < 4; ks++) {
            f32x4 z = {0.f, 0.f, 0.f, 0.f}; s4[ks] = z;
            short8 kb0 = *reinterpret_cast<const short8*>(&Ks[(ks * 16 + l15) * APAD + g * 8]);
            short8 kb1 = *reinterpret_cast<const short8*>(&Ks[(ks * 16 + l15) * APAD + 32 + g * 8]);
            s4[ks] = mfma_bf16(qa0, kb0, s4[ks]);
            s4[ks] = mfma_bf16(qa1, kb1, s4[ks]);
        }
        asm volatile("s_nop 7\n\ts_nop 7");   // MFMA -> VALU read hazard

        // ---- scale + causal mask ----
        int key_base = kc * 64 + l15;
#pragma unroll
        for (int ks = 0; ks < 4; ks++) {
            int key = key_base + ks * 16;
#pragma unroll
            for (int r = 0; r < 4; r++) {
                int q_abs = q0 + wave * 16 + g * 4 + r;
                float sv = s4[ks][r] * 0.125f;
                s4[ks][r] = (key > q_abs) ? -1e30f : sv;
            }
        }

        // ---- online softmax per q-row; write P (bf16) to per-wave LDS ----
#pragma unroll
        for (int r = 0; r < 4; r++) {
            float mx = fmaxf(fmaxf(s4[0][r], s4[1][r]), fmaxf(s4[2][r], s4[3][r]));
            mx = fmaxf(mx, __shfl_xor(mx, 1));
            mx = fmaxf(mx, __shfl_xor(mx, 2));
            mx = fmaxf(mx, __shfl_xor(mx, 4));
            mx = fmaxf(mx, __shfl_xor(mx, 8));
            float mnew = fmaxf(m[r], mx);
            float al = __expf(m[r] - mnew);
            m[r] = mnew;
            float p0 = __expf(s4[0][r] - mnew);
            float p1 = __expf(s4[1][r] - mnew);
            float p2 = __expf(s4[2][r] - mnew);
            float p3 = __expf(s4[3][r] - mnew);
            float ps = p0 + p1 + p2 + p3;
            ps += __shfl_xor(ps, 1);
            ps += __shfl_xor(ps, 2);
            ps += __shfl_xor(ps, 4);
            ps += __shfl_xor(ps, 8);
            l[r] = l[r] * al + ps;
#pragma unroll
            for (int ds_ = 0; ds_ < 4; ds_++) oacc[ds_][r] *= al;
            int row = g * 4 + r;
            pw[row * APAD +  0 + l15] = f2bf(p0);
            pw[row * APAD + 16 + l15] = f2bf(p1);
            pw[row * APAD + 32 + l15] = f2bf(p2);
            pw[row * APAD + 48 + l15] = f2bf(p3);
        }

        // ---- PV: read P as A-fragments, V^T as B-fragments; 8 MFMAs ----
        short8 pa0 = *reinterpret_cast<const short8*>(&pw[l15 * APAD + g * 8]);
        short8 pa1 = *reinterpret_cast<const short8*>(&pw[l15 * APAD + 32 + g * 8]);
#pragma unroll
        for (int dsub = 0; dsub < 4; dsub++) {
            int d = dsub * 16 + l15;
            int rot = d + (d >> 4);
            short8 vb0 = *reinterpret_cast<const short8*>(&Vt[d * APAD + (((0 + g) + rot) & 7) * 8]);
            short8 vb1 = *reinterpret_cast<const short8*>(&Vt[d * APAD + (((4 + g) + rot) & 7) * 8]);
            oacc[dsub] = mfma_bf16(pa0, vb0, oacc[dsub]);
            oacc[dsub] = mfma_bf16(pa1, vb1, oacc[dsub]);
        }
    }
    asm volatile("s_nop 7\n\ts_nop 7");       // MFMA -> VALU read hazard

    // ---- epilogue: O = oacc / l, bf16 ----
#pragma unroll
    for (int r = 0; r < 4; r++) {
        float inv = 1.0f / l[r];
        int row = q0 + wave * 16 + g * 4 + r;
#pragma unroll
        for (int dsub = 0; dsub < 4; dsub++) {
            O[base + (size_t)row * DIM + dsub * 16 + l15] = f2bf(oacc[dsub][r] * inv);
        }
    }
}

// ---------------------------------------------------------------------------
// aux = sum over gate columns of (colsum/T - 1/N)^2 * N
// ---------------------------------------------------------------------------
__global__ __launch_bounds__(256) void k_aux(const float* __restrict__ cs,
                                             float* __restrict__ out_aux) {
    __shared__ float red[4];
    int gtid = blockIdx.x * 256 + threadIdx.x;
    float acc = 0.f;
    for (int i = gtid; i < 3 * 4096 + 8192; i += gridDim.x * 256) {
        float mean = cs[i] * (1.0f / 4096.0f);
        float tN, Nf;
        if (i < 12288) { tN = 1.0f / 4096.0f; Nf = 4096.0f; }
        else           { tN = 1.0f / 8192.0f; Nf = 8192.0f; }
        float d = mean - tN;
        acc += d * d * Nf;
    }
    acc = blockReduceF(acc, red, threadIdx.x >> 6, threadIdx.x & 63);
    if (threadIdx.x == 0) atomicAdd(out_aux, acc);
}

// ---------------------------------------------------------------------------
extern "C" void kernel_launch(void* const* d_in, const int* in_sizes, int n_in,
                              void* d_out, int out_size, void* d_ws, size_t ws_size,
                              hipStream_t stream) {
    const float* x         = (const float*)d_in[0];
    const float* qk_emb    = (const float*)d_in[1];
    const float* qk_w      = (const float*)d_in[2];
    const float* v_emb     = (const float*)d_in[3];
    const float* v_w       = (const float*)d_in[4];
    const float* know_emb  = (const float*)d_in[5];
    const float* know_w    = (const float*)d_in[6];
    const float* tau_attn_k = (const float*)d_in[7];
    const float* tau_attn_b = (const float*)d_in[8];
    const float* tau_know_k = (const float*)d_in[9];
    const float* tau_know_b = (const float*)d_in[10];
    const float* expand_O  = (const float*)d_in[11];
    const float* ln1_s     = (const float*)d_in[12];
    const float* ln1_b     = (const float*)d_in[13];
    const float* ln2_s     = (const float*)d_in[14];
    const float* ln2_b     = (const float*)d_in[15];
    float* out = (float*)d_out;
    char*  ws  = (char*)d_ws;

    // workspace layout (bytes)
    u16*   nrm_bf   = (u16*)(ws + 0);                 //  8 MB
    u16*   qkemb_bf = (u16*)(ws + 8388608);           //  8 MB
    u16*   vemb_bf  = (u16*)(ws + 16777216);          //  8 MB
    u16*   knemb_bf = (u16*)(ws + 25165824);          // 16 MB
    u16*   expT_bf  = (u16*)(ws + 41943040);          //  2 MB
    u16*   attn_bf  = (u16*)(ws + 44040192);          //  8 MB
    u16*   qkw_bf   = (u16*)(ws + 52428800);          //  8 MB
    u16*   vw_bf    = (u16*)(ws + 60817408);          //  8 MB
    u16*   knw_bf   = (u16*)(ws + 69206016);          // 16 MB
    u16*   Qb       = (u16*)(ws + 85983232);          //  8 MB (bf16)
    u16*   Kb       = (u16*)(ws + 94371840);          //  8 MB (bf16)
    u16*   Vb       = (u16*)(ws + 102760448);         //  8 MB (bf16)
    u16*   keysbuf  = (u16*)(ws + 111149056);         // 32 MB (u16 keys)
    int*   selQK    = (int*)(ws + 178257920);
    float* valQ     = (float*)(ws + 179044352);
    float* valK     = (float*)(ws + 179830784);
    int*   selV     = (int*)(ws + 180617216);
    float* valV     = (float*)(ws + 181403648);
    int*   selKn    = (int*)(ws + 182190080);
    float* valKn    = (float*)(ws + 183762944);
    int*   cntQK    = (int*)(ws + 185335808);
    int*   cntV     = (int*)(ws + 185352192);
    int*   cntKn    = (int*)(ws + 185368576);
    float* tauA     = (float*)(ws + 185384960);       // [T][3]
    float* tauKn    = (float*)(ws + 185434112);       // [T]
    float* colsum   = (float*)(ws + 185450496);       // 20480 floats: Q,K,V,Kn
    const size_t WS_NEEDED = 185532416;
    if (ws_size < WS_NEEDED) return;   // workspace too small — bail cleanly

    float* colQ = colsum, *colK = colsum + 4096, *colV = colsum + 8192, *colKn = colsum + 12288;

    hipMemsetAsync(colsum, 0, 20480 * sizeof(float), stream);
    hipMemsetAsync(out + (size_t)TOK * DIM, 0, sizeof(float), stream);

    // bf16 conversions: all six tables in one launch + expand_O transpose
    k_convert_all<<<2048, 256, 0, stream>>>(qk_emb, v_emb, know_emb, qk_w, v_w, know_w,
                                            qkemb_bf, vemb_bf, knemb_bf, qkw_bf, vw_bf, knw_bf);
    k_transpose_bf16<<<dim3(32, 32), 256, 0, stream>>>(expand_O, expT_bf);

    // LN1 + tau(3)
    k_ln_tau<<<TOK, 256, 0, stream>>>(x, ln1_s, ln1_b, tau_attn_k, tau_attn_b, 3, nrm_bf, tauA);

    // scores_qk (u16 keys) + gate (g_Q, g_K share selection)
    k_gemm_bt<0, 1><<<dim3(NQK / 128, TOK / 128), 256, 0, stream>>>(nrm_bf, qkemb_bf, keysbuf, TOK, NQK, DIM, nullptr);
    k_gate<<<TOK, 256, NQK * sizeof(u16), stream>>>(keysbuf, NQK, 32, 0, tauA, 3, 0, 1,
                                                    selQK, valQ, valK, cntQK, colQ, colK, CAPA);
    // scores_v (u16 keys) + gate (g_V)
    k_gemm_bt<1, 1><<<dim3(NV / 128, TOK / 128), 256, 0, stream>>>(nrm_bf, vemb_bf, keysbuf, TOK, NV, DIM, nullptr);
    k_gate<<<TOK, 256, NV * sizeof(u16), stream>>>(keysbuf, NV, 32, 0, tauA, 3, 2, 0,
                                                   selV, valV, nullptr, cntV, colV, nullptr, CAPA);

    // sparse emits Q, K, V (bf16 weights -> bf16 out)
    k_gather2<<<TOK, 256, 0, stream>>>(qkw_bf, selQK, valQ, valK, cntQK, CAPA, Qb, Kb);
    k_gather1<<<TOK, 256, 0, stream>>>(vw_bf, selV, valV, cntV, CAPA, Vb);

    // causal MHA (bf16 MFMA) -> bf16 ; heavy q-tiles dispatch first
    k_attn<<<dim3(SLEN / 64, NH, 2), 256, 0, stream>>>(Qb, Kb, Vb, attn_bf);

    // out @ expand_O + residual x  -> x1 (stored in d_out)
    k_gemm_bt<2, 0><<<dim3(DIM / 128, TOK / 128), 256, 0, stream>>>(attn_bf, expT_bf, out, TOK, DIM, DIM, x);

    // LN2 + tau_know
    k_ln_tau<<<TOK, 256, 0, stream>>>(out, ln2_s, ln2_b, tau_know_k, tau_know_b, 1, nrm_bf, tauKn);

    // know scores (u16 keys) + gate, in 2 token chunks
    for (int c = 0; c < 2; c++) {
        k_gemm_bt<3, 1><<<dim3(NKN / 128, 2048 / 128), 256, 0, stream>>>(
            nrm_bf + (size_t)c * 2048 * DIM, knemb_bf, keysbuf, 2048, NKN, DIM, nullptr);
        k_gate<<<2048, 256, NKN * sizeof(u16), stream>>>(keysbuf, NKN, 64, c * 2048, tauKn, 1, 0, 0,
                                                         selKn, valKn, nullptr, cntKn, colKn, nullptr, CAPK);
    }

    // know emit + final residual (in place on d_out)
    k_gather_final<<<TOK, 256, 0, stream>>>(knw_bf, selKn, valKn, cntKn, CAPK, out);

    // aux scalar
    k_aux<<<20, 256, 0, stream>>>(colsum, out + (size_t)TOK * DIM);
}

// Round 7
// 743.936 us; speedup vs baseline: 2.3905x; 1.1004x over previous
//
#include <hip/hip_runtime.h>

// ---------------------------------------------------------------------------
// Problem constants (fixed by the reference)
// ---------------------------------------------------------------------------
#define TOK   4096      // B*S
#define DIM   1024
#define NQK   4096
#define NV    4096
#define NKN   8192
#define SLEN  2048
#define NH    16
#define DH    64
#define CAPA  48        // capacity for k=32 gates (slack for ties)
#define CAPK  96        // capacity for k=64 gate
#define APAD  72        // attn LDS row pad (bf16 elems): 144B keeps b128 align

typedef float  f32x4  __attribute__((ext_vector_type(4)));
typedef short  short8 __attribute__((ext_vector_type(8)));
typedef unsigned int  u32;
typedef unsigned short u16;

__device__ __forceinline__ u16 f2bf(float f) {
    u32 u = __float_as_uint(f);
    u32 r = (u + 0x7fffu + ((u >> 16) & 1u)) >> 16;
    return (u16)r;
}
__device__ __forceinline__ float bf2f(u16 v) { return __uint_as_float(((u32)v) << 16); }

// monotone bf16 -> u16 key (order-preserving over floats)
__device__ __forceinline__ u16 bfkey(u16 b) {
    return (b & 0x8000u) ? (u16)(~b) : (u16)(b | 0x8000u);
}
// inverse: key -> bf16 bits
__device__ __forceinline__ u16 keybf(u16 k) {
    return (k & 0x8000u) ? (u16)(k & 0x7fffu) : (u16)(~k);
}

__device__ __forceinline__ f32x4 mfma_bf16(short8 a, short8 b, f32x4 c) {
    asm volatile("v_mfma_f32_16x16x32_bf16 %0, %1, %2, %0"
                 : "+v"(c) : "v"(a), "v"(b));
    return c;
}

// async global->LDS, 16B per lane; LDS dest = wave-uniform base + lane*16
__device__ __forceinline__ void gload16(const u16* g, u16* s) {
    __builtin_amdgcn_global_load_lds((const __attribute__((address_space(1))) void*)g,
                                     (__attribute__((address_space(3))) void*)s, 16, 0, 0);
}

__device__ __forceinline__ float blockReduceF(float v, float* red, int wave, int lane) {
#pragma unroll
    for (int off = 32; off > 0; off >>= 1) v += __shfl_xor(v, off);
    __syncthreads();
    if (lane == 0) red[wave] = v;
    __syncthreads();
    return red[0] + red[1] + red[2] + red[3];
}

// ---------------------------------------------------------------------------
// fused f32 -> bf16 conversion of all six tables (one launch)
// ---------------------------------------------------------------------------
__global__ __launch_bounds__(256) void k_convert_all(const float* __restrict__ p0,
                                                     const float* __restrict__ p1,
                                                     const float* __restrict__ p2,
                                                     const float* __restrict__ p3,
                                                     const float* __restrict__ p4,
                                                     const float* __restrict__ p5,
                                                     u16* __restrict__ o0, u16* __restrict__ o1,
                                                     u16* __restrict__ o2, u16* __restrict__ o3,
                                                     u16* __restrict__ o4, u16* __restrict__ o5) {
    const int S0 = 1048576, S1 = 2097152, S2 = 4194304, S3 = 5242880, S4 = 6291456, S5 = 8388608;
    for (int i = blockIdx.x * 256 + threadIdx.x; i < S5; i += gridDim.x * 256) {
        const float* in; u16* out; int off;
        if (i < S0)      { in = p0; out = o0; off = i; }
        else if (i < S1) { in = p1; out = o1; off = i - S0; }
        else if (i < S2) { in = p2; out = o2; off = i - S1; }
        else if (i < S3) { in = p3; out = o3; off = i - S2; }
        else if (i < S4) { in = p4; out = o4; off = i - S3; }
        else             { in = p5; out = o5; off = i - S4; }
        float4 v = reinterpret_cast<const float4*>(in)[off];
        reinterpret_cast<ushort4*>(out)[off] = make_ushort4(f2bf(v.x), f2bf(v.y), f2bf(v.z), f2bf(v.w));
    }
}

// transpose 1024x1024 f32 -> bf16 (out[n][k] = in[k][n])
__global__ __launch_bounds__(256) void k_transpose_bf16(const float* __restrict__ in,
                                                        u16* __restrict__ out) {
    __shared__ float tile[32][33];
    int bx = blockIdx.x * 32;   // col of in
    int by = blockIdx.y * 32;   // row of in
    int tx = threadIdx.x & 31;
    int ty = threadIdx.x >> 5;  // 0..7
    for (int r = ty; r < 32; r += 8)
        tile[r][tx] = in[(size_t)(by + r) * DIM + bx + tx];
    __syncthreads();
    for (int r = ty; r < 32; r += 8)
        out[(size_t)(bx + r) * DIM + by + tx] = f2bf(tile[tx][r]);
}

// ---------------------------------------------------------------------------
// LayerNorm + tau projection; writes bf16 normed + f32 tau[t][ntau]
// ---------------------------------------------------------------------------
__global__ __launch_bounds__(256) void k_ln_tau(const float* __restrict__ x,
                                                const float* __restrict__ sc,
                                                const float* __restrict__ bi,
                                                const float* __restrict__ tauk,
                                                const float* __restrict__ taub,
                                                int ntau,
                                                u16* __restrict__ nrm,
                                                float* __restrict__ tau_out) {
    __shared__ float red[4];
    int t = blockIdx.x, tid = threadIdx.x, wave = tid >> 6, lane = tid & 63;
    const float4 xv = reinterpret_cast<const float4*>(x + (size_t)t * DIM)[tid];
    float s = xv.x + xv.y + xv.z + xv.w;
    s = blockReduceF(s, red, wave, lane);
    float mean = s * (1.0f / DIM);
    float d0 = xv.x - mean, d1 = xv.y - mean, d2 = xv.z - mean, d3 = xv.w - mean;
    float ss = d0 * d0 + d1 * d1 + d2 * d2 + d3 * d3;
    ss = blockReduceF(ss, red, wave, lane);
    float rstd = rsqrtf(ss * (1.0f / DIM) + 1e-6f);
    const float4 scv = reinterpret_cast<const float4*>(sc)[tid];
    const float4 biv = reinterpret_cast<const float4*>(bi)[tid];
    float n0 = d0 * rstd * scv.x + biv.x;
    float n1 = d1 * rstd * scv.y + biv.y;
    float n2 = d2 * rstd * scv.z + biv.z;
    float n3 = d3 * rstd * scv.w + biv.w;
    ushort4 o = make_ushort4(f2bf(n0), f2bf(n1), f2bf(n2), f2bf(n3));
    reinterpret_cast<ushort4*>(nrm + (size_t)t * DIM)[tid] = o;
    int d = tid * 4;
    for (int j = 0; j < ntau; j++) {
        float p = n0 * tauk[(size_t)(d + 0) * ntau + j] + n1 * tauk[(size_t)(d + 1) * ntau + j]
                + n2 * tauk[(size_t)(d + 2) * ntau + j] + n3 * tauk[(size_t)(d + 3) * ntau + j];
        p = blockReduceF(p, red, wave, lane);
        if (tid == 0) tau_out[(size_t)t * ntau + j] = p + taub[j];
    }
}

// ---------------------------------------------------------------------------
// C = A[M][K] @ B[N][K]^T  (bf16 in).  KEYOUT=0: f32 out (+res fuse).
// KEYOUT=1: write u16 monotone keys of bf16(score) for radix-select gates.
// ---------------------------------------------------------------------------
template<int TAG, int KEYOUT>
__global__ __launch_bounds__(256) void k_gemm_bt(const u16* __restrict__ A,
                                                 const u16* __restrict__ B,
                                                 void* __restrict__ Cv,
                                                 int M, int N, int K,
                                                 const float* __restrict__ res) {
    __shared__ __align__(16) u16 As[4096];
    __shared__ __align__(16) u16 Bs[4096];
    int tid = threadIdx.x;
    int wave = tid >> 6, lane = tid & 63;
    int m0 = blockIdx.y * 128, n0 = blockIdx.x * 128;
    int wm = (wave >> 1) * 64, wn = (wave & 1) * 64;
    int kg = lane >> 4, l15 = lane & 15;

    const u16* gA0 = A + (size_t)(m0 + lane) * K + wave * 8;
    const u16* gA1 = A + (size_t)(m0 + 64 + lane) * K + wave * 8;
    const u16* gB0 = B + (size_t)(n0 + lane) * K + wave * 8;
    const u16* gB1 = B + (size_t)(n0 + 64 + lane) * K + wave * 8;
    u16* sA0 = As + wave * 1024;
    u16* sA1 = As + wave * 1024 + 512;
    u16* sB0 = Bs + wave * 1024;
    u16* sB1 = Bs + wave * 1024 + 512;

    f32x4 acc[4][4];
#pragma unroll
    for (int i = 0; i < 4; i++)
#pragma unroll
        for (int j = 0; j < 4; j++) { f32x4 z = {0.f, 0.f, 0.f, 0.f}; acc[i][j] = z; }

    for (int k0 = 0; k0 < K; k0 += 32) {
        __syncthreads();
        gload16(gA0 + k0, sA0);
        gload16(gA1 + k0, sA1);
        gload16(gB0 + k0, sB0);
        gload16(gB1 + k0, sB1);
        __syncthreads();
        short8 af[4], bg[4];
#pragma unroll
        for (int mi = 0; mi < 4; mi++) {
            int row = wm + mi * 16 + l15;
            af[mi] = *reinterpret_cast<const short8*>(&As[(kg * 128 + row) * 8]);
        }
#pragma unroll
        for (int ni = 0; ni < 4; ni++) {
            int row = wn + ni * 16 + l15;
            bg[ni] = *reinterpret_cast<const short8*>(&Bs[(kg * 128 + row) * 8]);
        }
#pragma unroll
        for (int mi = 0; mi < 4; mi++)
#pragma unroll
            for (int ni = 0; ni < 4; ni++)
                acc[mi][ni] = mfma_bf16(af[mi], bg[ni], acc[mi][ni]);
    }
    asm volatile("s_nop 7\n\ts_nop 7");
#pragma unroll
    for (int mi = 0; mi < 4; mi++) {
#pragma unroll
        for (int ni = 0; ni < 4; ni++) {
            int col = n0 + wn + ni * 16 + l15;
#pragma unroll
            for (int r = 0; r < 4; r++) {
                int rowm = m0 + wm + mi * 16 + (lane >> 4) * 4 + r;
                size_t idx = (size_t)rowm * N + col;
                float v = acc[mi][ni][r];
                if (KEYOUT) {
                    ((u16*)Cv)[idx] = bfkey(f2bf(v));
                } else {
                    if (res) v += res[idx];
                    ((float*)Cv)[idx] = v;
                }
            }
        }
    }
}

// ---------------------------------------------------------------------------
// Fused top-k threshold gate + sparse emit.
// Phase 1: 2-pass radix select over u16 keys -> exact kth-largest; select
//          keys >= thr (ties, capacity-capped); wave 0 computes gate values
//          (emit weight = score*gate) into LDS + bare-gate colsum atomics.
// Phase 2: all 256 threads gather-emit:  O[t] = sum_s val[s] * w[idx[s]]
//          TWO=1: two gates (Q,K) share selection -> OA, OB (bf16).
//          RES=1: single gate, accumulate into f32 io (+residual), else OA.
// ---------------------------------------------------------------------------
template<int TWO, int RES>
__global__ __launch_bounds__(256) void k_gate_emit(const u16* __restrict__ keys_g, int NC, int ksel,
                                                   int row_off,
                                                   const float* __restrict__ tau, int tau_stride, int tcol0,
                                                   const u16* __restrict__ w,
                                                   u16* __restrict__ OA, u16* __restrict__ OB,
                                                   float* __restrict__ io,
                                                   float* __restrict__ csA, float* __restrict__ csB) {
    extern __shared__ u16 keys[];
    __shared__ int   hist[256];
    __shared__ int   scnt;
    __shared__ int   dsel;
    __shared__ int   knext;
    __shared__ int   sidx[CAPK];
    __shared__ float svA[CAPK];
    __shared__ float svB[CAPK];
    int r = blockIdx.x, tid = threadIdx.x, wave = tid >> 6, lane = tid & 63;
    int t = row_off + r;
    const int cap = TWO ? CAPA : (RES ? CAPK : CAPA);

    // stage keys (uint4 = 8 keys)
    const uint4* srow8 = reinterpret_cast<const uint4*>(keys_g + (size_t)r * NC);
    for (int c = tid; c < NC / 8; c += 256)
        reinterpret_cast<uint4*>(keys)[c] = srow8[c];
    if (tid == 0) scnt = 0;

    // ---- radix select: 2 passes of 8 bits, MSB first ----
    u32 prefix = 0;
    int krem = ksel;
#pragma unroll
    for (int pass = 0; pass < 2; pass++) {
        int shift = 8 - pass * 8;
        hist[tid] = 0;
        __syncthreads();
        u32 pmask = (pass == 0) ? 0u : 0xFF00u;
        for (int i = tid; i < NC; i += 256) {
            u32 ky = keys[i];
            if ((ky & pmask) == prefix)
                atomicAdd(&hist[(ky >> shift) & 255], 1);
        }
        __syncthreads();
        int v = hist[tid];
#pragma unroll
        for (int off = 1; off < 256; off <<= 1) {
            int other = (tid + off < 256) ? hist[tid + off] : 0;
            __syncthreads();
            v += other;
            hist[tid] = v;
            __syncthreads();
        }
        int sfx = v;
        int sfx_next = (tid < 255) ? hist[tid + 1] : 0;
        if (sfx >= krem && (tid == 255 || sfx_next < krem)) {
            dsel = tid;
            knext = krem - sfx_next;
        }
        __syncthreads();
        prefix |= ((u32)dsel) << shift;
        krem = knext;
        __syncthreads();
    }
    u32 thr = prefix;   // exact kth-largest u16 key

    // ---- select keys >= thr; store raw score (reuse svA slot) ----
    for (int i = tid; i < NC; i += 256) {
        u32 ky = keys[i];
        if (ky >= thr) {
            int p = atomicAdd(&scnt, 1);
            if (p < cap) {
                sidx[p] = i;
                svA[p] = bf2f(keybf((u16)ky));
            }
        }
    }
    __syncthreads();
    int n = scnt < cap ? scnt : cap;

    // ---- wave 0: gate values -> svA/svB (emit weights), colsum atomics ----
    if (wave == 0) {
        float tA = tau[(size_t)t * tau_stride + tcol0];
        float tB = TWO ? tau[(size_t)t * tau_stride + tcol0 + 1] : 0.f;
        float sumA = 0.f, mxA = -1e30f, sumB = 0.f, mxB = -1e30f;
        float sv0 = (lane < n) ? svA[lane] : 0.f;
        float sv1 = (lane + 64 < n) ? svA[lane + 64] : 0.f;
        for (int i = lane; i < n; i += 64) {
            float sv = svA[i];
            float rA = sv - tA;
            float gA = rA > 0.f ? rA : 1e-8f * expf(rA);
            float eA = expf(gA) - 1.0f;            // match reference quantization
            sumA += eA; mxA = fmaxf(mxA, eA);
            if (TWO) {
                float rB = sv - tB;
                float gB = rB > 0.f ? rB : 1e-8f * expf(rB);
                float eB = expf(gB) - 1.0f;
                sumB += eB; mxB = fmaxf(mxB, eB);
            }
        }
#pragma unroll
        for (int off = 32; off > 0; off >>= 1) {
            sumA += __shfl_xor(sumA, off); mxA = fmaxf(mxA, __shfl_xor(mxA, off));
            sumB += __shfl_xor(sumB, off); mxB = fmaxf(mxB, __shfl_xor(mxB, off));
        }
        float fA = tanhf(mxA) / (sumA + 1e-8f);
        float fB = tanhf(mxB) / (sumB + 1e-8f);
        // two strided slots max (n <= 96 < 128)
        if (lane < n) {
            float sv = sv0; int ci = sidx[lane];
            float rA = sv - tA;
            float gA = rA > 0.f ? rA : 1e-8f * expf(rA);
            float ga = (expf(gA) - 1.0f) * fA;
            svA[lane] = ga * sv;                   // emit weight = score * gate
            atomicAdd(&csA[ci], ga);
            if (TWO) {
                float rB = sv - tB;
                float gB = rB > 0.f ? rB : 1e-8f * expf(rB);
                float gb = (expf(gB) - 1.0f) * fB;
                svB[lane] = gb * sv;
                atomicAdd(&csB[ci], gb);
            }
        }
        if (lane + 64 < n) {
            float sv = sv1; int ci = sidx[lane + 64];
            float rA = sv - tA;
            float gA = rA > 0.f ? rA : 1e-8f * expf(rA);
            float ga = (expf(gA) - 1.0f) * fA;
            svA[lane + 64] = ga * sv;
            atomicAdd(&csA[ci], ga);
            if (TWO) {
                float rB = sv - tB;
                float gB = rB > 0.f ? rB : 1e-8f * expf(rB);
                float gb = (expf(gB) - 1.0f) * fB;
                svB[lane + 64] = gb * sv;
                atomicAdd(&csB[ci], gb);
            }
        }
    }
    __syncthreads();

    // ---- phase 2: gather-emit (all threads), 4 rows in flight ----
    float a0 = 0, a1 = 0, a2 = 0, a3 = 0, b0 = 0, b1 = 0, b2 = 0, b3 = 0;
    float4 base;
    if (RES) base = reinterpret_cast<const float4*>(io + (size_t)t * DIM)[tid];
    int s = 0;
    for (; s + 4 <= n; s += 4) {
        const ushort4 w0 = reinterpret_cast<const ushort4*>(w + (size_t)sidx[s]     * DIM)[tid];
        const ushort4 w1 = reinterpret_cast<const ushort4*>(w + (size_t)sidx[s + 1] * DIM)[tid];
        const ushort4 w2 = reinterpret_cast<const ushort4*>(w + (size_t)sidx[s + 2] * DIM)[tid];
        const ushort4 w3 = reinterpret_cast<const ushort4*>(w + (size_t)sidx[s + 3] * DIM)[tid];
        float vA0 = svA[s], vA1 = svA[s + 1], vA2 = svA[s + 2], vA3 = svA[s + 3];
        a0 += vA0 * bf2f(w0.x) + vA1 * bf2f(w1.x) + vA2 * bf2f(w2.x) + vA3 * bf2f(w3.x);
        a1 += vA0 * bf2f(w0.y) + vA1 * bf2f(w1.y) + vA2 * bf2f(w2.y) + vA3 * bf2f(w3.y);
        a2 += vA0 * bf2f(w0.z) + vA1 * bf2f(w1.z) + vA2 * bf2f(w2.z) + vA3 * bf2f(w3.z);
        a3 += vA0 * bf2f(w0.w) + vA1 * bf2f(w1.w) + vA2 * bf2f(w2.w) + vA3 * bf2f(w3.w);
        if (TWO) {
            float vB0 = svB[s], vB1 = svB[s + 1], vB2 = svB[s + 2], vB3 = svB[s + 3];
            b0 += vB0 * bf2f(w0.x) + vB1 * bf2f(w1.x) + vB2 * bf2f(w2.x) + vB3 * bf2f(w3.x);
            b1 += vB0 * bf2f(w0.y) + vB1 * bf2f(w1.y) + vB2 * bf2f(w2.y) + vB3 * bf2f(w3.y);
            b2 += vB0 * bf2f(w0.z) + vB1 * bf2f(w1.z) + vB2 * bf2f(w2.z) + vB3 * bf2f(w3.z);
            b3 += vB0 * bf2f(w0.w) + vB1 * bf2f(w1.w) + vB2 * bf2f(w2.w) + vB3 * bf2f(w3.w);
        }
    }
    for (; s < n; s++) {
        const ushort4 wv = reinterpret_cast<const ushort4*>(w + (size_t)sidx[s] * DIM)[tid];
        float va = svA[s];
        a0 += va * bf2f(wv.x); a1 += va * bf2f(wv.y); a2 += va * bf2f(wv.z); a3 += va * bf2f(wv.w);
        if (TWO) {
            float vb = svB[s];
            b0 += vb * bf2f(wv.x); b1 += vb * bf2f(wv.y); b2 += vb * bf2f(wv.z); b3 += vb * bf2f(wv.w);
        }
    }
    if (RES) {
        reinterpret_cast<float4*>(io + (size_t)t * DIM)[tid] =
            make_float4(base.x + a0, base.y + a1, base.z + a2, base.w + a3);
    } else {
        reinterpret_cast<ushort4*>(OA + (size_t)t * DIM)[tid] = make_ushort4(f2bf(a0), f2bf(a1), f2bf(a2), f2bf(a3));
        if (TWO)
            reinterpret_cast<ushort4*>(OB + (size_t)t * DIM)[tid] = make_ushort4(f2bf(b0), f2bf(b1), f2bf(b2), f2bf(b3));
    }
}

// ---------------------------------------------------------------------------
// Causal flash attention, bf16 MFMA (16x16x32).
// Block = 256 thr / 4 waves, one (b,h), 64 q rows (16 per wave).
// Grid (h, bb, qt): concurrent blocks = all heads at same qt -> K/V rows
// shared across resident set (L2-friendly; do NOT reorder — round-6 lesson).
// ---------------------------------------------------------------------------
__global__ __launch_bounds__(256) void k_attn(const u16* __restrict__ Q,
                                              const u16* __restrict__ K,
                                              const u16* __restrict__ V,
                                              u16* __restrict__ O) {
    __shared__ __align__(16) u16 Qs[64 * APAD];
    __shared__ __align__(16) u16 Ks[64 * APAD];
    __shared__ __align__(16) u16 Vt[64 * APAD];
    __shared__ __align__(16) u16 Ps[4][16 * APAD];
    int tid = threadIdx.x, wave = tid >> 6, lane = tid & 63;
    int h = blockIdx.x, bb = blockIdx.y, qt = blockIdx.z;
    int q0 = qt * 64;
    size_t base = ((size_t)bb * SLEN) * DIM + (size_t)h * DH;
    int sr = tid >> 2, sc = (tid & 3) * 16;     // staging row (0..63), col (0/16/32/48)
    int g = lane >> 4, l15 = lane & 15;

    // stage Q tile once
    {
        const u16* qp = Q + base + (size_t)(q0 + sr) * DIM + sc;
        *reinterpret_cast<short8*>(&Qs[sr * APAD + sc])     = *reinterpret_cast<const short8*>(qp);
        *reinterpret_cast<short8*>(&Qs[sr * APAD + sc + 8]) = *reinterpret_cast<const short8*>(qp + 8);
    }
    __syncthreads();
    short8 qa0 = *reinterpret_cast<const short8*>(&Qs[(wave * 16 + l15) * APAD + g * 8]);
    short8 qa1 = *reinterpret_cast<const short8*>(&Qs[(wave * 16 + l15) * APAD + 32 + g * 8]);

    float m[4], l[4];
    f32x4 oacc[4];
#pragma unroll
    for (int i = 0; i < 4; i++) {
        m[i] = -1e30f; l[i] = 0.f;
        f32x4 z = {0.f, 0.f, 0.f, 0.f}; oacc[i] = z;
    }
    u16* pw = &Ps[wave][0];

    for (int kc = 0; kc <= qt; kc++) {
        __syncthreads();
        // ---- stage K [key][dim] and V transposed [dim][key] ----
        {
            const u16* kp = K + base + (size_t)(kc * 64 + sr) * DIM + sc;
            *reinterpret_cast<short8*>(&Ks[sr * APAD + sc])     = *reinterpret_cast<const short8*>(kp);
            *reinterpret_cast<short8*>(&Ks[sr * APAD + sc + 8]) = *reinterpret_cast<const short8*>(kp + 8);
            const u16* vp = V + base + (size_t)(kc * 64 + sr) * DIM + sc;
            short8 w0 = *reinterpret_cast<const short8*>(vp);
            short8 w1 = *reinterpret_cast<const short8*>(vp + 8);
            const u16* w0p = reinterpret_cast<const u16*>(&w0);
            const u16* w1p = reinterpret_cast<const u16*>(&w1);
#pragma unroll
            for (int j = 0; j < 16; j++) {
                int d = sc + j;
                int phys = (((sr >> 3) + d + (d >> 4)) & 7);   // rotate key-blocks per dim
                Vt[d * APAD + phys * 8 + (sr & 7)] = (j < 8) ? w0p[j] : w1p[j - 8];
            }
        }
        __syncthreads();

        // ---- QK^T: 8 MFMAs -> s4[ks] (q_local = wave*16 + g*4 + r, key = ks*16 + l15)
        f32x4 s4[4];
#pragma unroll
        for (int ks = 0; ks < 4; ks++) {
            f32x4 z = {0.f, 0.f, 0.f, 0.f}; s4[ks] = z;
            short8 kb0 = *reinterpret_cast<const short8*>(&Ks[(ks * 16 + l15) * APAD + g * 8]);
            short8 kb1 = *reinterpret_cast<const short8*>(&Ks[(ks * 16 + l15) * APAD + 32 + g * 8]);
            s4[ks] = mfma_bf16(qa0, kb0, s4[ks]);
            s4[ks] = mfma_bf16(qa1, kb1, s4[ks]);
        }
        asm volatile("s_nop 7\n\ts_nop 7");   // MFMA -> VALU read hazard

        // ---- scale + causal mask ----
        int key_base = kc * 64 + l15;
#pragma unroll
        for (int ks = 0; ks < 4; ks++) {
            int key = key_base + ks * 16;
#pragma unroll
            for (int r = 0; r < 4; r++) {
                int q_abs = q0 + wave * 16 + g * 4 + r;
                float sv = s4[ks][r] * 0.125f;
                s4[ks][r] = (key > q_abs) ? -1e30f : sv;
            }
        }

        // ---- online softmax per q-row; write P (bf16) to per-wave LDS ----
#pragma unroll
        for (int r = 0; r < 4; r++) {
            float mx = fmaxf(fmaxf(s4[0][r], s4[1][r]), fmaxf(s4[2][r], s4[3][r]));
            mx = fmaxf(mx, __shfl_xor(mx, 1));
            mx = fmaxf(mx, __shfl_xor(mx, 2));
            mx = fmaxf(mx, __shfl_xor(mx, 4));
            mx = fmaxf(mx, __shfl_xor(mx, 8));
            float mnew = fmaxf(m[r], mx);
            float al = __expf(m[r] - mnew);
            m[r] = mnew;
            float p0 = __expf(s4[0][r] - mnew);
            float p1 = __expf(s4[1][r] - mnew);
            float p2 = __expf(s4[2][r] - mnew);
            float p3 = __expf(s4[3][r] - mnew);
            float ps = p0 + p1 + p2 + p3;
            ps += __shfl_xor(ps, 1);
            ps += __shfl_xor(ps, 2);
            ps += __shfl_xor(ps, 4);
            ps += __shfl_xor(ps, 8);
            l[r] = l[r] * al + ps;
#pragma unroll
            for (int ds_ = 0; ds_ < 4; ds_++) oacc[ds_][r] *= al;
            int row = g * 4 + r;
            pw[row * APAD +  0 + l15] = f2bf(p0);
            pw[row * APAD + 16 + l15] = f2bf(p1);
            pw[row * APAD + 32 + l15] = f2bf(p2);
            pw[row * APAD + 48 + l15] = f2bf(p3);
        }

        // ---- PV: read P as A-fragments, V^T as B-fragments; 8 MFMAs ----
        short8 pa0 = *reinterpret_cast<const short8*>(&pw[l15 * APAD + g * 8]);
        short8 pa1 = *reinterpret_cast<const short8*>(&pw[l15 * APAD + 32 + g * 8]);
#pragma unroll
        for (int dsub = 0; dsub < 4; dsub++) {
            int d = dsub * 16 + l15;
            int rot = d + (d >> 4);
            short8 vb0 = *reinterpret_cast<const short8*>(&Vt[d * APAD + (((0 + g) + rot) & 7) * 8]);
            short8 vb1 = *reinterpret_cast<const short8*>(&Vt[d * APAD + (((4 + g) + rot) & 7) * 8]);
            oacc[dsub] = mfma_bf16(pa0, vb0, oacc[dsub]);
            oacc[dsub] = mfma_bf16(pa1, vb1, oacc[dsub]);
        }
    }
    asm volatile("s_nop 7\n\ts_nop 7");       // MFMA -> VALU read hazard

    // ---- epilogue: O = oacc / l, bf16 ----
#pragma unroll
    for (int r = 0; r < 4; r++) {
        float inv = 1.0f / l[r];
        int row = q0 + wave * 16 + g * 4 + r;
#pragma unroll
        for (int dsub = 0; dsub < 4; dsub++) {
            O[base + (size_t)row * DIM + dsub * 16 + l15] = f2bf(oacc[dsub][r] * inv);
        }
    }
}

// ---------------------------------------------------------------------------
// aux = sum over gate columns of (colsum/T - 1/N)^2 * N
// ---------------------------------------------------------------------------
__global__ __launch_bounds__(256) void k_aux(const float* __restrict__ cs,
                                             float* __restrict__ out_aux) {
    __shared__ float red[4];
    int gtid = blockIdx.x * 256 + threadIdx.x;
    float acc = 0.f;
    for (int i = gtid; i < 3 * 4096 + 8192; i += gridDim.x * 256) {
        float mean = cs[i] * (1.0f / 4096.0f);
        float tN, Nf;
        if (i < 12288) { tN = 1.0f / 4096.0f; Nf = 4096.0f; }
        else           { tN = 1.0f / 8192.0f; Nf = 8192.0f; }
        float d = mean - tN;
        acc += d * d * Nf;
    }
    acc = blockReduceF(acc, red, threadIdx.x >> 6, threadIdx.x & 63);
    if (threadIdx.x == 0) atomicAdd(out_aux, acc);
}

// ---------------------------------------------------------------------------
extern "C" void kernel_launch(void* const* d_in, const int* in_sizes, int n_in,
                              void* d_out, int out_size, void* d_ws, size_t ws_size,
                              hipStream_t stream) {
    const float* x         = (const float*)d_in[0];
    const float* qk_emb    = (const float*)d_in[1];
    const float* qk_w      = (const float*)d_in[2];
    const float* v_emb     = (const float*)d_in[3];
    const float* v_w       = (const float*)d_in[4];
    const float* know_emb  = (const float*)d_in[5];
    const float* know_w    = (const float*)d_in[6];
    const float* tau_attn_k = (const float*)d_in[7];
    const float* tau_attn_b = (const float*)d_in[8];
    const float* tau_know_k = (const float*)d_in[9];
    const float* tau_know_b = (const float*)d_in[10];
    const float* expand_O  = (const float*)d_in[11];
    const float* ln1_s     = (const float*)d_in[12];
    const float* ln1_b     = (const float*)d_in[13];
    const float* ln2_s     = (const float*)d_in[14];
    const float* ln2_b     = (const float*)d_in[15];
    float* out = (float*)d_out;
    char*  ws  = (char*)d_ws;

    // workspace layout (bytes)
    u16*   nrm_bf   = (u16*)(ws + 0);                 //  8 MB
    u16*   qkemb_bf = (u16*)(ws + 8388608);           //  8 MB
    u16*   vemb_bf  = (u16*)(ws + 16777216);          //  8 MB
    u16*   knemb_bf = (u16*)(ws + 25165824);          // 16 MB
    u16*   expT_bf  = (u16*)(ws + 41943040);          //  2 MB
    u16*   attn_bf  = (u16*)(ws + 44040192);          //  8 MB
    u16*   qkw_bf   = (u16*)(ws + 52428800);          //  8 MB
    u16*   vw_bf    = (u16*)(ws + 60817408);          //  8 MB
    u16*   knw_bf   = (u16*)(ws + 69206016);          // 16 MB
    u16*   Qb       = (u16*)(ws + 85983232);          //  8 MB (bf16)
    u16*   Kb       = (u16*)(ws + 94371840);          //  8 MB (bf16)
    u16*   Vb       = (u16*)(ws + 102760448);         //  8 MB (bf16)
    u16*   keysbuf  = (u16*)(ws + 111149056);         // 32 MB (u16 keys)
    float* tauA     = (float*)(ws + 185384960);       // [T][3]
    float* tauKn    = (float*)(ws + 185434112);       // [T]
    float* colsum   = (float*)(ws + 185450496);       // 20480 floats: Q,K,V,Kn
    const size_t WS_NEEDED = 185532416;
    if (ws_size < WS_NEEDED) return;   // workspace too small — bail cleanly

    float* colQ = colsum, *colK = colsum + 4096, *colV = colsum + 8192, *colKn = colsum + 12288;

    hipMemsetAsync(colsum, 0, 20480 * sizeof(float), stream);
    hipMemsetAsync(out + (size_t)TOK * DIM, 0, sizeof(float), stream);

    // bf16 conversions: all six tables in one launch + expand_O transpose
    k_convert_all<<<2048, 256, 0, stream>>>(qk_emb, v_emb, know_emb, qk_w, v_w, know_w,
                                            qkemb_bf, vemb_bf, knemb_bf, qkw_bf, vw_bf, knw_bf);
    k_transpose_bf16<<<dim3(32, 32), 256, 0, stream>>>(expand_O, expT_bf);

    // LN1 + tau(3)
    k_ln_tau<<<TOK, 256, 0, stream>>>(x, ln1_s, ln1_b, tau_attn_k, tau_attn_b, 3, nrm_bf, tauA);

    // scores_qk (u16 keys) + fused gate+emit Q,K (shared selection)
    k_gemm_bt<0, 1><<<dim3(NQK / 128, TOK / 128), 256, 0, stream>>>(nrm_bf, qkemb_bf, keysbuf, TOK, NQK, DIM, nullptr);
    k_gate_emit<1, 0><<<TOK, 256, NQK * sizeof(u16), stream>>>(keysbuf, NQK, 32, 0, tauA, 3, 0,
                                                               qkw_bf, Qb, Kb, nullptr, colQ, colK);
    // scores_v (u16 keys) + fused gate+emit V
    k_gemm_bt<1, 1><<<dim3(NV / 128, TOK / 128), 256, 0, stream>>>(nrm_bf, vemb_bf, keysbuf, TOK, NV, DIM, nullptr);
    k_gate_emit<0, 0><<<TOK, 256, NV * sizeof(u16), stream>>>(keysbuf, NV, 32, 0, tauA, 3, 2,
                                                              vw_bf, Vb, nullptr, nullptr, colV, nullptr);

    // causal MHA (bf16 MFMA) -> bf16
    k_attn<<<dim3(NH, 2, SLEN / 64), 256, 0, stream>>>(Qb, Kb, Vb, attn_bf);

    // out @ expand_O + residual x  -> x1 (stored in d_out)
    k_gemm_bt<2, 0><<<dim3(DIM / 128, TOK / 128), 256, 0, stream>>>(attn_bf, expT_bf, out, TOK, DIM, DIM, x);

    // LN2 + tau_know
    k_ln_tau<<<TOK, 256, 0, stream>>>(out, ln2_s, ln2_b, tau_know_k, tau_know_b, 1, nrm_bf, tauKn);

    // know scores (u16 keys) + fused gate+emit(+residual), 2 token chunks
    for (int c = 0; c < 2; c++) {
        k_gemm_bt<3, 1><<<dim3(NKN / 128, 2048 / 128), 256, 0, stream>>>(
            nrm_bf + (size_t)c * 2048 * DIM, knemb_bf, keysbuf, 2048, NKN, DIM, nullptr);
        k_gate_emit<0, 1><<<2048, 256, NKN * sizeof(u16), stream>>>(keysbuf, NKN, 64, c * 2048, tauKn, 1, 0,
                                                                    knw_bf, nullptr, nullptr, out, colKn, nullptr);
    }

    // aux scalar
    k_aux<<<20, 256, 0, stream>>>(colsum, out + (size_t)TOK * DIM);
}

// Round 8
// 719.843 us; speedup vs baseline: 2.4705x; 1.0335x over previous
//
#include <hip/hip_runtime.h>

// ---------------------------------------------------------------------------
// Problem constants (fixed by the reference)
// ---------------------------------------------------------------------------
#define TOK   4096      // B*S
#define DIM   1024
#define NQK   4096
#define NV    4096
#define NKN   8192
#define SLEN  2048
#define NH    16
#define DH    64
#define CAPA  48        // capacity for k=32 gates (slack for ties)
#define CAPK  96        // capacity for k=64 gate
#define APAD  72        // attn LDS row pad (bf16 elems): 144B keeps b128 align

typedef float  f32x4  __attribute__((ext_vector_type(4)));
typedef short  short8 __attribute__((ext_vector_type(8)));
typedef unsigned int  u32;
typedef unsigned short u16;

__device__ __forceinline__ u16 f2bf(float f) {
    u32 u = __float_as_uint(f);
    u32 r = (u + 0x7fffu + ((u >> 16) & 1u)) >> 16;
    return (u16)r;
}
__device__ __forceinline__ float bf2f(u16 v) { return __uint_as_float(((u32)v) << 16); }

// monotone bf16 -> u16 key (order-preserving over floats)
__device__ __forceinline__ u16 bfkey(u16 b) {
    return (b & 0x8000u) ? (u16)(~b) : (u16)(b | 0x8000u);
}
// inverse: key -> bf16 bits
__device__ __forceinline__ u16 keybf(u16 k) {
    return (k & 0x8000u) ? (u16)(k & 0x7fffu) : (u16)(~k);
}

__device__ __forceinline__ f32x4 mfma_bf16(short8 a, short8 b, f32x4 c) {
    asm volatile("v_mfma_f32_16x16x32_bf16 %0, %1, %2, %0"
                 : "+v"(c) : "v"(a), "v"(b));
    return c;
}

// async global->LDS, 16B per lane; LDS dest = wave-uniform base + lane*16
__device__ __forceinline__ void gload16(const u16* g, u16* s) {
    __builtin_amdgcn_global_load_lds((const __attribute__((address_space(1))) void*)g,
                                     (__attribute__((address_space(3))) void*)s, 16, 0, 0);
}

__device__ __forceinline__ float blockReduceF(float v, float* red, int wave, int lane) {
#pragma unroll
    for (int off = 32; off > 0; off >>= 1) v += __shfl_xor(v, off);
    __syncthreads();
    if (lane == 0) red[wave] = v;
    __syncthreads();
    return red[0] + red[1] + red[2] + red[3];
}

// ---------------------------------------------------------------------------
// fused f32 -> bf16 conversion of all six tables (one launch)
// ---------------------------------------------------------------------------
__global__ __launch_bounds__(256) void k_convert_all(const float* __restrict__ p0,
                                                     const float* __restrict__ p1,
                                                     const float* __restrict__ p2,
                                                     const float* __restrict__ p3,
                                                     const float* __restrict__ p4,
                                                     const float* __restrict__ p5,
                                                     u16* __restrict__ o0, u16* __restrict__ o1,
                                                     u16* __restrict__ o2, u16* __restrict__ o3,
                                                     u16* __restrict__ o4, u16* __restrict__ o5) {
    const int S0 = 1048576, S1 = 2097152, S2 = 4194304, S3 = 5242880, S4 = 6291456, S5 = 8388608;
    for (int i = blockIdx.x * 256 + threadIdx.x; i < S5; i += gridDim.x * 256) {
        const float* in; u16* out; int off;
        if (i < S0)      { in = p0; out = o0; off = i; }
        else if (i < S1) { in = p1; out = o1; off = i - S0; }
        else if (i < S2) { in = p2; out = o2; off = i - S1; }
        else if (i < S3) { in = p3; out = o3; off = i - S2; }
        else if (i < S4) { in = p4; out = o4; off = i - S3; }
        else             { in = p5; out = o5; off = i - S4; }
        float4 v = reinterpret_cast<const float4*>(in)[off];
        reinterpret_cast<ushort4*>(out)[off] = make_ushort4(f2bf(v.x), f2bf(v.y), f2bf(v.z), f2bf(v.w));
    }
}

// transpose 1024x1024 f32 -> bf16 (out[n][k] = in[k][n])
__global__ __launch_bounds__(256) void k_transpose_bf16(const float* __restrict__ in,
                                                        u16* __restrict__ out) {
    __shared__ float tile[32][33];
    int bx = blockIdx.x * 32;   // col of in
    int by = blockIdx.y * 32;   // row of in
    int tx = threadIdx.x & 31;
    int ty = threadIdx.x >> 5;  // 0..7
    for (int r = ty; r < 32; r += 8)
        tile[r][tx] = in[(size_t)(by + r) * DIM + bx + tx];
    __syncthreads();
    for (int r = ty; r < 32; r += 8)
        out[(size_t)(bx + r) * DIM + by + tx] = f2bf(tile[tx][r]);
}

// ---------------------------------------------------------------------------
// LayerNorm + tau projection; writes bf16 normed + f32 tau[t][ntau]
// ---------------------------------------------------------------------------
__global__ __launch_bounds__(256) void k_ln_tau(const float* __restrict__ x,
                                                const float* __restrict__ sc,
                                                const float* __restrict__ bi,
                                                const float* __restrict__ tauk,
                                                const float* __restrict__ taub,
                                                int ntau,
                                                u16* __restrict__ nrm,
                                                float* __restrict__ tau_out) {
    __shared__ float red[4];
    int t = blockIdx.x, tid = threadIdx.x, wave = tid >> 6, lane = tid & 63;
    const float4 xv = reinterpret_cast<const float4*>(x + (size_t)t * DIM)[tid];
    float s = xv.x + xv.y + xv.z + xv.w;
    s = blockReduceF(s, red, wave, lane);
    float mean = s * (1.0f / DIM);
    float d0 = xv.x - mean, d1 = xv.y - mean, d2 = xv.z - mean, d3 = xv.w - mean;
    float ss = d0 * d0 + d1 * d1 + d2 * d2 + d3 * d3;
    ss = blockReduceF(ss, red, wave, lane);
    float rstd = rsqrtf(ss * (1.0f / DIM) + 1e-6f);
    const float4 scv = reinterpret_cast<const float4*>(sc)[tid];
    const float4 biv = reinterpret_cast<const float4*>(bi)[tid];
    float n0 = d0 * rstd * scv.x + biv.x;
    float n1 = d1 * rstd * scv.y + biv.y;
    float n2 = d2 * rstd * scv.z + biv.z;
    float n3 = d3 * rstd * scv.w + biv.w;
    ushort4 o = make_ushort4(f2bf(n0), f2bf(n1), f2bf(n2), f2bf(n3));
    reinterpret_cast<ushort4*>(nrm + (size_t)t * DIM)[tid] = o;
    int d = tid * 4;
    for (int j = 0; j < ntau; j++) {
        float p = n0 * tauk[(size_t)(d + 0) * ntau + j] + n1 * tauk[(size_t)(d + 1) * ntau + j]
                + n2 * tauk[(size_t)(d + 2) * ntau + j] + n3 * tauk[(size_t)(d + 3) * ntau + j];
        p = blockReduceF(p, red, wave, lane);
        if (tid == 0) tau_out[(size_t)t * ntau + j] = p + taub[j];
    }
}

// ---------------------------------------------------------------------------
// C = A[M][K] @ B[N][K]^T  (bf16 in).  KEYOUT=0: f32 out (+res fuse).
// KEYOUT=1: write u16 monotone keys of bf16(score) for radix-select gates.
// m97 structure + 2-phase LDS double-buffer: stage(next) issued right after
// the loop-top barrier so the global_load_lds flight overlaps ds_read+MFMA
// of the current tile; the next barrier's vmcnt(0) drain completes it.
// ---------------------------------------------------------------------------
template<int TAG, int KEYOUT>
__global__ __launch_bounds__(256) void k_gemm_bt(const u16* __restrict__ A,
                                                 const u16* __restrict__ B,
                                                 void* __restrict__ Cv,
                                                 int M, int N, int K,
                                                 const float* __restrict__ res) {
    __shared__ __align__(16) u16 As[2][4096];
    __shared__ __align__(16) u16 Bs[2][4096];
    int tid = threadIdx.x;
    int wave = tid >> 6, lane = tid & 63;
    int m0 = blockIdx.y * 128, n0 = blockIdx.x * 128;
    int wm = (wave >> 1) * 64, wn = (wave & 1) * 64;
    int kg = lane >> 4, l15 = lane & 15;

    const u16* gA0 = A + (size_t)(m0 + lane) * K + wave * 8;
    const u16* gA1 = A + (size_t)(m0 + 64 + lane) * K + wave * 8;
    const u16* gB0 = B + (size_t)(n0 + lane) * K + wave * 8;
    const u16* gB1 = B + (size_t)(n0 + 64 + lane) * K + wave * 8;

    f32x4 acc[4][4];
#pragma unroll
    for (int i = 0; i < 4; i++)
#pragma unroll
        for (int j = 0; j < 4; j++) { f32x4 z = {0.f, 0.f, 0.f, 0.f}; acc[i][j] = z; }

    // prologue: stage tile 0 into buffer 0
    gload16(gA0, As[0] + wave * 1024);
    gload16(gA1, As[0] + wave * 1024 + 512);
    gload16(gB0, Bs[0] + wave * 1024);
    gload16(gB1, Bs[0] + wave * 1024 + 512);

    int cur = 0;
    for (int k0 = 0; k0 < K; k0 += 32) {
        __syncthreads();   // vmcnt(0)+lgkmcnt(0) drain: buf[cur] ready, prev reads done
        if (k0 + 32 < K) { // stage next tile into buf[cur^1]; overlaps compute below
            int kn = k0 + 32;
            gload16(gA0 + kn, As[cur ^ 1] + wave * 1024);
            gload16(gA1 + kn, As[cur ^ 1] + wave * 1024 + 512);
            gload16(gB0 + kn, Bs[cur ^ 1] + wave * 1024);
            gload16(gB1 + kn, Bs[cur ^ 1] + wave * 1024 + 512);
        }
        const u16* Ac = As[cur];
        const u16* Bc = Bs[cur];
        short8 af[4], bg[4];
#pragma unroll
        for (int mi = 0; mi < 4; mi++) {
            int row = wm + mi * 16 + l15;
            af[mi] = *reinterpret_cast<const short8*>(&Ac[(kg * 128 + row) * 8]);
        }
#pragma unroll
        for (int ni = 0; ni < 4; ni++) {
            int row = wn + ni * 16 + l15;
            bg[ni] = *reinterpret_cast<const short8*>(&Bc[(kg * 128 + row) * 8]);
        }
#pragma unroll
        for (int mi = 0; mi < 4; mi++)
#pragma unroll
            for (int ni = 0; ni < 4; ni++)
                acc[mi][ni] = mfma_bf16(af[mi], bg[ni], acc[mi][ni]);
        cur ^= 1;
    }
    asm volatile("s_nop 7\n\ts_nop 7");
#pragma unroll
    for (int mi = 0; mi < 4; mi++) {
#pragma unroll
        for (int ni = 0; ni < 4; ni++) {
            int col = n0 + wn + ni * 16 + l15;
#pragma unroll
            for (int r = 0; r < 4; r++) {
                int rowm = m0 + wm + mi * 16 + (lane >> 4) * 4 + r;
                size_t idx = (size_t)rowm * N + col;
                float v = acc[mi][ni][r];
                if (KEYOUT) {
                    ((u16*)Cv)[idx] = bfkey(f2bf(v));
                } else {
                    if (res) v += res[idx];
                    ((float*)Cv)[idx] = v;
                }
            }
        }
    }
}

// ---------------------------------------------------------------------------
// Fused top-k threshold gate + sparse emit.
// Phase 1: 2-pass radix select over u16 keys -> exact kth-largest; select
//          keys >= thr (ties, capacity-capped); wave 0 computes gate values
//          (emit weight = score*gate) into LDS + bare-gate colsum atomics.
// Phase 2: all 256 threads gather-emit:  O[t] = sum_s val[s] * w[idx[s]]
//          TWO=1: two gates (Q,K) share selection -> OA, OB (bf16).
//          RES=1: single gate, accumulate into f32 io (+residual), else OA.
// ---------------------------------------------------------------------------
template<int TWO, int RES>
__global__ __launch_bounds__(256) void k_gate_emit(const u16* __restrict__ keys_g, int NC, int ksel,
                                                   int row_off,
                                                   const float* __restrict__ tau, int tau_stride, int tcol0,
                                                   const u16* __restrict__ w,
                                                   u16* __restrict__ OA, u16* __restrict__ OB,
                                                   float* __restrict__ io,
                                                   float* __restrict__ csA, float* __restrict__ csB) {
    extern __shared__ u16 keys[];
    __shared__ int   hist[256];
    __shared__ int   scnt;
    __shared__ int   dsel;
    __shared__ int   knext;
    __shared__ int   sidx[CAPK];
    __shared__ float svA[CAPK];
    __shared__ float svB[CAPK];
    int r = blockIdx.x, tid = threadIdx.x, wave = tid >> 6, lane = tid & 63;
    int t = row_off + r;
    const int cap = TWO ? CAPA : (RES ? CAPK : CAPA);

    // stage keys (uint4 = 8 keys)
    const uint4* srow8 = reinterpret_cast<const uint4*>(keys_g + (size_t)r * NC);
    for (int c = tid; c < NC / 8; c += 256)
        reinterpret_cast<uint4*>(keys)[c] = srow8[c];
    if (tid == 0) scnt = 0;

    // ---- radix select: 2 passes of 8 bits, MSB first ----
    u32 prefix = 0;
    int krem = ksel;
#pragma unroll
    for (int pass = 0; pass < 2; pass++) {
        int shift = 8 - pass * 8;
        hist[tid] = 0;
        __syncthreads();
        u32 pmask = (pass == 0) ? 0u : 0xFF00u;
        for (int i = tid; i < NC; i += 256) {
            u32 ky = keys[i];
            if ((ky & pmask) == prefix)
                atomicAdd(&hist[(ky >> shift) & 255], 1);
        }
        __syncthreads();
        int v = hist[tid];
#pragma unroll
        for (int off = 1; off < 256; off <<= 1) {
            int other = (tid + off < 256) ? hist[tid + off] : 0;
            __syncthreads();
            v += other;
            hist[tid] = v;
            __syncthreads();
        }
        int sfx = v;
        int sfx_next = (tid < 255) ? hist[tid + 1] : 0;
        if (sfx >= krem && (tid == 255 || sfx_next < krem)) {
            dsel = tid;
            knext = krem - sfx_next;
        }
        __syncthreads();
        prefix |= ((u32)dsel) << shift;
        krem = knext;
        __syncthreads();
    }
    u32 thr = prefix;   // exact kth-largest u16 key

    // ---- select keys >= thr; store raw score (reuse svA slot) ----
    for (int i = tid; i < NC; i += 256) {
        u32 ky = keys[i];
        if (ky >= thr) {
            int p = atomicAdd(&scnt, 1);
            if (p < cap) {
                sidx[p] = i;
                svA[p] = bf2f(keybf((u16)ky));
            }
        }
    }
    __syncthreads();
    int n = scnt < cap ? scnt : cap;

    // ---- wave 0: gate values -> svA/svB (emit weights), colsum atomics ----
    if (wave == 0) {
        float tA = tau[(size_t)t * tau_stride + tcol0];
        float tB = TWO ? tau[(size_t)t * tau_stride + tcol0 + 1] : 0.f;
        float sumA = 0.f, mxA = -1e30f, sumB = 0.f, mxB = -1e30f;
        float sv0 = (lane < n) ? svA[lane] : 0.f;
        float sv1 = (lane + 64 < n) ? svA[lane + 64] : 0.f;
        for (int i = lane; i < n; i += 64) {
            float sv = svA[i];
            float rA = sv - tA;
            float gA = rA > 0.f ? rA : 1e-8f * expf(rA);
            float eA = expf(gA) - 1.0f;            // match reference quantization
            sumA += eA; mxA = fmaxf(mxA, eA);
            if (TWO) {
                float rB = sv - tB;
                float gB = rB > 0.f ? rB : 1e-8f * expf(rB);
                float eB = expf(gB) - 1.0f;
                sumB += eB; mxB = fmaxf(mxB, eB);
            }
        }
#pragma unroll
        for (int off = 32; off > 0; off >>= 1) {
            sumA += __shfl_xor(sumA, off); mxA = fmaxf(mxA, __shfl_xor(mxA, off));
            sumB += __shfl_xor(sumB, off); mxB = fmaxf(mxB, __shfl_xor(mxB, off));
        }
        float fA = tanhf(mxA) / (sumA + 1e-8f);
        float fB = tanhf(mxB) / (sumB + 1e-8f);
        // two strided slots max (n <= 96 < 128)
        if (lane < n) {
            float sv = sv0; int ci = sidx[lane];
            float rA = sv - tA;
            float gA = rA > 0.f ? rA : 1e-8f * expf(rA);
            float ga = (expf(gA) - 1.0f) * fA;
            svA[lane] = ga * sv;                   // emit weight = score * gate
            atomicAdd(&csA[ci], ga);
            if (TWO) {
                float rB = sv - tB;
                float gB = rB > 0.f ? rB : 1e-8f * expf(rB);
                float gb = (expf(gB) - 1.0f) * fB;
                svB[lane] = gb * sv;
                atomicAdd(&csB[ci], gb);
            }
        }
        if (lane + 64 < n) {
            float sv = sv1; int ci = sidx[lane + 64];
            float rA = sv - tA;
            float gA = rA > 0.f ? rA : 1e-8f * expf(rA);
            float ga = (expf(gA) - 1.0f) * fA;
            svA[lane + 64] = ga * sv;
            atomicAdd(&csA[ci], ga);
            if (TWO) {
                float rB = sv - tB;
                float gB = rB > 0.f ? rB : 1e-8f * expf(rB);
                float gb = (expf(gB) - 1.0f) * fB;
                svB[lane + 64] = gb * sv;
                atomicAdd(&csB[ci], gb);
            }
        }
    }
    __syncthreads();

    // ---- phase 2: gather-emit (all threads), 4 rows in flight ----
    float a0 = 0, a1 = 0, a2 = 0, a3 = 0, b0 = 0, b1 = 0, b2 = 0, b3 = 0;
    float4 base;
    if (RES) base = reinterpret_cast<const float4*>(io + (size_t)t * DIM)[tid];
    int s = 0;
    for (; s + 4 <= n; s += 4) {
        const ushort4 w0 = reinterpret_cast<const ushort4*>(w + (size_t)sidx[s]     * DIM)[tid];
        const ushort4 w1 = reinterpret_cast<const ushort4*>(w + (size_t)sidx[s + 1] * DIM)[tid];
        const ushort4 w2 = reinterpret_cast<const ushort4*>(w + (size_t)sidx[s + 2] * DIM)[tid];
        const ushort4 w3 = reinterpret_cast<const ushort4*>(w + (size_t)sidx[s + 3] * DIM)[tid];
        float vA0 = svA[s], vA1 = svA[s + 1], vA2 = svA[s + 2], vA3 = svA[s + 3];
        a0 += vA0 * bf2f(w0.x) + vA1 * bf2f(w1.x) + vA2 * bf2f(w2.x) + vA3 * bf2f(w3.x);
        a1 += vA0 * bf2f(w0.y) + vA1 * bf2f(w1.y) + vA2 * bf2f(w2.y) + vA3 * bf2f(w3.y);
        a2 += vA0 * bf2f(w0.z) + vA1 * bf2f(w1.z) + vA2 * bf2f(w2.z) + vA3 * bf2f(w3.z);
        a3 += vA0 * bf2f(w0.w) + vA1 * bf2f(w1.w) + vA2 * bf2f(w2.w) + vA3 * bf2f(w3.w);
        if (TWO) {
            float vB0 = svB[s], vB1 = svB[s + 1], vB2 = svB[s + 2], vB3 = svB[s + 3];
            b0 += vB0 * bf2f(w0.x) + vB1 * bf2f(w1.x) + vB2 * bf2f(w2.x) + vB3 * bf2f(w3.x);
            b1 += vB0 * bf2f(w0.y) + vB1 * bf2f(w1.y) + vB2 * bf2f(w2.y) + vB3 * bf2f(w3.y);
            b2 += vB0 * bf2f(w0.z) + vB1 * bf2f(w1.z) + vB2 * bf2f(w2.z) + vB3 * bf2f(w3.z);
            b3 += vB0 * bf2f(w0.w) + vB1 * bf2f(w1.w) + vB2 * bf2f(w2.w) + vB3 * bf2f(w3.w);
        }
    }
    for (; s < n; s++) {
        const ushort4 wv = reinterpret_cast<const ushort4*>(w + (size_t)sidx[s] * DIM)[tid];
        float va = svA[s];
        a0 += va * bf2f(wv.x); a1 += va * bf2f(wv.y); a2 += va * bf2f(wv.z); a3 += va * bf2f(wv.w);
        if (TWO) {
            float vb = svB[s];
            b0 += vb * bf2f(wv.x); b1 += vb * bf2f(wv.y); b2 += vb * bf2f(wv.z); b3 += vb * bf2f(wv.w);
        }
    }
    if (RES) {
        reinterpret_cast<float4*>(io + (size_t)t * DIM)[tid] =
            make_float4(base.x + a0, base.y + a1, base.z + a2, base.w + a3);
    } else {
        reinterpret_cast<ushort4*>(OA + (size_t)t * DIM)[tid] = make_ushort4(f2bf(a0), f2bf(a1), f2bf(a2), f2bf(a3));
        if (TWO)
            reinterpret_cast<ushort4*>(OB + (size_t)t * DIM)[tid] = make_ushort4(f2bf(b0), f2bf(b1), f2bf(b2), f2bf(b3));
    }
}

// ---------------------------------------------------------------------------
// Causal flash attention, bf16 MFMA (16x16x32).
// Block = 256 thr / 4 waves, one (b,h), 64 q rows (16 per wave).
// Grid (h, bb, qt): concurrent blocks = all heads at same qt -> K/V rows
// shared across resident set (L2-friendly; do NOT reorder — round-6 lesson).
// ---------------------------------------------------------------------------
__global__ __launch_bounds__(256) void k_attn(const u16* __restrict__ Q,
                                              const u16* __restrict__ K,
                                              const u16* __restrict__ V,
                                              u16* __restrict__ O) {
    __shared__ __align__(16) u16 Qs[64 * APAD];
    __shared__ __align__(16) u16 Ks[64 * APAD];
    __shared__ __align__(16) u16 Vt[64 * APAD];
    __shared__ __align__(16) u16 Ps[4][16 * APAD];
    int tid = threadIdx.x, wave = tid >> 6, lane = tid & 63;
    int h = blockIdx.x, bb = blockIdx.y, qt = blockIdx.z;
    int q0 = qt * 64;
    size_t base = ((size_t)bb * SLEN) * DIM + (size_t)h * DH;
    int sr = tid >> 2, sc = (tid & 3) * 16;     // staging row (0..63), col (0/16/32/48)
    int g = lane >> 4, l15 = lane & 15;

    // stage Q tile once
    {
        const u16* qp = Q + base + (size_t)(q0 + sr) * DIM + sc;
        *reinterpret_cast<short8*>(&Qs[sr * APAD + sc])     = *reinterpret_cast<const short8*>(qp);
        *reinterpret_cast<short8*>(&Qs[sr * APAD + sc + 8]) = *reinterpret_cast<const short8*>(qp + 8);
    }
    __syncthreads();
    short8 qa0 = *reinterpret_cast<const short8*>(&Qs[(wave * 16 + l15) * APAD + g * 8]);
    short8 qa1 = *reinterpret_cast<const short8*>(&Qs[(wave * 16 + l15) * APAD + 32 + g * 8]);

    float m[4], l[4];
    f32x4 oacc[4];
#pragma unroll
    for (int i = 0; i < 4; i++) {
        m[i] = -1e30f; l[i] = 0.f;
        f32x4 z = {0.f, 0.f, 0.f, 0.f}; oacc[i] = z;
    }
    u16* pw = &Ps[wave][0];

    for (int kc = 0; kc <= qt; kc++) {
        __syncthreads();
        // ---- stage K [key][dim] and V transposed [dim][key] ----
        {
            const u16* kp = K + base + (size_t)(kc * 64 + sr) * DIM + sc;
            *reinterpret_cast<short8*>(&Ks[sr * APAD + sc])     = *reinterpret_cast<const short8*>(kp);
            *reinterpret_cast<short8*>(&Ks[sr * APAD + sc + 8]) = *reinterpret_cast<const short8*>(kp + 8);
            const u16* vp = V + base + (size_t)(kc * 64 + sr) * DIM + sc;
            short8 w0 = *reinterpret_cast<const short8*>(vp);
            short8 w1 = *reinterpret_cast<const short8*>(vp + 8);
            const u16* w0p = reinterpret_cast<const u16*>(&w0);
            const u16* w1p = reinterpret_cast<const u16*>(&w1);
#pragma unroll
            for (int j = 0; j < 16; j++) {
                int d = sc + j;
                int phys = (((sr >> 3) + d + (d >> 4)) & 7);   // rotate key-blocks per dim
                Vt[d * APAD + phys * 8 + (sr & 7)] = (j < 8) ? w0p[j] : w1p[j - 8];
            }
        }
        __syncthreads();

        // ---- QK^T: 8 MFMAs -> s4[ks] (q_local = wave*16 + g*4 + r, key = ks*16 + l15)
        f32x4 s4[4];
#pragma unroll
        for (int ks = 0; ks < 4; ks++) {
            f32x4 z = {0.f, 0.f, 0.f, 0.f}; s4[ks] = z;
            short8 kb0 = *reinterpret_cast<const short8*>(&Ks[(ks * 16 + l15) * APAD + g * 8]);
            short8 kb1 = *reinterpret_cast<const short8*>(&Ks[(ks * 16 + l15) * APAD + 32 + g * 8]);
            s4[ks] = mfma_bf16(qa0, kb0, s4[ks]);
            s4[ks] = mfma_bf16(qa1, kb1, s4[ks]);
        }
        asm volatile("s_nop 7\n\ts_nop 7");   // MFMA -> VALU read hazard

        // ---- scale + causal mask ----
        int key_base = kc * 64 + l15;
#pragma unroll
        for (int ks = 0; ks < 4; ks++) {
            int key = key_base + ks * 16;
#pragma unroll
            for (int r = 0; r < 4; r++) {
                int q_abs = q0 + wave * 16 + g * 4 + r;
                float sv = s4[ks][r] * 0.125f;
                s4[ks][r] = (key > q_abs) ? -1e30f : sv;
            }
        }

        // ---- online softmax per q-row; write P (bf16) to per-wave LDS ----
#pragma unroll
        for (int r = 0; r < 4; r++) {
            float mx = fmaxf(fmaxf(s4[0][r], s4[1][r]), fmaxf(s4[2][r], s4[3][r]));
            mx = fmaxf(mx, __shfl_xor(mx, 1));
            mx = fmaxf(mx, __shfl_xor(mx, 2));
            mx = fmaxf(mx, __shfl_xor(mx, 4));
            mx = fmaxf(mx, __shfl_xor(mx, 8));
            float mnew = fmaxf(m[r], mx);
            float al = __expf(m[r] - mnew);
            m[r] = mnew;
            float p0 = __expf(s4[0][r] - mnew);
            float p1 = __expf(s4[1][r] - mnew);
            float p2 = __expf(s4[2][r] - mnew);
            float p3 = __expf(s4[3][r] - mnew);
            float ps = p0 + p1 + p2 + p3;
            ps += __shfl_xor(ps, 1);
            ps += __shfl_xor(ps, 2);
            ps += __shfl_xor(ps, 4);
            ps += __shfl_xor(ps, 8);
            l[r] = l[r] * al + ps;
#pragma unroll
            for (int ds_ = 0; ds_ < 4; ds_++) oacc[ds_][r] *= al;
            int row = g * 4 + r;
            pw[row * APAD +  0 + l15] = f2bf(p0);
            pw[row * APAD + 16 + l15] = f2bf(p1);
            pw[row * APAD + 32 + l15] = f2bf(p2);
            pw[row * APAD + 48 + l15] = f2bf(p3);
        }

        // ---- PV: read P as A-fragments, V^T as B-fragments; 8 MFMAs ----
        short8 pa0 = *reinterpret_cast<const short8*>(&pw[l15 * APAD + g * 8]);
        short8 pa1 = *reinterpret_cast<const short8*>(&pw[l15 * APAD + 32 + g * 8]);
#pragma unroll
        for (int dsub = 0; dsub < 4; dsub++) {
            int d = dsub * 16 + l15;
            int rot = d + (d >> 4);
            short8 vb0 = *reinterpret_cast<const short8*>(&Vt[d * APAD + (((0 + g) + rot) & 7) * 8]);
            short8 vb1 = *reinterpret_cast<const short8*>(&Vt[d * APAD + (((4 + g) + rot) & 7) * 8]);
            oacc[dsub] = mfma_bf16(pa0, vb0, oacc[dsub]);
            oacc[dsub] = mfma_bf16(pa1, vb1, oacc[dsub]);
        }
    }
    asm volatile("s_nop 7\n\ts_nop 7");       // MFMA -> VALU read hazard

    // ---- epilogue: O = oacc / l, bf16 ----
#pragma unroll
    for (int r = 0; r < 4; r++) {
        float inv = 1.0f / l[r];
        int row = q0 + wave * 16 + g * 4 + r;
#pragma unroll
        for (int dsub = 0; dsub < 4; dsub++) {
            O[base + (size_t)row * DIM + dsub * 16 + l15] = f2bf(oacc[dsub][r] * inv);
        }
    }
}

// ---------------------------------------------------------------------------
// aux = sum over gate columns of (colsum/T - 1/N)^2 * N
// ---------------------------------------------------------------------------
__global__ __launch_bounds__(256) void k_aux(const float* __restrict__ cs,
                                             float* __restrict__ out_aux) {
    __shared__ float red[4];
    int gtid = blockIdx.x * 256 + threadIdx.x;
    float acc = 0.f;
    for (int i = gtid; i < 3 * 4096 + 8192; i += gridDim.x * 256) {
        float mean = cs[i] * (1.0f / 4096.0f);
        float tN, Nf;
        if (i < 12288) { tN = 1.0f / 4096.0f; Nf = 4096.0f; }
        else           { tN = 1.0f / 8192.0f; Nf = 8192.0f; }
        float d = mean - tN;
        acc += d * d * Nf;
    }
    acc = blockReduceF(acc, red, threadIdx.x >> 6, threadIdx.x & 63);
    if (threadIdx.x == 0) atomicAdd(out_aux, acc);
}

// ---------------------------------------------------------------------------
extern "C" void kernel_launch(void* const* d_in, const int* in_sizes, int n_in,
                              void* d_out, int out_size, void* d_ws, size_t ws_size,
                              hipStream_t stream) {
    const float* x         = (const float*)d_in[0];
    const float* qk_emb    = (const float*)d_in[1];
    const float* qk_w      = (const float*)d_in[2];
    const float* v_emb     = (const float*)d_in[3];
    const float* v_w       = (const float*)d_in[4];
    const float* know_emb  = (const float*)d_in[5];
    const float* know_w    = (const float*)d_in[6];
    const float* tau_attn_k = (const float*)d_in[7];
    const float* tau_attn_b = (const float*)d_in[8];
    const float* tau_know_k = (const float*)d_in[9];
    const float* tau_know_b = (const float*)d_in[10];
    const float* expand_O  = (const float*)d_in[11];
    const float* ln1_s     = (const float*)d_in[12];
    const float* ln1_b     = (const float*)d_in[13];
    const float* ln2_s     = (const float*)d_in[14];
    const float* ln2_b     = (const float*)d_in[15];
    float* out = (float*)d_out;
    char*  ws  = (char*)d_ws;

    // workspace layout (bytes)
    u16*   nrm_bf   = (u16*)(ws + 0);                 //  8 MB
    u16*   qkemb_bf = (u16*)(ws + 8388608);           //  8 MB
    u16*   vemb_bf  = (u16*)(ws + 16777216);          //  8 MB
    u16*   knemb_bf = (u16*)(ws + 25165824);          // 16 MB
    u16*   expT_bf  = (u16*)(ws + 41943040);          //  2 MB
    u16*   attn_bf  = (u16*)(ws + 44040192);          //  8 MB
    u16*   qkw_bf   = (u16*)(ws + 52428800);          //  8 MB
    u16*   vw_bf    = (u16*)(ws + 60817408);          //  8 MB
    u16*   knw_bf   = (u16*)(ws + 69206016);          // 16 MB
    u16*   Qb       = (u16*)(ws + 85983232);          //  8 MB (bf16)
    u16*   Kb       = (u16*)(ws + 94371840);          //  8 MB (bf16)
    u16*   Vb       = (u16*)(ws + 102760448);         //  8 MB (bf16)
    u16*   keysbuf  = (u16*)(ws + 111149056);         // 64 MB (u16 keys, know full M)
    float* tauA     = (float*)(ws + 185384960);       // [T][3]
    float* tauKn    = (float*)(ws + 185434112);       // [T]
    float* colsum   = (float*)(ws + 185450496);       // 20480 floats: Q,K,V,Kn
    const size_t WS_NEEDED = 185532416;
    if (ws_size < WS_NEEDED) return;   // workspace too small — bail cleanly

    float* colQ = colsum, *colK = colsum + 4096, *colV = colsum + 8192, *colKn = colsum + 12288;

    hipMemsetAsync(colsum, 0, 20480 * sizeof(float), stream);
    hipMemsetAsync(out + (size_t)TOK * DIM, 0, sizeof(float), stream);

    // bf16 conversions: all six tables in one launch + expand_O transpose
    k_convert_all<<<2048, 256, 0, stream>>>(qk_emb, v_emb, know_emb, qk_w, v_w, know_w,
                                            qkemb_bf, vemb_bf, knemb_bf, qkw_bf, vw_bf, knw_bf);
    k_transpose_bf16<<<dim3(32, 32), 256, 0, stream>>>(expand_O, expT_bf);

    // LN1 + tau(3)
    k_ln_tau<<<TOK, 256, 0, stream>>>(x, ln1_s, ln1_b, tau_attn_k, tau_attn_b, 3, nrm_bf, tauA);

    // scores_qk (u16 keys) + fused gate+emit Q,K (shared selection)
    k_gemm_bt<0, 1><<<dim3(NQK / 128, TOK / 128), 256, 0, stream>>>(nrm_bf, qkemb_bf, keysbuf, TOK, NQK, DIM, nullptr);
    k_gate_emit<1, 0><<<TOK, 256, NQK * sizeof(u16), stream>>>(keysbuf, NQK, 32, 0, tauA, 3, 0,
                                                               qkw_bf, Qb, Kb, nullptr, colQ, colK);
    // scores_v (u16 keys) + fused gate+emit V
    k_gemm_bt<1, 1><<<dim3(NV / 128, TOK / 128), 256, 0, stream>>>(nrm_bf, vemb_bf, keysbuf, TOK, NV, DIM, nullptr);
    k_gate_emit<0, 0><<<TOK, 256, NV * sizeof(u16), stream>>>(keysbuf, NV, 32, 0, tauA, 3, 2,
                                                              vw_bf, Vb, nullptr, nullptr, colV, nullptr);

    // causal MHA (bf16 MFMA) -> bf16
    k_attn<<<dim3(NH, 2, SLEN / 64), 256, 0, stream>>>(Qb, Kb, Vb, attn_bf);

    // out @ expand_O + residual x  -> x1 (stored in d_out)
    k_gemm_bt<2, 0><<<dim3(DIM / 128, TOK / 128), 256, 0, stream>>>(attn_bf, expT_bf, out, TOK, DIM, DIM, x);

    // LN2 + tau_know
    k_ln_tau<<<TOK, 256, 0, stream>>>(out, ln2_s, ln2_b, tau_know_k, tau_know_b, 1, nrm_bf, tauKn);

    // know scores (u16 keys) + fused gate+emit(+residual), full M in one shot
    k_gemm_bt<3, 1><<<dim3(NKN / 128, TOK / 128), 256, 0, stream>>>(nrm_bf, knemb_bf, keysbuf, TOK, NKN, DIM, nullptr);
    k_gate_emit<0, 1><<<TOK, 256, NKN * sizeof(u16), stream>>>(keysbuf, NKN, 64, 0, tauKn, 1, 0,
                                                               knw_bf, nullptr, nullptr, out, colKn, nullptr);

    // aux scalar
    k_aux<<<20, 256, 0, stream>>>(colsum, out + (size_t)TOK * DIM);
}